// Round 3
// baseline (8868.127 us; speedup 1.0000x reference)
//
#include <hip/hip_runtime.h>
#include <hip/hip_bf16.h>

#define N_DRUG 20000
#define N_DIS  20000
#define E_G    320000
#define BATCH  4096
#define N_MOL  65536
#define E_MOL  262144
#define DIN    128
#define DH     256
#define DOUT   128
#define NF     9
#define NV     128

__device__ __forceinline__ void atomAddF(float* p, float v) { atomicAdd(p, v); }

// ---------------- misc ----------------
__global__ void k_sentinel(float* out, int n, float v) {
    int i = blockIdx.x * 256 + threadIdx.x;
    if (i < n) out[i] = v;
}

// ---------------- diagnostics: non-finite scan ----------------
__global__ void k_nanscan(const float* __restrict__ buf, long long n, int* __restrict__ flags, int stage) {
    long long i = (long long)blockIdx.x * 256 + threadIdx.x;
    const long long stride = (long long)gridDim.x * 256;
    int bad = 0;
    for (; i < n; i += stride) {
        float v = buf[i];
        if (!(fabsf(v) <= 1e30f)) bad = 1;  // catches NaN and +-Inf
    }
    if (bad) flags[stage] = 1;
}

__global__ void k_diag(const int* __restrict__ flags, float* __restrict__ out) {
    if (blockIdx.x == 0 && threadIdx.x == 0) {
        for (int s = 1; s <= 9; ++s) {
            if (flags[s]) { out[0] = 100.f + 10.f * (float)s; return; }
        }
    }
}

// ---------------- degree ----------------
__global__ void k_count(const int* __restrict__ dst, int* __restrict__ cnt, int E) {
    int e = blockIdx.x * 256 + threadIdx.x;
    if (e < E) atomicAdd(&cnt[dst[e]], 1);
}
__global__ void k_dinv(const int* __restrict__ cnt, float* __restrict__ dinv, int n) {
    int i = blockIdx.x * 256 + threadIdx.x;
    if (i < n) dinv[i] = rsqrtf(1.0f + (float)cnt[i]);
}

// ---------------- GEMM: C[M,N] = A[M,K] @ B[K,N], all f32 ----------------
__global__ __launch_bounds__(256) void k_gemm(const float* __restrict__ A,
                                              const float* __restrict__ B,
                                              float* __restrict__ C, int M, int K, int N) {
    __shared__ float As[32][64];   // [k][m]
    __shared__ float Bs[32][64];   // [k][n]
    const int bm = blockIdx.y * 64;
    const int bn = blockIdx.x * 64;
    const int tid = threadIdx.x;
    const int tx = tid & 15;
    const int ty = tid >> 4;
    const int ra = tid >> 3;        // 0..31
    const int c4 = (tid & 7) * 4;   // A k-offset
    const int s8 = (tid & 7) * 8;   // B n-offset
    float acc[4][4];
#pragma unroll
    for (int i = 0; i < 4; ++i)
#pragma unroll
        for (int j = 0; j < 4; ++j) acc[i][j] = 0.f;

    for (int k0 = 0; k0 < K; k0 += 32) {
#pragma unroll
        for (int half = 0; half < 2; ++half) {
            int rr = ra + half * 32;
            int row = bm + rr;
            float4 v = make_float4(0.f, 0.f, 0.f, 0.f);
            if (row < M) v = *reinterpret_cast<const float4*>(A + (size_t)row * K + k0 + c4);
            As[c4 + 0][rr] = v.x; As[c4 + 1][rr] = v.y;
            As[c4 + 2][rr] = v.z; As[c4 + 3][rr] = v.w;
        }
        {
            size_t boff = (size_t)(k0 + ra) * N + bn + s8;
            float4 v0 = *reinterpret_cast<const float4*>(B + boff);
            float4 v1 = *reinterpret_cast<const float4*>(B + boff + 4);
            Bs[ra][s8 + 0] = v0.x; Bs[ra][s8 + 1] = v0.y;
            Bs[ra][s8 + 2] = v0.z; Bs[ra][s8 + 3] = v0.w;
            Bs[ra][s8 + 4] = v1.x; Bs[ra][s8 + 5] = v1.y;
            Bs[ra][s8 + 6] = v1.z; Bs[ra][s8 + 7] = v1.w;
        }
        __syncthreads();
#pragma unroll
        for (int kk = 0; kk < 32; ++kk) {
            const float4 av = *reinterpret_cast<const float4*>(&As[kk][ty << 2]);
            const float4 bv = *reinterpret_cast<const float4*>(&Bs[kk][tx << 2]);
            acc[0][0] += av.x * bv.x; acc[0][1] += av.x * bv.y; acc[0][2] += av.x * bv.z; acc[0][3] += av.x * bv.w;
            acc[1][0] += av.y * bv.x; acc[1][1] += av.y * bv.y; acc[1][2] += av.y * bv.z; acc[1][3] += av.y * bv.w;
            acc[2][0] += av.z * bv.x; acc[2][1] += av.z * bv.y; acc[2][2] += av.z * bv.z; acc[2][3] += av.z * bv.w;
            acc[3][0] += av.w * bv.x; acc[3][1] += av.w * bv.y; acc[3][2] += av.w * bv.z; acc[3][3] += av.w * bv.w;
        }
        __syncthreads();
    }
#pragma unroll
    for (int i = 0; i < 4; ++i) {
        int row = bm + (ty << 2) + i;
        if (row < M) {
            float* cp = C + (size_t)row * N + bn + (tx << 2);
            cp[0] = acc[i][0]; cp[1] = acc[i][1]; cp[2] = acc[i][2]; cp[3] = acc[i][3];
        }
    }
}

// ---------------- aggregation ----------------
__global__ void k_agg_init(const float* __restrict__ h, const float* __restrict__ dinv,
                           const float* __restrict__ bias, float* __restrict__ out,
                           long long tot, int cshift) {
    long long idx = (long long)blockIdx.x * 256 + threadIdx.x;
    if (idx >= tot) return;
    int i = (int)(idx >> cshift);
    int j = (int)idx & ((1 << cshift) - 1);
    float d = dinv[i];
    out[idx] = h[idx] * d * d + bias[j];
}

__global__ void k_edge_scatter(const float* __restrict__ h, const float* __restrict__ dinv,
                               const int* __restrict__ src, const int* __restrict__ dst,
                               float* __restrict__ out, int E, int c4shift, int C) {
    long long tid = (long long)blockIdx.x * 256 + threadIdx.x;
    if (tid >= ((long long)E << c4shift)) return;
    int e = (int)(tid >> c4shift);
    int c = ((int)tid & ((1 << c4shift) - 1)) * 4;
    int s = src[e], d = dst[e];
    float w = dinv[s] * dinv[d];
    const float4 hv = *reinterpret_cast<const float4*>(h + (size_t)s * C + c);
    float* op = out + (size_t)d * C + c;
    atomAddF(op + 0, w * hv.x);
    atomAddF(op + 1, w * hv.y);
    atomAddF(op + 2, w * hv.z);
    atomAddF(op + 3, w * hv.w);
}

// ---------------- BatchNorm ----------------
__global__ void k_bn_stats(const float* __restrict__ x, float* __restrict__ sum,
                           float* __restrict__ sq, int n, int C, int rpb) {
    int j = threadIdx.x;
    int r0 = blockIdx.x * rpb;
    int r1 = min(r0 + rpb, n);
    float s = 0.f, q = 0.f;
    for (int r = r0; r < r1; ++r) {
        float v = x[(size_t)r * C + j];
        s += v; q += v * v;
    }
    atomAddF(&sum[j], s);
    atomAddF(&sq[j], q);
}

__global__ void k_bn_apply(float* __restrict__ x, const float* __restrict__ sum,
                           const float* __restrict__ sq, const float* __restrict__ g,
                           const float* __restrict__ be, long long tot, int cshift, float invN) {
    long long idx = (long long)blockIdx.x * 256 + threadIdx.x;
    if (idx >= tot) return;
    int j = (int)idx & ((1 << cshift) - 1);
    float m = sum[j] * invN;
    float v = sq[j] * invN - m * m;
    float r = rsqrtf(fmaxf(v, 0.f) + 1e-5f);
    float y = g[j] * (x[idx] - m) * r + be[j];
    x[idx] = fmaxf(y, 0.f);
}

// ---------------- atom encoder ----------------
__global__ __launch_bounds__(256) void k_atom_enc(const int* __restrict__ mol_x,
                                                  const float* __restrict__ emb,
                                                  float* __restrict__ h) {
    __shared__ int idx[NF];
    int i = blockIdx.x;
    int j = threadIdx.x;
    if (j < NF) idx[j] = mol_x[i * NF + j];
    __syncthreads();
    float s = 0.f;
#pragma unroll
    for (int f = 0; f < NF; ++f)
        s += emb[((size_t)f * NV + idx[f]) * DH + j];
    h[(size_t)i * DH + j] = s;
}

// ---------------- segment pool ----------------
__global__ void k_pool(const float* __restrict__ mfeat, const int* __restrict__ batch,
                       float* __restrict__ mpool) {
    int tid = blockIdx.x * 256 + threadIdx.x;
    int i = tid >> 5;
    if (i >= N_MOL) return;
    int c = (tid & 31) * 4;
    int b = batch[i];
    const float4 v = *reinterpret_cast<const float4*>(mfeat + (size_t)i * 128 + c);
    float* p = mpool + (size_t)b * 128 + c;
    atomAddF(p + 0, v.x); atomAddF(p + 1, v.y);
    atomAddF(p + 2, v.z); atomAddF(p + 3, v.w);
}

// ---------------- head: conv1 ----------------
__global__ __launch_bounds__(64) void k_conv1(const float* __restrict__ dfeat,
                                              const float* __restrict__ mpool,
                                              const float* __restrict__ sfeat,
                                              const int* __restrict__ drug_idx,
                                              const int* __restrict__ dis_idx,
                                              const float* __restrict__ W,
                                              const float* __restrict__ bias,
                                              float* __restrict__ y1) {
    __shared__ float xs[3][128];
    __shared__ float w[54];
    __shared__ float bb[6];
    int b = blockIdx.x, t = threadIdx.x;
    int di = drug_idx[b], si = dis_idx[b];
    const float* r0 = dfeat + (size_t)di * 128;
    const float* r1 = mpool + (size_t)b * 128;
    const float* r2 = sfeat + (size_t)si * 128;
    xs[0][t] = r0[t]; xs[0][t + 64] = r0[t + 64];
    xs[1][t] = r1[t]; xs[1][t + 64] = r1[t + 64];
    xs[2][t] = r2[t]; xs[2][t + 64] = r2[t + 64];
    if (t < 54) w[t] = W[t];
    if (t < 6) bb[t] = bias[t];
    __syncthreads();
    int l0 = 2 * t, l1 = l0 + 1;
#pragma unroll
    for (int o = 0; o < 6; ++o) {
        float ya = bb[o], yb = bb[o];
#pragma unroll
        for (int i = 0; i < 3; ++i) {
            const float* wi = &w[(o * 3 + i) * 3];
            float xm1 = (l0 > 0) ? xs[i][l0 - 1] : 0.f;
            float x0 = xs[i][l0];
            float x1 = xs[i][l1];
            float x2 = (l1 < 127) ? xs[i][l1 + 1] : 0.f;
            ya += wi[0] * xm1 + wi[1] * x0 + wi[2] * x1;
            yb += wi[0] * x0 + wi[1] * x1 + wi[2] * x2;
        }
        y1[((size_t)b * 6 + o) * 64 + t] = fmaxf(ya, yb);
    }
}

// hb layout per 'which' (32 floats): [0..5]=sum [8..13]=sumsq [16..21]=mean [24..29]=rstd
__global__ __launch_bounds__(256) void k_head_stats(const float* __restrict__ y,
                                                    float* __restrict__ hb, int which, int L) {
    int o = blockIdx.x;
    int b0 = blockIdx.y * 16;
    int t = threadIdx.x;
    float s = 0.f, q = 0.f;
    int per = 16 * L;
    for (int idx = t; idx < per; idx += 256) {
        int b = b0 + idx / L;
        int l = idx - (idx / L) * L;
        float v = y[((size_t)b * 6 + o) * L + l];
        s += v; q += v * v;
    }
    __shared__ float sms[4], smq[4];
#pragma unroll
    for (int off = 32; off > 0; off >>= 1) {
        s += __shfl_down(s, off);
        q += __shfl_down(q, off);
    }
    if ((t & 63) == 0) { sms[t >> 6] = s; smq[t >> 6] = q; }
    __syncthreads();
    if (t == 0) {
        float S = 0.f, Q = 0.f;
        for (int i = 0; i < 4; ++i) { S += sms[i]; Q += smq[i]; }
        atomAddF(hb + which * 32 + o, S);
        atomAddF(hb + which * 32 + 8 + o, Q);
    }
}

__global__ void k_bn_fin(float* __restrict__ hb, int which, float invN) {
    int o = threadIdx.x;
    if (o >= 6) return;
    float* p = hb + which * 32;
    float m = p[o] * invN;
    float v = p[8 + o] * invN - m * m;
    p[16 + o] = m;
    p[24 + o] = rsqrtf(fmaxf(v, 0.f) + 1e-5f);
}

// ---------------- head: conv2 ----------------
__global__ __launch_bounds__(64) void k_conv2(const float* __restrict__ y1,
                                              const float* __restrict__ hb,
                                              const float* __restrict__ g1,
                                              const float* __restrict__ be1,
                                              const float* __restrict__ W,
                                              const float* __restrict__ bias,
                                              float* __restrict__ y2) {
    __shared__ float xs[6][64];
    __shared__ float w[108];
    __shared__ float bb[6];
    int b = blockIdx.x, t = threadIdx.x;  // 64 threads; lower 32 compute
    const float* mean = hb + 16;
    const float* rstd = hb + 24;
    for (int idx = t; idx < 384; idx += 64) {
        int o = idx >> 6, l = idx & 63;
        float v = y1[((size_t)b * 6 + o) * 64 + l];
        v = g1[o] * (v - mean[o]) * rstd[o] + be1[o];
        xs[o][l] = fmaxf(v, 0.f);
    }
    for (int idx = t; idx < 108; idx += 64) w[idx] = W[idx];
    if (t < 6) bb[t] = bias[t];
    __syncthreads();
    if (t >= 32) return;
    int l0 = 2 * t, l1 = l0 + 1;
#pragma unroll
    for (int o = 0; o < 6; ++o) {
        float ya = bb[o], yb = bb[o];
#pragma unroll
        for (int i = 0; i < 6; ++i) {
            const float* wi = &w[(o * 6 + i) * 3];
            float xm1 = (l0 > 0) ? xs[i][l0 - 1] : 0.f;
            float x0 = xs[i][l0];
            float x1 = xs[i][l1];
            float x2 = (l1 < 63) ? xs[i][l1 + 1] : 0.f;
            ya += wi[0] * xm1 + wi[1] * x0 + wi[2] * x1;
            yb += wi[0] * x0 + wi[1] * x1 + wi[2] * x2;
        }
        y2[((size_t)b * 6 + o) * 32 + t] = fmaxf(ya, yb);
    }
}

// ---------------- head final ----------------
__global__ __launch_bounds__(128) void k_head(const float* __restrict__ y2,
                                              const float* __restrict__ hb,
                                              const float* __restrict__ g2,
                                              const float* __restrict__ be2,
                                              const float* __restrict__ l1W,
                                              const float* __restrict__ l1b,
                                              const float* __restrict__ l2W,
                                              const float* __restrict__ l2b,
                                              float* __restrict__ out) {
    __shared__ float fs[192];
    __shared__ float sm[2];
    int b = blockIdx.x, t = threadIdx.x;
    const float* mean = hb + 32 + 16;
    const float* rstd = hb + 32 + 24;
    for (int idx = t; idx < 192; idx += 128) {
        int o = idx >> 5, l = idx & 31;
        float v = y2[((size_t)b * 6 + o) * 32 + l];
        v = g2[o] * (v - mean[o]) * rstd[o] + be2[o];
        fs[idx] = fmaxf(v, 0.f);
    }
    __syncthreads();
    float h = l1b[t];
    for (int k = 0; k < 192; ++k)
        h += fs[k] * l1W[k * 128 + t];
    h = fmaxf(h, 0.f);
    float p = h * l2W[t];
#pragma unroll
    for (int off = 32; off > 0; off >>= 1) p += __shfl_down(p, off);
    if ((t & 63) == 0) sm[t >> 6] = p;
    __syncthreads();
    if (t == 0) out[b] = sm[0] + sm[1] + l2b[0];
}

// ---------------- host-side GCN driver ----------------
static void gcn_layer(const float* x, const float* W, const float* bias,
                      float* h, float* outp, int n, int K, int Cout,
                      const int* src, const int* dst, int E, const float* dinv,
                      bool do_bn, const float* g, const float* be,
                      float* bnsum, float* bnsq, hipStream_t stream) {
    dim3 gg(Cout / 64, (n + 63) / 64);
    k_gemm<<<gg, 256, 0, stream>>>(x, W, h, n, K, Cout);
    int cshift = (Cout == 256) ? 8 : 7;
    long long tot = (long long)n * Cout;
    k_agg_init<<<(int)((tot + 255) / 256), 256, 0, stream>>>(h, dinv, bias, outp, tot, cshift);
    int c4shift = cshift - 2;
    long long st = (long long)E << c4shift;
    k_edge_scatter<<<(int)((st + 255) / 256), 256, 0, stream>>>(h, dinv, src, dst, outp, E, c4shift, Cout);
    if (do_bn) {
        hipMemsetAsync(bnsum, 0, 512 * sizeof(float), stream);
        k_bn_stats<<<(n + 127) / 128, Cout, 0, stream>>>(outp, bnsum, bnsq, n, Cout, 128);
        float invN = 1.0f / (float)n;
        k_bn_apply<<<(int)((tot + 255) / 256), 256, 0, stream>>>(outp, bnsum, bnsq, g, be, tot, cshift, invN);
    }
}

static void run_gcn(const float* x0, float* bufA, float* bufB, float* outF,
                    const int* ei, int n, int E, int inDim,
                    const float* W0, const float* W1, const float* W2,
                    const float* b0, const float* b1, const float* b2,
                    const float* g0, const float* g1, const float* be0, const float* be1,
                    int* cnt, float* dinv, float* bnsum, float* bnsq, hipStream_t stream) {
    const int* src = ei;
    const int* dst = ei + E;
    hipMemsetAsync(cnt, 0, (size_t)n * sizeof(int), stream);
    k_count<<<(E + 255) / 256, 256, 0, stream>>>(dst, cnt, E);
    k_dinv<<<(n + 255) / 256, 256, 0, stream>>>(cnt, dinv, n);
    gcn_layer(x0,   W0, b0, bufB, bufA, n, inDim, 256, src, dst, E, dinv, true, g0, be0, bnsum, bnsq, stream);
    gcn_layer(bufA, W1, b1, bufB, bufA, n, 256, 256, src, dst, E, dinv, true, g1, be1, bnsum, bnsq, stream);
    gcn_layer(bufA, W2, b2, bufB, outF, n, 256, 128, src, dst, E, dinv, false, nullptr, nullptr, bnsum, bnsq, stream);
}

extern "C" void kernel_launch(void* const* d_in, const int* in_sizes, int n_in,
                              void* d_out, int out_size, void* d_ws, size_t ws_size,
                              hipStream_t stream) {
    float* out = (float*)d_out;
    if (n_in != 52) { k_sentinel<<<16, 256, 0, stream>>>(out, out_size, -111.f); return; }
    if (in_sizes[0] != N_DRUG * DIN || in_sizes[29] != NF * NV * DH || in_sizes[48] != 192 * 128) {
        k_sentinel<<<16, 256, 0, stream>>>(out, out_size, -222.f); return;
    }

    char* w = (char*)d_ws;
    auto alloc = [&](size_t bytes) { char* p = w; w += (bytes + 255) & ~(size_t)255; return p; };
    float* bufA  = (float*)alloc((size_t)N_MOL * 256 * 4);
    float* bufB  = (float*)alloc((size_t)N_MOL * 256 * 4);
    float* dfeat = (float*)alloc((size_t)N_DRUG * 128 * 4);
    float* sfeat = (float*)alloc((size_t)N_DIS * 128 * 4);
    float* mpool = (float*)alloc((size_t)BATCH * 128 * 4);
    int*   cnt   = (int*)alloc((size_t)N_MOL * 4);
    float* dinv  = (float*)alloc((size_t)N_MOL * 4);
    float* bnsum = (float*)alloc(512 * 4);
    float* bnsq  = bnsum + 256;
    float* hstat = (float*)alloc(64 * 4);
    int*   flags = (int*)alloc(16 * 4);
    float* y1    = (float*)alloc((size_t)BATCH * 6 * 64 * 4);
    float* y2    = (float*)alloc((size_t)BATCH * 6 * 32 * 4);
    if ((size_t)(w - (char*)d_ws) > ws_size) {
        k_sentinel<<<16, 256, 0, stream>>>(out, out_size, -333.f); return;
    }

    const float* drug_x  = (const float*)d_in[0];
    const int* drug_ei   = (const int*)d_in[1];
    const int* drug_idx  = (const int*)d_in[2];
    const float* dis_x   = (const float*)d_in[3];
    const int* dis_ei    = (const int*)d_in[4];
    const int* dis_idx   = (const int*)d_in[5];
    const int* mol_x     = (const int*)d_in[6];
    const int* mol_ei    = (const int*)d_in[7];
    const int* mol_b     = (const int*)d_in[8];
    const float *dr_W0 = (const float*)d_in[9], *dr_W1 = (const float*)d_in[10], *dr_W2 = (const float*)d_in[11];
    const float *dr_b0 = (const float*)d_in[12], *dr_b1 = (const float*)d_in[13], *dr_b2 = (const float*)d_in[14];
    const float *dr_g0 = (const float*)d_in[15], *dr_g1 = (const float*)d_in[16];
    const float *dr_be0 = (const float*)d_in[17], *dr_be1 = (const float*)d_in[18];
    const float *di_W0 = (const float*)d_in[19], *di_W1 = (const float*)d_in[20], *di_W2 = (const float*)d_in[21];
    const float *di_b0 = (const float*)d_in[22], *di_b1 = (const float*)d_in[23], *di_b2 = (const float*)d_in[24];
    const float *di_g0 = (const float*)d_in[25], *di_g1 = (const float*)d_in[26];
    const float *di_be0 = (const float*)d_in[27], *di_be1 = (const float*)d_in[28];
    const float* mol_emb = (const float*)d_in[29];
    const float *mo_W0 = (const float*)d_in[30], *mo_W1 = (const float*)d_in[31], *mo_W2 = (const float*)d_in[32];
    const float *mo_b0 = (const float*)d_in[33], *mo_b1 = (const float*)d_in[34], *mo_b2 = (const float*)d_in[35];
    const float *mo_g0 = (const float*)d_in[36], *mo_g1 = (const float*)d_in[37];
    const float *mo_be0 = (const float*)d_in[38], *mo_be1 = (const float*)d_in[39];
    const float *c1_W = (const float*)d_in[40], *c1_b = (const float*)d_in[41];
    const float *c1_g = (const float*)d_in[42], *c1_be = (const float*)d_in[43];
    const float *c2_W = (const float*)d_in[44], *c2_b = (const float*)d_in[45];
    const float *c2_g = (const float*)d_in[46], *c2_be = (const float*)d_in[47];
    const float *l1_W = (const float*)d_in[48], *l1_b = (const float*)d_in[49];
    const float *l2_W = (const float*)d_in[50], *l2_b = (const float*)d_in[51];

    hipMemsetAsync(flags, 0, 16 * 4, stream);

    // ---- drug GCN -> dfeat ----
    run_gcn(drug_x, bufA, bufB, dfeat, drug_ei, N_DRUG, E_G, DIN,
            dr_W0, dr_W1, dr_W2, dr_b0, dr_b1, dr_b2, dr_g0, dr_g1, dr_be0, dr_be1,
            cnt, dinv, bnsum, bnsq, stream);
    k_nanscan<<<2048, 256, 0, stream>>>(dfeat, (long long)N_DRUG * 128, flags, 1);

    // ---- disease GCN -> sfeat ----
    run_gcn(dis_x, bufA, bufB, sfeat, dis_ei, N_DIS, E_G, DIN,
            di_W0, di_W1, di_W2, di_b0, di_b1, di_b2, di_g0, di_g1, di_be0, di_be1,
            cnt, dinv, bnsum, bnsq, stream);
    k_nanscan<<<2048, 256, 0, stream>>>(sfeat, (long long)N_DIS * 128, flags, 2);

    // ---- mol: atom encoder -> GCN -> pool ----
    k_atom_enc<<<N_MOL, 256, 0, stream>>>(mol_x, mol_emb, bufA);
    k_nanscan<<<2048, 256, 0, stream>>>(bufA, (long long)N_MOL * 256, flags, 3);
    run_gcn(bufA, bufA, bufB, bufA, mol_ei, N_MOL, E_MOL, 256,
            mo_W0, mo_W1, mo_W2, mo_b0, mo_b1, mo_b2, mo_g0, mo_g1, mo_be0, mo_be1,
            cnt, dinv, bnsum, bnsq, stream);
    k_nanscan<<<2048, 256, 0, stream>>>(bufA, (long long)N_MOL * 128, flags, 4);
    hipMemsetAsync(mpool, 0, (size_t)BATCH * 128 * 4, stream);
    k_pool<<<(N_MOL * 32 + 255) / 256, 256, 0, stream>>>(bufA, mol_b, mpool);
    k_nanscan<<<512, 256, 0, stream>>>(mpool, (long long)BATCH * 128, flags, 5);

    // ---- head ----
    hipMemsetAsync(hstat, 0, 64 * 4, stream);
    k_conv1<<<BATCH, 64, 0, stream>>>(dfeat, mpool, sfeat, drug_idx, dis_idx, c1_W, c1_b, y1);
    k_nanscan<<<1024, 256, 0, stream>>>(y1, (long long)BATCH * 6 * 64, flags, 6);
    k_head_stats<<<dim3(6, BATCH / 16), 256, 0, stream>>>(y1, hstat, 0, 64);
    k_bn_fin<<<1, 8, 0, stream>>>(hstat, 0, 1.0f / (BATCH * 64.0f));
    k_nanscan<<<1, 64, 0, stream>>>(hstat, 32, flags, 7);
    k_conv2<<<BATCH, 64, 0, stream>>>(y1, hstat, c1_g, c1_be, c2_W, c2_b, y2);
    k_nanscan<<<512, 256, 0, stream>>>(y2, (long long)BATCH * 6 * 32, flags, 8);
    k_head_stats<<<dim3(6, BATCH / 16), 256, 0, stream>>>(y2, hstat, 1, 32);
    k_bn_fin<<<1, 8, 0, stream>>>(hstat, 1, 1.0f / (BATCH * 32.0f));
    k_nanscan<<<1, 64, 0, stream>>>(hstat + 32, 32, flags, 9);
    k_head<<<BATCH, 128, 0, stream>>>(y2, hstat, c2_g, c2_be, l1_W, l1_b, l2_W, l2_b, out);

    // diagnostics: overwrite out[0] with 100+10*stage of first non-finite buffer (no-op when clean)
    k_diag<<<1, 64, 0, stream>>>(flags, out);
}

// Round 4
// 1556.180 us; speedup vs baseline: 5.6987x; 5.6987x over previous
//
#include <hip/hip_runtime.h>
#include <hip/hip_bf16.h>

#define N_DRUG 20000
#define N_DIS  20000
#define E_G    320000
#define BATCH  4096
#define N_MOL  65536
#define E_MOL  262144
#define DIN    128
#define DH     256
#define DOUT   128
#define NF     9
#define NV     128

__device__ __forceinline__ void atomAddF(float* p, float v) { atomicAdd(p, v); }

// ---------------- misc ----------------
__global__ void k_sentinel(float* out, int n, float v) {
    int i = blockIdx.x * 256 + threadIdx.x;
    if (i < n) out[i] = v;
}

// ---------------- degree ----------------
__global__ void k_count(const int* __restrict__ dst, int* __restrict__ cnt, int E) {
    int e = blockIdx.x * 256 + threadIdx.x;
    if (e < E) atomicAdd(&cnt[dst[e]], 1);
}
__global__ void k_dinv(const int* __restrict__ cnt, float* __restrict__ dinv, int n) {
    int i = blockIdx.x * 256 + threadIdx.x;
    if (i < n) dinv[i] = rsqrtf(1.0f + (float)cnt[i]);
}

// ---------------- CSR build: exclusive scan of counts ----------------
__global__ void k_scan1(const int* __restrict__ cnt, int* __restrict__ rowStart,
                        int* __restrict__ bsum, int n) {
    __shared__ int sh[256];
    int i = blockIdx.x * 256 + threadIdx.x;
    int v = (i < n) ? cnt[i] : 0;
    sh[threadIdx.x] = v;
    __syncthreads();
    for (int off = 1; off < 256; off <<= 1) {
        int t = (threadIdx.x >= off) ? sh[threadIdx.x - off] : 0;
        __syncthreads();
        sh[threadIdx.x] += t;
        __syncthreads();
    }
    if (i < n) rowStart[i] = sh[threadIdx.x] - v;   // exclusive
    if (threadIdx.x == 255) bsum[blockIdx.x] = sh[255];
}
__global__ void k_scan2(int* __restrict__ bsum, int nb) {
    __shared__ int sh[256];
    int t = threadIdx.x;
    int v = (t < nb) ? bsum[t] : 0;
    sh[t] = v;
    __syncthreads();
    for (int off = 1; off < 256; off <<= 1) {
        int u = (t >= off) ? sh[t - off] : 0;
        __syncthreads();
        sh[t] += u;
        __syncthreads();
    }
    if (t < nb) bsum[t] = sh[t] - v;                 // exclusive
}
__global__ void k_scan3(int* __restrict__ rowStart, int* __restrict__ cursor,
                        const int* __restrict__ bsum, int n, int E) {
    int i = blockIdx.x * 256 + threadIdx.x;
    if (i < n) {
        int r = rowStart[i] + bsum[blockIdx.x];
        rowStart[i] = r;
        cursor[i] = r;
    }
    if (i == 0) rowStart[n] = E;
}
__global__ void k_fill(const int* __restrict__ src, const int* __restrict__ dst,
                       int* __restrict__ cursor, int* __restrict__ csr, int E) {
    int e = blockIdx.x * 256 + threadIdx.x;
    if (e < E) {
        int p = atomicAdd(&cursor[dst[e]], 1);
        csr[p] = src[e];
    }
}

// ---------------- GEMM: C[M,N] = A[M,K] @ B[K,N], all f32 ----------------
__global__ __launch_bounds__(256) void k_gemm(const float* __restrict__ A,
                                              const float* __restrict__ B,
                                              float* __restrict__ C, int M, int K, int N) {
    __shared__ float As[32][64];   // [k][m]
    __shared__ float Bs[32][64];   // [k][n]
    const int bm = blockIdx.y * 64;
    const int bn = blockIdx.x * 64;
    const int tid = threadIdx.x;
    const int tx = tid & 15;
    const int ty = tid >> 4;
    const int ra = tid >> 3;        // 0..31
    const int c4 = (tid & 7) * 4;   // A k-offset
    const int s8 = (tid & 7) * 8;   // B n-offset
    float acc[4][4];
#pragma unroll
    for (int i = 0; i < 4; ++i)
#pragma unroll
        for (int j = 0; j < 4; ++j) acc[i][j] = 0.f;

    for (int k0 = 0; k0 < K; k0 += 32) {
#pragma unroll
        for (int half = 0; half < 2; ++half) {
            int rr = ra + half * 32;
            int row = bm + rr;
            float4 v = make_float4(0.f, 0.f, 0.f, 0.f);
            if (row < M) v = *reinterpret_cast<const float4*>(A + (size_t)row * K + k0 + c4);
            As[c4 + 0][rr] = v.x; As[c4 + 1][rr] = v.y;
            As[c4 + 2][rr] = v.z; As[c4 + 3][rr] = v.w;
        }
        {
            size_t boff = (size_t)(k0 + ra) * N + bn + s8;
            float4 v0 = *reinterpret_cast<const float4*>(B + boff);
            float4 v1 = *reinterpret_cast<const float4*>(B + boff + 4);
            Bs[ra][s8 + 0] = v0.x; Bs[ra][s8 + 1] = v0.y;
            Bs[ra][s8 + 2] = v0.z; Bs[ra][s8 + 3] = v0.w;
            Bs[ra][s8 + 4] = v1.x; Bs[ra][s8 + 5] = v1.y;
            Bs[ra][s8 + 6] = v1.z; Bs[ra][s8 + 7] = v1.w;
        }
        __syncthreads();
#pragma unroll
        for (int kk = 0; kk < 32; ++kk) {
            const float4 av = *reinterpret_cast<const float4*>(&As[kk][ty << 2]);
            const float4 bv = *reinterpret_cast<const float4*>(&Bs[kk][tx << 2]);
            acc[0][0] += av.x * bv.x; acc[0][1] += av.x * bv.y; acc[0][2] += av.x * bv.z; acc[0][3] += av.x * bv.w;
            acc[1][0] += av.y * bv.x; acc[1][1] += av.y * bv.y; acc[1][2] += av.y * bv.z; acc[1][3] += av.y * bv.w;
            acc[2][0] += av.z * bv.x; acc[2][1] += av.z * bv.y; acc[2][2] += av.z * bv.z; acc[2][3] += av.z * bv.w;
            acc[3][0] += av.w * bv.x; acc[3][1] += av.w * bv.y; acc[3][2] += av.w * bv.z; acc[3][3] += av.w * bv.w;
        }
        __syncthreads();
    }
#pragma unroll
    for (int i = 0; i < 4; ++i) {
        int row = bm + (ty << 2) + i;
        if (row < M) {
            float* cp = C + (size_t)row * N + bn + (tx << 2);
            cp[0] = acc[i][0]; cp[1] = acc[i][1]; cp[2] = acc[i][2]; cp[3] = acc[i][3];
        }
    }
}

// ---------------- CSR gather aggregation (fused self-loop + bias) ----------------
// out[d,:] = h[d,:]*dinv[d]^2 + bias + sum_{s in N(d)} dinv[s]*dinv[d]*h[s,:]
// One 64-lane wave per row; 4 rows per 256-thread block.
__global__ __launch_bounds__(256) void k_gather4(const float* __restrict__ h,
                                                 const float* __restrict__ dinv,
                                                 const float* __restrict__ bias,
                                                 const int* __restrict__ csr,
                                                 const int* __restrict__ rowStart,
                                                 float* __restrict__ out, int n) {
    const int C = 256;
    int row = blockIdx.x * 4 + (threadIdx.x >> 6);
    if (row >= n) return;
    int lane = threadIdx.x & 63;
    float dd = dinv[row];
    float w0 = dd * dd;
    int beg = rowStart[row], end = rowStart[row + 1];
    const float4 hv = *reinterpret_cast<const float4*>(h + (size_t)row * C + lane * 4);
    const float4 bv = *reinterpret_cast<const float4*>(bias + lane * 4);
    float4 acc;
    acc.x = hv.x * w0 + bv.x; acc.y = hv.y * w0 + bv.y;
    acc.z = hv.z * w0 + bv.z; acc.w = hv.w * w0 + bv.w;
    for (int j = beg; j < end; ++j) {
        int s = csr[j];
        float w = dinv[s] * dd;
        const float4 sv = *reinterpret_cast<const float4*>(h + (size_t)s * C + lane * 4);
        acc.x += w * sv.x; acc.y += w * sv.y; acc.z += w * sv.z; acc.w += w * sv.w;
    }
    *reinterpret_cast<float4*>(out + (size_t)row * C + lane * 4) = acc;
}

__global__ __launch_bounds__(256) void k_gather2(const float* __restrict__ h,
                                                 const float* __restrict__ dinv,
                                                 const float* __restrict__ bias,
                                                 const int* __restrict__ csr,
                                                 const int* __restrict__ rowStart,
                                                 float* __restrict__ out, int n) {
    const int C = 128;
    int row = blockIdx.x * 4 + (threadIdx.x >> 6);
    if (row >= n) return;
    int lane = threadIdx.x & 63;
    float dd = dinv[row];
    float w0 = dd * dd;
    int beg = rowStart[row], end = rowStart[row + 1];
    const float2 hv = *reinterpret_cast<const float2*>(h + (size_t)row * C + lane * 2);
    const float2 bv = *reinterpret_cast<const float2*>(bias + lane * 2);
    float2 acc;
    acc.x = hv.x * w0 + bv.x; acc.y = hv.y * w0 + bv.y;
    for (int j = beg; j < end; ++j) {
        int s = csr[j];
        float w = dinv[s] * dd;
        const float2 sv = *reinterpret_cast<const float2*>(h + (size_t)s * C + lane * 2);
        acc.x += w * sv.x; acc.y += w * sv.y;
    }
    *reinterpret_cast<float2*>(out + (size_t)row * C + lane * 2) = acc;
}

// ---------------- BatchNorm ----------------
__global__ void k_bn_stats(const float* __restrict__ x, float* __restrict__ sum,
                           float* __restrict__ sq, int n, int C, int rpb) {
    int j = threadIdx.x;
    int r0 = blockIdx.x * rpb;
    int r1 = min(r0 + rpb, n);
    float s = 0.f, q = 0.f;
    for (int r = r0; r < r1; ++r) {
        float v = x[(size_t)r * C + j];
        s += v; q += v * v;
    }
    atomAddF(&sum[j], s);
    atomAddF(&sq[j], q);
}

__global__ void k_bn_apply(float* __restrict__ x, const float* __restrict__ sum,
                           const float* __restrict__ sq, const float* __restrict__ g,
                           const float* __restrict__ be, long long tot, int cshift, float invN) {
    long long idx = (long long)blockIdx.x * 256 + threadIdx.x;
    if (idx >= tot) return;
    int j = (int)idx & ((1 << cshift) - 1);
    float m = sum[j] * invN;
    float v = sq[j] * invN - m * m;
    float r = rsqrtf(fmaxf(v, 0.f) + 1e-5f);
    float y = g[j] * (x[idx] - m) * r + be[j];
    x[idx] = fmaxf(y, 0.f);
}

// ---------------- atom encoder ----------------
__global__ __launch_bounds__(256) void k_atom_enc(const int* __restrict__ mol_x,
                                                  const float* __restrict__ emb,
                                                  float* __restrict__ h) {
    __shared__ int idx[NF];
    int i = blockIdx.x;
    int j = threadIdx.x;
    if (j < NF) idx[j] = mol_x[i * NF + j];
    __syncthreads();
    float s = 0.f;
#pragma unroll
    for (int f = 0; f < NF; ++f)
        s += emb[((size_t)f * NV + idx[f]) * DH + j];
    h[(size_t)i * DH + j] = s;
}

// ---------------- segment pool (mol_batch sorted) ----------------
__global__ void k_bstart(const int* __restrict__ batch, int* __restrict__ bstart) {
    int b = blockIdx.x * 256 + threadIdx.x;
    if (b > BATCH) return;
    if (b == BATCH) { bstart[b] = N_MOL; return; }
    int lo = 0, hi = N_MOL;
    while (lo < hi) {
        int mid = (lo + hi) >> 1;
        if (batch[mid] < b) lo = mid + 1; else hi = mid;
    }
    bstart[b] = lo;
}
__global__ __launch_bounds__(128) void k_pool_seg(const float* __restrict__ mfeat,
                                                  const int* __restrict__ bstart,
                                                  float* __restrict__ mpool) {
    int b = blockIdx.x, t = threadIdx.x;   // 128 threads = channels
    float s = 0.f;
    int e = bstart[b + 1];
    for (int i = bstart[b]; i < e; ++i) s += mfeat[(size_t)i * 128 + t];
    mpool[(size_t)b * 128 + t] = s;
}

// ---------------- head: conv1 ----------------
__global__ __launch_bounds__(64) void k_conv1(const float* __restrict__ dfeat,
                                              const float* __restrict__ mpool,
                                              const float* __restrict__ sfeat,
                                              const int* __restrict__ drug_idx,
                                              const int* __restrict__ dis_idx,
                                              const float* __restrict__ W,
                                              const float* __restrict__ bias,
                                              float* __restrict__ y1) {
    __shared__ float xs[3][128];
    __shared__ float w[54];
    __shared__ float bb[6];
    int b = blockIdx.x, t = threadIdx.x;
    int di = drug_idx[b], si = dis_idx[b];
    const float* r0 = dfeat + (size_t)di * 128;
    const float* r1 = mpool + (size_t)b * 128;
    const float* r2 = sfeat + (size_t)si * 128;
    xs[0][t] = r0[t]; xs[0][t + 64] = r0[t + 64];
    xs[1][t] = r1[t]; xs[1][t + 64] = r1[t + 64];
    xs[2][t] = r2[t]; xs[2][t + 64] = r2[t + 64];
    if (t < 54) w[t] = W[t];
    if (t < 6) bb[t] = bias[t];
    __syncthreads();
    int l0 = 2 * t, l1 = l0 + 1;
#pragma unroll
    for (int o = 0; o < 6; ++o) {
        float ya = bb[o], yb = bb[o];
#pragma unroll
        for (int i = 0; i < 3; ++i) {
            const float* wi = &w[(o * 3 + i) * 3];
            float xm1 = (l0 > 0) ? xs[i][l0 - 1] : 0.f;
            float x0 = xs[i][l0];
            float x1 = xs[i][l1];
            float x2 = (l1 < 127) ? xs[i][l1 + 1] : 0.f;
            ya += wi[0] * xm1 + wi[1] * x0 + wi[2] * x1;
            yb += wi[0] * x0 + wi[1] * x1 + wi[2] * x2;
        }
        y1[((size_t)b * 6 + o) * 64 + t] = fmaxf(ya, yb);
    }
}

// hb layout per 'which' (32 floats): [0..5]=sum [8..13]=sumsq [16..21]=mean [24..29]=rstd
__global__ __launch_bounds__(256) void k_head_stats(const float* __restrict__ y,
                                                    float* __restrict__ hb, int which, int L) {
    int o = blockIdx.x;
    int b0 = blockIdx.y * 16;
    int t = threadIdx.x;
    float s = 0.f, q = 0.f;
    int per = 16 * L;
    for (int idx = t; idx < per; idx += 256) {
        int b = b0 + idx / L;
        int l = idx - (idx / L) * L;
        float v = y[((size_t)b * 6 + o) * L + l];
        s += v; q += v * v;
    }
    __shared__ float sms[4], smq[4];
#pragma unroll
    for (int off = 32; off > 0; off >>= 1) {
        s += __shfl_down(s, off);
        q += __shfl_down(q, off);
    }
    if ((t & 63) == 0) { sms[t >> 6] = s; smq[t >> 6] = q; }
    __syncthreads();
    if (t == 0) {
        float S = 0.f, Q = 0.f;
        for (int i = 0; i < 4; ++i) { S += sms[i]; Q += smq[i]; }
        atomAddF(hb + which * 32 + o, S);
        atomAddF(hb + which * 32 + 8 + o, Q);
    }
}

__global__ void k_bn_fin(float* __restrict__ hb, int which, float invN) {
    int o = threadIdx.x;
    if (o >= 6) return;
    float* p = hb + which * 32;
    float m = p[o] * invN;
    float v = p[8 + o] * invN - m * m;
    p[16 + o] = m;
    p[24 + o] = rsqrtf(fmaxf(v, 0.f) + 1e-5f);
}

// ---------------- head: conv2 ----------------
__global__ __launch_bounds__(64) void k_conv2(const float* __restrict__ y1,
                                              const float* __restrict__ hb,
                                              const float* __restrict__ g1,
                                              const float* __restrict__ be1,
                                              const float* __restrict__ W,
                                              const float* __restrict__ bias,
                                              float* __restrict__ y2) {
    __shared__ float xs[6][64];
    __shared__ float w[108];
    __shared__ float bb[6];
    int b = blockIdx.x, t = threadIdx.x;  // 64 threads; lower 32 compute
    const float* mean = hb + 16;
    const float* rstd = hb + 24;
    for (int idx = t; idx < 384; idx += 64) {
        int o = idx >> 6, l = idx & 63;
        float v = y1[((size_t)b * 6 + o) * 64 + l];
        v = g1[o] * (v - mean[o]) * rstd[o] + be1[o];
        xs[o][l] = fmaxf(v, 0.f);
    }
    for (int idx = t; idx < 108; idx += 64) w[idx] = W[idx];
    if (t < 6) bb[t] = bias[t];
    __syncthreads();
    if (t >= 32) return;
    int l0 = 2 * t, l1 = l0 + 1;
#pragma unroll
    for (int o = 0; o < 6; ++o) {
        float ya = bb[o], yb = bb[o];
#pragma unroll
        for (int i = 0; i < 6; ++i) {
            const float* wi = &w[(o * 6 + i) * 3];
            float xm1 = (l0 > 0) ? xs[i][l0 - 1] : 0.f;
            float x0 = xs[i][l0];
            float x1 = xs[i][l1];
            float x2 = (l1 < 63) ? xs[i][l1 + 1] : 0.f;
            ya += wi[0] * xm1 + wi[1] * x0 + wi[2] * x1;
            yb += wi[0] * x0 + wi[1] * x1 + wi[2] * x2;
        }
        y2[((size_t)b * 6 + o) * 32 + t] = fmaxf(ya, yb);
    }
}

// ---------------- head final ----------------
__global__ __launch_bounds__(128) void k_head(const float* __restrict__ y2,
                                              const float* __restrict__ hb,
                                              const float* __restrict__ g2,
                                              const float* __restrict__ be2,
                                              const float* __restrict__ l1W,
                                              const float* __restrict__ l1b,
                                              const float* __restrict__ l2W,
                                              const float* __restrict__ l2b,
                                              float* __restrict__ out) {
    __shared__ float fs[192];
    __shared__ float sm[2];
    int b = blockIdx.x, t = threadIdx.x;
    const float* mean = hb + 32 + 16;
    const float* rstd = hb + 32 + 24;
    for (int idx = t; idx < 192; idx += 128) {
        int o = idx >> 5, l = idx & 31;
        float v = y2[((size_t)b * 6 + o) * 32 + l];
        v = g2[o] * (v - mean[o]) * rstd[o] + be2[o];
        fs[idx] = fmaxf(v, 0.f);
    }
    __syncthreads();
    float h = l1b[t];
    for (int k = 0; k < 192; ++k)
        h += fs[k] * l1W[k * 128 + t];
    h = fmaxf(h, 0.f);
    float p = h * l2W[t];
#pragma unroll
    for (int off = 32; off > 0; off >>= 1) p += __shfl_down(p, off);
    if ((t & 63) == 0) sm[t >> 6] = p;
    __syncthreads();
    if (t == 0) out[b] = sm[0] + sm[1] + l2b[0];
}

// ---------------- host-side GCN driver ----------------
static void gcn_layer(const float* x, const float* W, const float* bias,
                      float* h, float* outp, int n, int K, int Cout,
                      const int* csr, const int* rowStart, const float* dinv,
                      bool do_bn, const float* g, const float* be,
                      float* bnsum, float* bnsq, hipStream_t stream) {
    dim3 gg(Cout / 64, (n + 63) / 64);
    k_gemm<<<gg, 256, 0, stream>>>(x, W, h, n, K, Cout);
    int gb = (n + 3) / 4;
    if (Cout == 256)
        k_gather4<<<gb, 256, 0, stream>>>(h, dinv, bias, csr, rowStart, outp, n);
    else
        k_gather2<<<gb, 256, 0, stream>>>(h, dinv, bias, csr, rowStart, outp, n);
    if (do_bn) {
        long long tot = (long long)n * Cout;
        int cshift = (Cout == 256) ? 8 : 7;
        hipMemsetAsync(bnsum, 0, 512 * sizeof(float), stream);
        k_bn_stats<<<(n + 127) / 128, Cout, 0, stream>>>(outp, bnsum, bnsq, n, Cout, 128);
        float invN = 1.0f / (float)n;
        k_bn_apply<<<(int)((tot + 255) / 256), 256, 0, stream>>>(outp, bnsum, bnsq, g, be, tot, cshift, invN);
    }
}

static void run_gcn(const float* x0, float* bufA, float* bufB, float* outF,
                    const int* ei, int n, int E, int inDim,
                    const float* W0, const float* W1, const float* W2,
                    const float* b0, const float* b1, const float* b2,
                    const float* g0, const float* g1, const float* be0, const float* be1,
                    int* cnt, float* dinv, int* rowStart, int* cursor, int* csr, int* bsum,
                    float* bnsum, float* bnsq, hipStream_t stream) {
    const int* src = ei;
    const int* dst = ei + E;
    // CSR build (once per graph, reused by all 3 layers)
    hipMemsetAsync(cnt, 0, (size_t)n * sizeof(int), stream);
    k_count<<<(E + 255) / 256, 256, 0, stream>>>(dst, cnt, E);
    k_dinv<<<(n + 255) / 256, 256, 0, stream>>>(cnt, dinv, n);
    int nb = (n + 255) / 256;
    k_scan1<<<nb, 256, 0, stream>>>(cnt, rowStart, bsum, n);
    k_scan2<<<1, 256, 0, stream>>>(bsum, nb);
    k_scan3<<<nb, 256, 0, stream>>>(rowStart, cursor, bsum, n, E);
    k_fill<<<(E + 255) / 256, 256, 0, stream>>>(src, dst, cursor, csr, E);

    gcn_layer(x0,   W0, b0, bufB, bufA, n, inDim, 256, csr, rowStart, dinv, true, g0, be0, bnsum, bnsq, stream);
    gcn_layer(bufA, W1, b1, bufB, bufA, n, 256, 256, csr, rowStart, dinv, true, g1, be1, bnsum, bnsq, stream);
    gcn_layer(bufA, W2, b2, bufB, outF, n, 256, 128, csr, rowStart, dinv, false, nullptr, nullptr, bnsum, bnsq, stream);
}

extern "C" void kernel_launch(void* const* d_in, const int* in_sizes, int n_in,
                              void* d_out, int out_size, void* d_ws, size_t ws_size,
                              hipStream_t stream) {
    float* out = (float*)d_out;
    if (n_in != 52) { k_sentinel<<<16, 256, 0, stream>>>(out, out_size, -111.f); return; }
    if (in_sizes[0] != N_DRUG * DIN || in_sizes[29] != NF * NV * DH || in_sizes[48] != 192 * 128) {
        k_sentinel<<<16, 256, 0, stream>>>(out, out_size, -222.f); return;
    }

    char* w = (char*)d_ws;
    auto alloc = [&](size_t bytes) { char* p = w; w += (bytes + 255) & ~(size_t)255; return p; };
    float* bufA  = (float*)alloc((size_t)N_MOL * 256 * 4);
    float* bufB  = (float*)alloc((size_t)N_MOL * 256 * 4);
    float* dfeat = (float*)alloc((size_t)N_DRUG * 128 * 4);
    float* sfeat = (float*)alloc((size_t)N_DIS * 128 * 4);
    float* mpool = (float*)alloc((size_t)BATCH * 128 * 4);
    int*   cnt   = (int*)alloc((size_t)N_MOL * 4);
    float* dinv  = (float*)alloc((size_t)N_MOL * 4);
    int*   rowStart = (int*)alloc((size_t)(N_MOL + 1) * 4);
    int*   cursor   = (int*)alloc((size_t)N_MOL * 4);
    int*   csr      = (int*)alloc((size_t)E_G * 4);       // max(E_G, E_MOL) = 320000
    int*   bsum     = (int*)alloc(512 * 4);
    int*   bstart   = (int*)alloc((size_t)(BATCH + 1) * 4);
    float* bnsum = (float*)alloc(512 * 4);
    float* bnsq  = bnsum + 256;
    float* hstat = (float*)alloc(64 * 4);
    float* y1    = (float*)alloc((size_t)BATCH * 6 * 64 * 4);
    float* y2    = (float*)alloc((size_t)BATCH * 6 * 32 * 4);
    if ((size_t)(w - (char*)d_ws) > ws_size) {
        k_sentinel<<<16, 256, 0, stream>>>(out, out_size, -333.f); return;
    }

    const float* drug_x  = (const float*)d_in[0];
    const int* drug_ei   = (const int*)d_in[1];
    const int* drug_idx  = (const int*)d_in[2];
    const float* dis_x   = (const float*)d_in[3];
    const int* dis_ei    = (const int*)d_in[4];
    const int* dis_idx   = (const int*)d_in[5];
    const int* mol_x     = (const int*)d_in[6];
    const int* mol_ei    = (const int*)d_in[7];
    const int* mol_b     = (const int*)d_in[8];
    const float *dr_W0 = (const float*)d_in[9], *dr_W1 = (const float*)d_in[10], *dr_W2 = (const float*)d_in[11];
    const float *dr_b0 = (const float*)d_in[12], *dr_b1 = (const float*)d_in[13], *dr_b2 = (const float*)d_in[14];
    const float *dr_g0 = (const float*)d_in[15], *dr_g1 = (const float*)d_in[16];
    const float *dr_be0 = (const float*)d_in[17], *dr_be1 = (const float*)d_in[18];
    const float *di_W0 = (const float*)d_in[19], *di_W1 = (const float*)d_in[20], *di_W2 = (const float*)d_in[21];
    const float *di_b0 = (const float*)d_in[22], *di_b1 = (const float*)d_in[23], *di_b2 = (const float*)d_in[24];
    const float *di_g0 = (const float*)d_in[25], *di_g1 = (const float*)d_in[26];
    const float *di_be0 = (const float*)d_in[27], *di_be1 = (const float*)d_in[28];
    const float* mol_emb = (const float*)d_in[29];
    const float *mo_W0 = (const float*)d_in[30], *mo_W1 = (const float*)d_in[31], *mo_W2 = (const float*)d_in[32];
    const float *mo_b0 = (const float*)d_in[33], *mo_b1 = (const float*)d_in[34], *mo_b2 = (const float*)d_in[35];
    const float *mo_g0 = (const float*)d_in[36], *mo_g1 = (const float*)d_in[37];
    const float *mo_be0 = (const float*)d_in[38], *mo_be1 = (const float*)d_in[39];
    const float *c1_W = (const float*)d_in[40], *c1_b = (const float*)d_in[41];
    const float *c1_g = (const float*)d_in[42], *c1_be = (const float*)d_in[43];
    const float *c2_W = (const float*)d_in[44], *c2_b = (const float*)d_in[45];
    const float *c2_g = (const float*)d_in[46], *c2_be = (const float*)d_in[47];
    const float *l1_W = (const float*)d_in[48], *l1_b = (const float*)d_in[49];
    const float *l2_W = (const float*)d_in[50], *l2_b = (const float*)d_in[51];

    // ---- drug GCN -> dfeat ----
    run_gcn(drug_x, bufA, bufB, dfeat, drug_ei, N_DRUG, E_G, DIN,
            dr_W0, dr_W1, dr_W2, dr_b0, dr_b1, dr_b2, dr_g0, dr_g1, dr_be0, dr_be1,
            cnt, dinv, rowStart, cursor, csr, bsum, bnsum, bnsq, stream);

    // ---- disease GCN -> sfeat ----
    run_gcn(dis_x, bufA, bufB, sfeat, dis_ei, N_DIS, E_G, DIN,
            di_W0, di_W1, di_W2, di_b0, di_b1, di_b2, di_g0, di_g1, di_be0, di_be1,
            cnt, dinv, rowStart, cursor, csr, bsum, bnsum, bnsq, stream);

    // ---- mol: atom encoder -> GCN -> pool ----
    k_atom_enc<<<N_MOL, 256, 0, stream>>>(mol_x, mol_emb, bufA);
    run_gcn(bufA, bufA, bufB, bufA, mol_ei, N_MOL, E_MOL, 256,
            mo_W0, mo_W1, mo_W2, mo_b0, mo_b1, mo_b2, mo_g0, mo_g1, mo_be0, mo_be1,
            cnt, dinv, rowStart, cursor, csr, bsum, bnsum, bnsq, stream);
    k_bstart<<<(BATCH + 256) / 256, 256, 0, stream>>>(mol_b, bstart);
    k_pool_seg<<<BATCH, 128, 0, stream>>>(bufA, bstart, mpool);

    // ---- head ----
    hipMemsetAsync(hstat, 0, 64 * 4, stream);
    k_conv1<<<BATCH, 64, 0, stream>>>(dfeat, mpool, sfeat, drug_idx, dis_idx, c1_W, c1_b, y1);
    k_head_stats<<<dim3(6, BATCH / 16), 256, 0, stream>>>(y1, hstat, 0, 64);
    k_bn_fin<<<1, 8, 0, stream>>>(hstat, 0, 1.0f / (BATCH * 64.0f));
    k_conv2<<<BATCH, 64, 0, stream>>>(y1, hstat, c1_g, c1_be, c2_W, c2_b, y2);
    k_head_stats<<<dim3(6, BATCH / 16), 256, 0, stream>>>(y2, hstat, 1, 32);
    k_bn_fin<<<1, 8, 0, stream>>>(hstat, 1, 1.0f / (BATCH * 32.0f));
    k_head<<<BATCH, 128, 0, stream>>>(y2, hstat, c2_g, c2_be, l1_W, l1_b, l2_W, l2_b, out);
}

// Round 5
// 1157.745 us; speedup vs baseline: 7.6598x; 1.3441x over previous
//
#include <hip/hip_runtime.h>
#include <hip/hip_bf16.h>

#define N_DRUG 20000
#define N_DIS  20000
#define E_G    320000
#define BATCH  4096
#define N_MOL  65536
#define E_MOL  262144
#define DIN    128
#define DH     256
#define DOUT   128
#define NF     9
#define NV     128

typedef short s16x8 __attribute__((ext_vector_type(8)));
typedef unsigned short u16x8 __attribute__((ext_vector_type(8)));
typedef float f32x4 __attribute__((ext_vector_type(4)));

__device__ __forceinline__ float bfu2f(unsigned short u) {
    return __uint_as_float(((unsigned int)u) << 16);
}
__device__ __forceinline__ unsigned short f2bfu(float f) {
    __hip_bfloat16 b = __float2bfloat16(f);
    return *reinterpret_cast<unsigned short*>(&b);
}
__device__ __forceinline__ void atomAddF(float* p, float v) { atomicAdd(p, v); }

// ---------------- misc ----------------
__global__ void k_sentinel(float* out, int n, float v) {
    int i = blockIdx.x * 256 + threadIdx.x;
    if (i < n) out[i] = v;
}

__global__ void k_cast_bf(const float* __restrict__ in, unsigned short* __restrict__ out, int n) {
    int i = blockIdx.x * 256 + threadIdx.x;
    if (i < n) out[i] = f2bfu(in[i]);
}

// W [K][N] f32 -> Wt [N][K] bf16
__global__ void k_wcastT(const float* __restrict__ W, unsigned short* __restrict__ Wt, int K, int N) {
    int i = blockIdx.x * 256 + threadIdx.x;
    if (i >= K * N) return;
    int k = i / N, c = i - k * N;
    Wt[(size_t)c * K + k] = f2bfu(W[i]);
}

// ---------------- degree ----------------
__global__ void k_count(const int* __restrict__ dst, int* __restrict__ cnt, int E) {
    int e = blockIdx.x * 256 + threadIdx.x;
    if (e < E) atomicAdd(&cnt[dst[e]], 1);
}
__global__ void k_dinv(const int* __restrict__ cnt, float* __restrict__ dinv, int n) {
    int i = blockIdx.x * 256 + threadIdx.x;
    if (i < n) dinv[i] = rsqrtf(1.0f + (float)cnt[i]);
}

// ---------------- CSR build ----------------
__global__ void k_scan1(const int* __restrict__ cnt, int* __restrict__ rowStart,
                        int* __restrict__ bsum, int n) {
    __shared__ int sh[256];
    int i = blockIdx.x * 256 + threadIdx.x;
    int v = (i < n) ? cnt[i] : 0;
    sh[threadIdx.x] = v;
    __syncthreads();
    for (int off = 1; off < 256; off <<= 1) {
        int t = (threadIdx.x >= off) ? sh[threadIdx.x - off] : 0;
        __syncthreads();
        sh[threadIdx.x] += t;
        __syncthreads();
    }
    if (i < n) rowStart[i] = sh[threadIdx.x] - v;
    if (threadIdx.x == 255) bsum[blockIdx.x] = sh[255];
}
__global__ void k_scan2(int* __restrict__ bsum, int nb) {
    __shared__ int sh[256];
    int t = threadIdx.x;
    int v = (t < nb) ? bsum[t] : 0;
    sh[t] = v;
    __syncthreads();
    for (int off = 1; off < 256; off <<= 1) {
        int u = (t >= off) ? sh[t - off] : 0;
        __syncthreads();
        sh[t] += u;
        __syncthreads();
    }
    if (t < nb) bsum[t] = sh[t] - v;
}
__global__ void k_scan3(int* __restrict__ rowStart, int* __restrict__ cursor,
                        const int* __restrict__ bsum, int n, int E) {
    int i = blockIdx.x * 256 + threadIdx.x;
    if (i < n) {
        int r = rowStart[i] + bsum[blockIdx.x];
        rowStart[i] = r;
        cursor[i] = r;
    }
    if (i == 0) rowStart[n] = E;
}
__global__ void k_fill(const int* __restrict__ src, const int* __restrict__ dst,
                       int* __restrict__ cursor, int* __restrict__ csr, int E) {
    int e = blockIdx.x * 256 + threadIdx.x;
    if (e < E) {
        int p = atomicAdd(&cursor[dst[e]], 1);
        csr[p] = src[e];
    }
}

// ---------------- MFMA GEMM: C[M,N] = A[M,K]bf16 @ B[K,N]bf16 (B given as Bt[N][K]) ----------------
// 128x128 tile, 256 threads (4 waves, 2x2 of 64x64), BK=32, mfma_f32_16x16x32_bf16.
// LDS chunk-major [kchunk][row][8] -> conflict-free ds_read_b128 fragment loads.
template<int STORE_BF16>
__global__ __launch_bounds__(256) void k_gemm_mfma(const unsigned short* __restrict__ A,
                                                   const unsigned short* __restrict__ Bt,
                                                   void* __restrict__ Cout,
                                                   int M, int K, int N) {
    __shared__ unsigned short Al[4][128][8];
    __shared__ unsigned short Bl[4][128][8];
    const int tid = threadIdx.x;
    const int bm = blockIdx.y * 128;
    const int bn = blockIdx.x * 128;
    const int w = tid >> 6, l = tid & 63;
    const int wrow = (w >> 1) * 64, wcol = (w & 1) * 64;
    const int kg = l >> 4, lr = l & 15;

    f32x4 acc[4][4];
#pragma unroll
    for (int fm = 0; fm < 4; ++fm)
#pragma unroll
        for (int fn = 0; fn < 4; ++fn) acc[fm][fn] = f32x4{0.f, 0.f, 0.f, 0.f};

    for (int k0 = 0; k0 < K; k0 += 32) {
#pragma unroll
        for (int c = 0; c < 2; ++c) {
            int idx = c * 256 + tid;        // 0..511
            int row = idx >> 2;             // 0..127
            int koff = idx & 3;             // 0..3
            u16x8 va = {0, 0, 0, 0, 0, 0, 0, 0};
            int grow = bm + row;
            if (grow < M)
                va = *reinterpret_cast<const u16x8*>(A + (size_t)grow * K + k0 + koff * 8);
            *reinterpret_cast<u16x8*>(&Al[koff][row][0]) = va;
            u16x8 vb = *reinterpret_cast<const u16x8*>(Bt + (size_t)(bn + row) * K + k0 + koff * 8);
            *reinterpret_cast<u16x8*>(&Bl[koff][row][0]) = vb;
        }
        __syncthreads();
        s16x8 a[4], b[4];
#pragma unroll
        for (int fm = 0; fm < 4; ++fm)
            a[fm] = *reinterpret_cast<const s16x8*>(&Al[kg][wrow + fm * 16 + lr][0]);
#pragma unroll
        for (int fn = 0; fn < 4; ++fn)
            b[fn] = *reinterpret_cast<const s16x8*>(&Bl[kg][wcol + fn * 16 + lr][0]);
#pragma unroll
        for (int fm = 0; fm < 4; ++fm)
#pragma unroll
            for (int fn = 0; fn < 4; ++fn)
                acc[fm][fn] = __builtin_amdgcn_mfma_f32_16x16x32_bf16(a[fm], b[fn], acc[fm][fn], 0, 0, 0);
        __syncthreads();
    }
    // C/D layout (m89-verified): col = lane&15, row = (lane>>4)*4 + reg
#pragma unroll
    for (int fm = 0; fm < 4; ++fm)
#pragma unroll
        for (int r = 0; r < 4; ++r) {
            int row = bm + wrow + fm * 16 + kg * 4 + r;
            if (row >= M) continue;
#pragma unroll
            for (int fn = 0; fn < 4; ++fn) {
                int col = bn + wcol + fn * 16 + lr;
                if (STORE_BF16)
                    ((unsigned short*)Cout)[(size_t)row * N + col] = f2bfu(acc[fm][fn][r]);
                else
                    ((float*)Cout)[(size_t)row * N + col] = acc[fm][fn][r];
            }
        }
}

// ---------------- CSR gather (bf16 in, f32 accum, f32/bf16 out, optional bias) ----------------
// out[d,:] = h[d,:]*dinv[d]^2 (+bias) + sum_{s in N(d)} dinv[s]*dinv[d]*h[s,:]
template<int C, int BIAS, int OUTBF>
__global__ __launch_bounds__(256) void k_gather_bf(const unsigned short* __restrict__ h,
                                                   const float* __restrict__ dinv,
                                                   const float* __restrict__ bias,
                                                   const int* __restrict__ csr,
                                                   const int* __restrict__ rowStart,
                                                   void* __restrict__ outv, int n) {
    constexpr int PL = C / 64;  // 4 (C=256) or 2 (C=128)
    int row = blockIdx.x * 4 + (threadIdx.x >> 6);
    if (row >= n) return;
    int lane = threadIdx.x & 63;
    int c0 = lane * PL;
    float dd = dinv[row], w0 = dd * dd;
    int beg = rowStart[row], end = rowStart[row + 1];
    float acc[PL];
    if constexpr (PL == 4) {
        ushort4 v = *reinterpret_cast<const ushort4*>(h + (size_t)row * C + c0);
        acc[0] = bfu2f(v.x) * w0; acc[1] = bfu2f(v.y) * w0;
        acc[2] = bfu2f(v.z) * w0; acc[3] = bfu2f(v.w) * w0;
    } else {
        ushort2 v = *reinterpret_cast<const ushort2*>(h + (size_t)row * C + c0);
        acc[0] = bfu2f(v.x) * w0; acc[1] = bfu2f(v.y) * w0;
    }
    for (int j = beg; j < end; ++j) {
        int s = csr[j];
        float w = dinv[s] * dd;
        if constexpr (PL == 4) {
            ushort4 v = *reinterpret_cast<const ushort4*>(h + (size_t)s * C + c0);
            acc[0] += w * bfu2f(v.x); acc[1] += w * bfu2f(v.y);
            acc[2] += w * bfu2f(v.z); acc[3] += w * bfu2f(v.w);
        } else {
            ushort2 v = *reinterpret_cast<const ushort2*>(h + (size_t)s * C + c0);
            acc[0] += w * bfu2f(v.x); acc[1] += w * bfu2f(v.y);
        }
    }
    if (BIAS) {
#pragma unroll
        for (int p = 0; p < PL; ++p) acc[p] += bias[c0 + p];
    }
    if constexpr (OUTBF) {
        unsigned short* o = (unsigned short*)outv + (size_t)row * C + c0;
        if constexpr (PL == 4) {
            ushort4 ov = {f2bfu(acc[0]), f2bfu(acc[1]), f2bfu(acc[2]), f2bfu(acc[3])};
            *reinterpret_cast<ushort4*>(o) = ov;
        } else {
            ushort2 ov = {f2bfu(acc[0]), f2bfu(acc[1])};
            *reinterpret_cast<ushort2*>(o) = ov;
        }
    } else {
        float* o = (float*)outv + (size_t)row * C + c0;
        if constexpr (PL == 4) {
            float4 ov = {acc[0], acc[1], acc[2], acc[3]};
            *reinterpret_cast<float4*>(o) = ov;
        } else {
            float2 ov = {acc[0], acc[1]};
            *reinterpret_cast<float2*>(o) = ov;
        }
    }
}

// ---------------- BatchNorm (stats on f32, apply writes bf16) ----------------
__global__ void k_bn_stats(const float* __restrict__ x, float* __restrict__ sum,
                           float* __restrict__ sq, int n, int C, int rpb) {
    int j = threadIdx.x;
    int r0 = blockIdx.x * rpb;
    int r1 = min(r0 + rpb, n);
    float s = 0.f, q = 0.f;
    for (int r = r0; r < r1; ++r) {
        float v = x[(size_t)r * C + j];
        s += v; q += v * v;
    }
    atomAddF(&sum[j], s);
    atomAddF(&sq[j], q);
}

__global__ void k_bn_apply_bf(const float* __restrict__ x, const float* __restrict__ sum,
                              const float* __restrict__ sq, const float* __restrict__ g,
                              const float* __restrict__ be, unsigned short* __restrict__ xout,
                              long long tot, float invN) {
    long long idx = (long long)blockIdx.x * 256 + threadIdx.x;
    if (idx >= tot) return;
    int j = (int)idx & 255;
    float m = sum[j] * invN;
    float v = sq[j] * invN - m * m;
    float r = rsqrtf(fmaxf(v, 0.f) + 1e-5f);
    float y = g[j] * (x[idx] - m) * r + be[j];
    xout[idx] = f2bfu(fmaxf(y, 0.f));
}

// ---------------- atom encoder (writes bf16) ----------------
__global__ __launch_bounds__(256) void k_atom_enc(const int* __restrict__ mol_x,
                                                  const float* __restrict__ emb,
                                                  unsigned short* __restrict__ h) {
    __shared__ int idx[NF];
    int i = blockIdx.x;
    int j = threadIdx.x;
    if (j < NF) idx[j] = mol_x[i * NF + j];
    __syncthreads();
    float s = 0.f;
#pragma unroll
    for (int f = 0; f < NF; ++f)
        s += emb[((size_t)f * NV + idx[f]) * DH + j];
    h[(size_t)i * DH + j] = f2bfu(s);
}

// ---------------- segment pool (mol_batch sorted) ----------------
__global__ void k_bstart(const int* __restrict__ batch, int* __restrict__ bstart) {
    int b = blockIdx.x * 256 + threadIdx.x;
    if (b > BATCH) return;
    if (b == BATCH) { bstart[b] = N_MOL; return; }
    int lo = 0, hi = N_MOL;
    while (lo < hi) {
        int mid = (lo + hi) >> 1;
        if (batch[mid] < b) lo = mid + 1; else hi = mid;
    }
    bstart[b] = lo;
}
__global__ __launch_bounds__(128) void k_pool_seg(const float* __restrict__ mfeat,
                                                  const int* __restrict__ bstart,
                                                  float* __restrict__ mpool) {
    int b = blockIdx.x, t = threadIdx.x;
    float s = 0.f;
    int e = bstart[b + 1];
    for (int i = bstart[b]; i < e; ++i) s += mfeat[(size_t)i * 128 + t];
    mpool[(size_t)b * 128 + t] = s;
}

// ---------------- head: conv1 ----------------
__global__ __launch_bounds__(64) void k_conv1(const float* __restrict__ dfeat,
                                              const float* __restrict__ mpool,
                                              const float* __restrict__ sfeat,
                                              const int* __restrict__ drug_idx,
                                              const int* __restrict__ dis_idx,
                                              const float* __restrict__ W,
                                              const float* __restrict__ bias,
                                              float* __restrict__ y1) {
    __shared__ float xs[3][128];
    __shared__ float w[54];
    __shared__ float bb[6];
    int b = blockIdx.x, t = threadIdx.x;
    int di = drug_idx[b], si = dis_idx[b];
    const float* r0 = dfeat + (size_t)di * 128;
    const float* r1 = mpool + (size_t)b * 128;
    const float* r2 = sfeat + (size_t)si * 128;
    xs[0][t] = r0[t]; xs[0][t + 64] = r0[t + 64];
    xs[1][t] = r1[t]; xs[1][t + 64] = r1[t + 64];
    xs[2][t] = r2[t]; xs[2][t + 64] = r2[t + 64];
    if (t < 54) w[t] = W[t];
    if (t < 6) bb[t] = bias[t];
    __syncthreads();
    int l0 = 2 * t, l1 = l0 + 1;
#pragma unroll
    for (int o = 0; o < 6; ++o) {
        float ya = bb[o], yb = bb[o];
#pragma unroll
        for (int i = 0; i < 3; ++i) {
            const float* wi = &w[(o * 3 + i) * 3];
            float xm1 = (l0 > 0) ? xs[i][l0 - 1] : 0.f;
            float x0 = xs[i][l0];
            float x1 = xs[i][l1];
            float x2 = (l1 < 127) ? xs[i][l1 + 1] : 0.f;
            ya += wi[0] * xm1 + wi[1] * x0 + wi[2] * x1;
            yb += wi[0] * x0 + wi[1] * x1 + wi[2] * x2;
        }
        y1[((size_t)b * 6 + o) * 64 + t] = fmaxf(ya, yb);
    }
}

// hb layout per 'which' (32 floats): [0..5]=sum [8..13]=sumsq [16..21]=mean [24..29]=rstd
__global__ __launch_bounds__(256) void k_head_stats(const float* __restrict__ y,
                                                    float* __restrict__ hb, int which, int L) {
    int o = blockIdx.x;
    int b0 = blockIdx.y * 16;
    int t = threadIdx.x;
    float s = 0.f, q = 0.f;
    int per = 16 * L;
    for (int idx = t; idx < per; idx += 256) {
        int b = b0 + idx / L;
        int l = idx - (idx / L) * L;
        float v = y[((size_t)b * 6 + o) * L + l];
        s += v; q += v * v;
    }
    __shared__ float sms[4], smq[4];
#pragma unroll
    for (int off = 32; off > 0; off >>= 1) {
        s += __shfl_down(s, off);
        q += __shfl_down(q, off);
    }
    if ((t & 63) == 0) { sms[t >> 6] = s; smq[t >> 6] = q; }
    __syncthreads();
    if (t == 0) {
        float S = 0.f, Q = 0.f;
        for (int i = 0; i < 4; ++i) { S += sms[i]; Q += smq[i]; }
        atomAddF(hb + which * 32 + o, S);
        atomAddF(hb + which * 32 + 8 + o, Q);
    }
}

__global__ void k_bn_fin(float* __restrict__ hb, int which, float invN) {
    int o = threadIdx.x;
    if (o >= 6) return;
    float* p = hb + which * 32;
    float m = p[o] * invN;
    float v = p[8 + o] * invN - m * m;
    p[16 + o] = m;
    p[24 + o] = rsqrtf(fmaxf(v, 0.f) + 1e-5f);
}

// ---------------- head: conv2 ----------------
__global__ __launch_bounds__(64) void k_conv2(const float* __restrict__ y1,
                                              const float* __restrict__ hb,
                                              const float* __restrict__ g1,
                                              const float* __restrict__ be1,
                                              const float* __restrict__ W,
                                              const float* __restrict__ bias,
                                              float* __restrict__ y2) {
    __shared__ float xs[6][64];
    __shared__ float w[108];
    __shared__ float bb[6];
    int b = blockIdx.x, t = threadIdx.x;
    const float* mean = hb + 16;
    const float* rstd = hb + 24;
    for (int idx = t; idx < 384; idx += 64) {
        int o = idx >> 6, l = idx & 63;
        float v = y1[((size_t)b * 6 + o) * 64 + l];
        v = g1[o] * (v - mean[o]) * rstd[o] + be1[o];
        xs[o][l] = fmaxf(v, 0.f);
    }
    for (int idx = t; idx < 108; idx += 64) w[idx] = W[idx];
    if (t < 6) bb[t] = bias[t];
    __syncthreads();
    if (t >= 32) return;
    int l0 = 2 * t, l1 = l0 + 1;
#pragma unroll
    for (int o = 0; o < 6; ++o) {
        float ya = bb[o], yb = bb[o];
#pragma unroll
        for (int i = 0; i < 6; ++i) {
            const float* wi = &w[(o * 6 + i) * 3];
            float xm1 = (l0 > 0) ? xs[i][l0 - 1] : 0.f;
            float x0 = xs[i][l0];
            float x1 = xs[i][l1];
            float x2 = (l1 < 63) ? xs[i][l1 + 1] : 0.f;
            ya += wi[0] * xm1 + wi[1] * x0 + wi[2] * x1;
            yb += wi[0] * x0 + wi[1] * x1 + wi[2] * x2;
        }
        y2[((size_t)b * 6 + o) * 32 + t] = fmaxf(ya, yb);
    }
}

// ---------------- head final ----------------
__global__ __launch_bounds__(128) void k_head(const float* __restrict__ y2,
                                              const float* __restrict__ hb,
                                              const float* __restrict__ g2,
                                              const float* __restrict__ be2,
                                              const float* __restrict__ l1W,
                                              const float* __restrict__ l1b,
                                              const float* __restrict__ l2W,
                                              const float* __restrict__ l2b,
                                              float* __restrict__ out) {
    __shared__ float fs[192];
    __shared__ float sm[2];
    int b = blockIdx.x, t = threadIdx.x;
    const float* mean = hb + 32 + 16;
    const float* rstd = hb + 32 + 24;
    for (int idx = t; idx < 192; idx += 128) {
        int o = idx >> 5, l = idx & 31;
        float v = y2[((size_t)b * 6 + o) * 32 + l];
        v = g2[o] * (v - mean[o]) * rstd[o] + be2[o];
        fs[idx] = fmaxf(v, 0.f);
    }
    __syncthreads();
    float h = l1b[t];
    for (int k = 0; k < 192; ++k)
        h += fs[k] * l1W[k * 128 + t];
    h = fmaxf(h, 0.f);
    float p = h * l2W[t];
#pragma unroll
    for (int off = 32; off > 0; off >>= 1) p += __shfl_down(p, off);
    if ((t & 63) == 0) sm[t >> 6] = p;
    __syncthreads();
    if (t == 0) out[b] = sm[0] + sm[1] + l2b[0];
}

// ---------------- host-side GCN driver ----------------
struct GcnScratch {
    int *cnt, *rowStart, *cursor, *csr, *bsum;
    float *dinv, *bnsum, *bnsq;
    unsigned short *wt0, *wt1, *wt2;
};

static void bn_pass(const float* out_f, unsigned short* xb, int n,
                    const float* g, const float* be, GcnScratch& S, hipStream_t stream) {
    long long tot = (long long)n * 256;
    hipMemsetAsync(S.bnsum, 0, 512 * sizeof(float), stream);
    k_bn_stats<<<(n + 127) / 128, 256, 0, stream>>>(out_f, S.bnsum, S.bnsq, n, 256, 128);
    k_bn_apply_bf<<<(int)((tot + 255) / 256), 256, 0, stream>>>(out_f, S.bnsum, S.bnsq, g, be, xb,
                                                                tot, 1.0f / (float)n);
}

// xin: bf16 [n][Cin]; outputs outF f32 [n][128]
static void run_gcn(const unsigned short* xin, int Cin,
                    float* out_f, unsigned short* xb, unsigned short* h_bf, float* outF,
                    const int* ei, int n, int E,
                    const float* W0, const float* W1, const float* W2, const float* b2,
                    const float* g0, const float* g1, const float* be0, const float* be1,
                    GcnScratch& S, hipStream_t stream) {
    const int* src = ei;
    const int* dst = ei + E;
    // CSR build (once per graph)
    hipMemsetAsync(S.cnt, 0, (size_t)n * sizeof(int), stream);
    k_count<<<(E + 255) / 256, 256, 0, stream>>>(dst, S.cnt, E);
    k_dinv<<<(n + 255) / 256, 256, 0, stream>>>(S.cnt, S.dinv, n);
    int nb = (n + 255) / 256;
    k_scan1<<<nb, 256, 0, stream>>>(S.cnt, S.rowStart, S.bsum, n);
    k_scan2<<<1, 256, 0, stream>>>(S.bsum, nb);
    k_scan3<<<nb, 256, 0, stream>>>(S.rowStart, S.cursor, S.bsum, n, E);
    k_fill<<<(E + 255) / 256, 256, 0, stream>>>(src, dst, S.cursor, S.csr, E);
    // weight transposes -> bf16
    k_wcastT<<<(Cin * 256 + 255) / 256, 256, 0, stream>>>(W0, S.wt0, Cin, 256);
    k_wcastT<<<(256 * 256 + 255) / 256, 256, 0, stream>>>(W1, S.wt1, 256, 256);
    k_wcastT<<<(256 * 128 + 255) / 256, 256, 0, stream>>>(W2, S.wt2, 256, 128);

    int gb = (n + 3) / 4;
    int gy = (n + 127) / 128;
    // L0: aggregate-first (S·X)·W0, bias dropped (cancelled by BN)
    if (Cin == 256)
        k_gather_bf<256, 0, 1><<<gb, 256, 0, stream>>>(xin, S.dinv, nullptr, S.csr, S.rowStart, xb, n);
    else
        k_gather_bf<128, 0, 1><<<gb, 256, 0, stream>>>(xin, S.dinv, nullptr, S.csr, S.rowStart, xb, n);
    k_gemm_mfma<0><<<dim3(2, gy), 256, 0, stream>>>(xb, S.wt0, out_f, n, Cin, 256);
    bn_pass(out_f, xb, n, g0, be0, S, stream);
    // L1: GEMM -> gather (bias dropped)
    k_gemm_mfma<1><<<dim3(2, gy), 256, 0, stream>>>(xb, S.wt1, h_bf, n, 256, 256);
    k_gather_bf<256, 0, 0><<<gb, 256, 0, stream>>>(h_bf, S.dinv, nullptr, S.csr, S.rowStart, out_f, n);
    bn_pass(out_f, xb, n, g1, be1, S, stream);
    // L2: GEMM -> gather + bias (no BN)
    k_gemm_mfma<1><<<dim3(1, gy), 256, 0, stream>>>(xb, S.wt2, h_bf, n, 256, 128);
    k_gather_bf<128, 1, 0><<<gb, 256, 0, stream>>>(h_bf, S.dinv, b2, S.csr, S.rowStart, outF, n);
}

extern "C" void kernel_launch(void* const* d_in, const int* in_sizes, int n_in,
                              void* d_out, int out_size, void* d_ws, size_t ws_size,
                              hipStream_t stream) {
    float* out = (float*)d_out;
    if (n_in != 52) { k_sentinel<<<16, 256, 0, stream>>>(out, out_size, -111.f); return; }
    if (in_sizes[0] != N_DRUG * DIN || in_sizes[29] != NF * NV * DH || in_sizes[48] != 192 * 128) {
        k_sentinel<<<16, 256, 0, stream>>>(out, out_size, -222.f); return;
    }

    char* w = (char*)d_ws;
    auto alloc = [&](size_t bytes) { char* p = w; w += (bytes + 255) & ~(size_t)255; return p; };
    unsigned short* xb   = (unsigned short*)alloc((size_t)N_MOL * 256 * 2);  // 33.5 MB
    unsigned short* h_bf = (unsigned short*)alloc((size_t)N_MOL * 256 * 2);  // 33.5 MB
    float* out_f = (float*)alloc((size_t)N_MOL * 256 * 4);                   // 67 MB (xin_bf aliases)
    unsigned short* xin_bf = (unsigned short*)out_f;  // alias: dead before out_f first written
    float* dfeat = (float*)alloc((size_t)N_DRUG * 128 * 4);
    float* sfeat = (float*)alloc((size_t)N_DIS * 128 * 4);
    float* mpool = (float*)alloc((size_t)BATCH * 128 * 4);
    GcnScratch S;
    S.cnt      = (int*)alloc((size_t)N_MOL * 4);
    S.dinv     = (float*)alloc((size_t)N_MOL * 4);
    S.rowStart = (int*)alloc((size_t)(N_MOL + 1) * 4);
    S.cursor   = (int*)alloc((size_t)N_MOL * 4);
    S.csr      = (int*)alloc((size_t)E_G * 4);
    S.bsum     = (int*)alloc(512 * 4);
    S.bnsum    = (float*)alloc(512 * 4);
    S.bnsq     = S.bnsum + 256;
    S.wt0      = (unsigned short*)alloc((size_t)256 * 256 * 2);
    S.wt1      = (unsigned short*)alloc((size_t)256 * 256 * 2);
    S.wt2      = (unsigned short*)alloc((size_t)256 * 256 * 2);
    int*   bstart = (int*)alloc((size_t)(BATCH + 1) * 4);
    float* hstat  = (float*)alloc(64 * 4);
    float* y1     = (float*)alloc((size_t)BATCH * 6 * 64 * 4);
    float* y2     = (float*)alloc((size_t)BATCH * 6 * 32 * 4);
    if ((size_t)(w - (char*)d_ws) > ws_size) {
        k_sentinel<<<16, 256, 0, stream>>>(out, out_size, -333.f); return;
    }

    const float* drug_x  = (const float*)d_in[0];
    const int* drug_ei   = (const int*)d_in[1];
    const int* drug_idx  = (const int*)d_in[2];
    const float* dis_x   = (const float*)d_in[3];
    const int* dis_ei    = (const int*)d_in[4];
    const int* dis_idx   = (const int*)d_in[5];
    const int* mol_x     = (const int*)d_in[6];
    const int* mol_ei    = (const int*)d_in[7];
    const int* mol_b     = (const int*)d_in[8];
    const float *dr_W0 = (const float*)d_in[9], *dr_W1 = (const float*)d_in[10], *dr_W2 = (const float*)d_in[11];
    const float *dr_b2 = (const float*)d_in[14];
    const float *dr_g0 = (const float*)d_in[15], *dr_g1 = (const float*)d_in[16];
    const float *dr_be0 = (const float*)d_in[17], *dr_be1 = (const float*)d_in[18];
    const float *di_W0 = (const float*)d_in[19], *di_W1 = (const float*)d_in[20], *di_W2 = (const float*)d_in[21];
    const float *di_b2 = (const float*)d_in[24];
    const float *di_g0 = (const float*)d_in[25], *di_g1 = (const float*)d_in[26];
    const float *di_be0 = (const float*)d_in[27], *di_be1 = (const float*)d_in[28];
    const float* mol_emb = (const float*)d_in[29];
    const float *mo_W0 = (const float*)d_in[30], *mo_W1 = (const float*)d_in[31], *mo_W2 = (const float*)d_in[32];
    const float *mo_b2 = (const float*)d_in[35];
    const float *mo_g0 = (const float*)d_in[36], *mo_g1 = (const float*)d_in[37];
    const float *mo_be0 = (const float*)d_in[38], *mo_be1 = (const float*)d_in[39];
    const float *c1_W = (const float*)d_in[40], *c1_b = (const float*)d_in[41];
    const float *c1_g = (const float*)d_in[42], *c1_be = (const float*)d_in[43];
    const float *c2_W = (const float*)d_in[44], *c2_b = (const float*)d_in[45];
    const float *c2_g = (const float*)d_in[46], *c2_be = (const float*)d_in[47];
    const float *l1_W = (const float*)d_in[48], *l1_b = (const float*)d_in[49];
    const float *l2_W = (const float*)d_in[50], *l2_b = (const float*)d_in[51];

    // ---- drug GCN -> dfeat ----
    k_cast_bf<<<(N_DRUG * DIN + 255) / 256, 256, 0, stream>>>(drug_x, xin_bf, N_DRUG * DIN);
    run_gcn(xin_bf, DIN, out_f, xb, h_bf, dfeat, drug_ei, N_DRUG, E_G,
            dr_W0, dr_W1, dr_W2, dr_b2, dr_g0, dr_g1, dr_be0, dr_be1, S, stream);

    // ---- disease GCN -> sfeat ----
    k_cast_bf<<<(N_DIS * DIN + 255) / 256, 256, 0, stream>>>(dis_x, xin_bf, N_DIS * DIN);
    run_gcn(xin_bf, DIN, out_f, xb, h_bf, sfeat, dis_ei, N_DIS, E_G,
            di_W0, di_W1, di_W2, di_b2, di_g0, di_g1, di_be0, di_be1, S, stream);

    // ---- mol: atom encoder -> GCN -> pool (mol outF lands in out_f) ----
    k_atom_enc<<<N_MOL, 256, 0, stream>>>(mol_x, mol_emb, xin_bf);
    run_gcn(xin_bf, 256, out_f, xb, h_bf, out_f, mol_ei, N_MOL, E_MOL,
            mo_W0, mo_W1, mo_W2, mo_b2, mo_g0, mo_g1, mo_be0, mo_be1, S, stream);
    k_bstart<<<(BATCH + 256) / 256, 256, 0, stream>>>(mol_b, bstart);
    k_pool_seg<<<BATCH, 128, 0, stream>>>(out_f, bstart, mpool);

    // ---- head ----
    hipMemsetAsync(hstat, 0, 64 * 4, stream);
    k_conv1<<<BATCH, 64, 0, stream>>>(dfeat, mpool, sfeat, drug_idx, dis_idx, c1_W, c1_b, y1);
    k_head_stats<<<dim3(6, BATCH / 16), 256, 0, stream>>>(y1, hstat, 0, 64);
    k_bn_fin<<<1, 8, 0, stream>>>(hstat, 0, 1.0f / (BATCH * 64.0f));
    k_conv2<<<BATCH, 64, 0, stream>>>(y1, hstat, c1_g, c1_be, c2_W, c2_b, y2);
    k_head_stats<<<dim3(6, BATCH / 16), 256, 0, stream>>>(y2, hstat, 1, 32);
    k_bn_fin<<<1, 8, 0, stream>>>(hstat, 1, 1.0f / (BATCH * 32.0f));
    k_head<<<BATCH, 128, 0, stream>>>(y2, hstat, c2_g, c2_be, l1_W, l1_b, l2_W, l2_b, out);
}

// Round 6
// 918.121 us; speedup vs baseline: 9.6590x; 1.2610x over previous
//
#include <hip/hip_runtime.h>
#include <hip/hip_bf16.h>

#define N_DRUG 20000
#define N_DIS  20000
#define E_G    320000
#define BATCH  4096
#define N_MOL  65536
#define E_MOL  262144
#define DIN    128
#define DH     256
#define DOUT   128
#define NF     9
#define NV     128

typedef short s16x8 __attribute__((ext_vector_type(8)));
typedef unsigned short u16x8 __attribute__((ext_vector_type(8)));
typedef float f32x4 __attribute__((ext_vector_type(4)));

__device__ __forceinline__ float bfu2f(unsigned short u) {
    return __uint_as_float(((unsigned int)u) << 16);
}
__device__ __forceinline__ unsigned short f2bfu(float f) {
    __hip_bfloat16 b = __float2bfloat16(f);
    return *reinterpret_cast<unsigned short*>(&b);
}
__device__ __forceinline__ void atomAddF(float* p, float v) { atomicAdd(p, v); }

// ---------------- misc ----------------
__global__ void k_sentinel(float* out, int n, float v) {
    int i = blockIdx.x * 256 + threadIdx.x;
    if (i < n) out[i] = v;
}

__global__ void k_cast_bf(const float* __restrict__ in, unsigned short* __restrict__ out, int n) {
    int i = blockIdx.x * 256 + threadIdx.x;
    if (i < n) out[i] = f2bfu(in[i]);
}

// W [K][N] f32 -> Wt [N][K] bf16
__global__ void k_wcastT(const float* __restrict__ W, unsigned short* __restrict__ Wt, int K, int N) {
    int i = blockIdx.x * 256 + threadIdx.x;
    if (i >= K * N) return;
    int k = i / N, c = i - k * N;
    Wt[(size_t)c * K + k] = f2bfu(W[i]);
}

// ---------------- degree ----------------
__global__ void k_count(const int* __restrict__ dst, int* __restrict__ cnt, int E) {
    int e = blockIdx.x * 256 + threadIdx.x;
    if (e < E) atomicAdd(&cnt[dst[e]], 1);
}
__global__ void k_dinv(const int* __restrict__ cnt, float* __restrict__ dinv, int n) {
    int i = blockIdx.x * 256 + threadIdx.x;
    if (i < n) dinv[i] = rsqrtf(1.0f + (float)cnt[i]);
}

// ---------------- CSR build ----------------
__global__ void k_scan1(const int* __restrict__ cnt, int* __restrict__ rowStart,
                        int* __restrict__ bsum, int n) {
    __shared__ int sh[256];
    int i = blockIdx.x * 256 + threadIdx.x;
    int v = (i < n) ? cnt[i] : 0;
    sh[threadIdx.x] = v;
    __syncthreads();
    for (int off = 1; off < 256; off <<= 1) {
        int t = (threadIdx.x >= off) ? sh[threadIdx.x - off] : 0;
        __syncthreads();
        sh[threadIdx.x] += t;
        __syncthreads();
    }
    if (i < n) rowStart[i] = sh[threadIdx.x] - v;
    if (threadIdx.x == 255) bsum[blockIdx.x] = sh[255];
}
__global__ void k_scan2(int* __restrict__ bsum, int nb) {
    __shared__ int sh[256];
    int t = threadIdx.x;
    int v = (t < nb) ? bsum[t] : 0;
    sh[t] = v;
    __syncthreads();
    for (int off = 1; off < 256; off <<= 1) {
        int u = (t >= off) ? sh[t - off] : 0;
        __syncthreads();
        sh[t] += u;
        __syncthreads();
    }
    if (t < nb) bsum[t] = sh[t] - v;
}
__global__ void k_scan3(int* __restrict__ rowStart, int* __restrict__ cursor,
                        const int* __restrict__ bsum, int n, int E) {
    int i = blockIdx.x * 256 + threadIdx.x;
    if (i < n) {
        int r = rowStart[i] + bsum[blockIdx.x];
        rowStart[i] = r;
        cursor[i] = r;
    }
    if (i == 0) rowStart[n] = E;
}
__global__ void k_fill(const int* __restrict__ src, const int* __restrict__ dst,
                       int* __restrict__ cursor, int* __restrict__ csr, int E) {
    int e = blockIdx.x * 256 + threadIdx.x;
    if (e < E) {
        int p = atomicAdd(&cursor[dst[e]], 1);
        csr[p] = src[e];
    }
}

// ---------------- MFMA GEMM: C[M,N]bf16 = act(A[M,K]bf16) @ B (given Bt[N][K]bf16) ----------------
// AFFINE: A' = relu(scale[k]*A + shift[k]) applied during staging (fused BatchNorm+ReLU).
// 128x128 tile, 4 waves (2x2 of 64x64), BK=32, mfma_f32_16x16x32_bf16.
template<int AFFINE>
__global__ __launch_bounds__(256) void k_gemm_mfma(const unsigned short* __restrict__ A,
                                                   const unsigned short* __restrict__ Bt,
                                                   const float* __restrict__ coef,   // scale[0..255], shift[256..511]
                                                   unsigned short* __restrict__ Cout,
                                                   int M, int K, int N) {
    __shared__ unsigned short Al[4][128][8];
    __shared__ unsigned short Bl[4][128][8];
    const int tid = threadIdx.x;
    const int bm = blockIdx.y * 128;
    const int bn = blockIdx.x * 128;
    const int w = tid >> 6, l = tid & 63;
    const int wrow = (w >> 1) * 64, wcol = (w & 1) * 64;
    const int kg = l >> 4, lr = l & 15;

    f32x4 acc[4][4];
#pragma unroll
    for (int fm = 0; fm < 4; ++fm)
#pragma unroll
        for (int fn = 0; fn < 4; ++fn) acc[fm][fn] = f32x4{0.f, 0.f, 0.f, 0.f};

    for (int k0 = 0; k0 < K; k0 += 32) {
#pragma unroll
        for (int c = 0; c < 2; ++c) {
            int idx = c * 256 + tid;        // 0..511
            int row = idx >> 2;             // 0..127
            int koff = idx & 3;             // 0..3
            u16x8 va = {0, 0, 0, 0, 0, 0, 0, 0};
            int grow = bm + row;
            if (grow < M)
                va = *reinterpret_cast<const u16x8*>(A + (size_t)grow * K + k0 + koff * 8);
            if (AFFINE) {
                int kb = k0 + koff * 8;
#pragma unroll
                for (int e = 0; e < 8; ++e) {
                    float f = bfu2f((unsigned short)va[e]);
                    f = fmaf(coef[kb + e], f, coef[256 + kb + e]);
                    va[e] = f2bfu(fmaxf(f, 0.f));
                }
            }
            *reinterpret_cast<u16x8*>(&Al[koff][row][0]) = va;
            u16x8 vb = *reinterpret_cast<const u16x8*>(Bt + (size_t)(bn + row) * K + k0 + koff * 8);
            *reinterpret_cast<u16x8*>(&Bl[koff][row][0]) = vb;
        }
        __syncthreads();
        s16x8 a[4], b[4];
#pragma unroll
        for (int fm = 0; fm < 4; ++fm)
            a[fm] = *reinterpret_cast<const s16x8*>(&Al[kg][wrow + fm * 16 + lr][0]);
#pragma unroll
        for (int fn = 0; fn < 4; ++fn)
            b[fn] = *reinterpret_cast<const s16x8*>(&Bl[kg][wcol + fn * 16 + lr][0]);
#pragma unroll
        for (int fm = 0; fm < 4; ++fm)
#pragma unroll
            for (int fn = 0; fn < 4; ++fn)
                acc[fm][fn] = __builtin_amdgcn_mfma_f32_16x16x32_bf16(a[fm], b[fn], acc[fm][fn], 0, 0, 0);
        __syncthreads();
    }
    // C/D layout: col = lane&15, row = (lane>>4)*4 + reg
#pragma unroll
    for (int fm = 0; fm < 4; ++fm)
#pragma unroll
        for (int r = 0; r < 4; ++r) {
            int row = bm + wrow + fm * 16 + kg * 4 + r;
            if (row >= M) continue;
#pragma unroll
            for (int fn = 0; fn < 4; ++fn) {
                int col = bn + wcol + fn * 16 + lr;
                Cout[(size_t)row * N + col] = f2bfu(acc[fm][fn][r]);
            }
        }
}

// ---------------- CSR gather (bf16 in, f32 accum, 4-deep MLP unroll) ----------------
// out[d,:] = h[d,:]*dinv[d]^2 (+bias) + sum_{s in N(d)} dinv[s]*dinv[d]*h[s,:]
template<int C, int BIAS, int OUTBF>
__global__ __launch_bounds__(256) void k_gather_bf(const unsigned short* __restrict__ h,
                                                   const float* __restrict__ dinv,
                                                   const float* __restrict__ bias,
                                                   const int* __restrict__ csr,
                                                   const int* __restrict__ rowStart,
                                                   void* __restrict__ outv, int n) {
    constexpr int PL = C / 64;  // 4 (C=256) or 2 (C=128)
    int row = blockIdx.x * 4 + (threadIdx.x >> 6);
    if (row >= n) return;
    int lane = threadIdx.x & 63;
    int c0 = lane * PL;
    float dd = dinv[row], ws = dd * dd;
    int beg = rowStart[row], end = rowStart[row + 1];
    float a0[PL], a1[PL], a2[PL], a3[PL];
#pragma unroll
    for (int p = 0; p < PL; ++p) { a1[p] = 0.f; a2[p] = 0.f; a3[p] = 0.f; }
    if constexpr (PL == 4) {
        ushort4 v = *reinterpret_cast<const ushort4*>(h + (size_t)row * C + c0);
        a0[0] = bfu2f(v.x) * ws; a0[1] = bfu2f(v.y) * ws;
        a0[2] = bfu2f(v.z) * ws; a0[3] = bfu2f(v.w) * ws;
    } else {
        ushort2 v = *reinterpret_cast<const ushort2*>(h + (size_t)row * C + c0);
        a0[0] = bfu2f(v.x) * ws; a0[1] = bfu2f(v.y) * ws;
    }
    int j = beg;
    for (; j + 4 <= end; j += 4) {
        int s0 = csr[j], s1 = csr[j + 1], s2 = csr[j + 2], s3 = csr[j + 3];
        float w0 = dinv[s0] * dd, w1 = dinv[s1] * dd, w2 = dinv[s2] * dd, w3 = dinv[s3] * dd;
        if constexpr (PL == 4) {
            ushort4 v0 = *reinterpret_cast<const ushort4*>(h + (size_t)s0 * C + c0);
            ushort4 v1 = *reinterpret_cast<const ushort4*>(h + (size_t)s1 * C + c0);
            ushort4 v2 = *reinterpret_cast<const ushort4*>(h + (size_t)s2 * C + c0);
            ushort4 v3 = *reinterpret_cast<const ushort4*>(h + (size_t)s3 * C + c0);
            a0[0] += w0 * bfu2f(v0.x); a0[1] += w0 * bfu2f(v0.y); a0[2] += w0 * bfu2f(v0.z); a0[3] += w0 * bfu2f(v0.w);
            a1[0] += w1 * bfu2f(v1.x); a1[1] += w1 * bfu2f(v1.y); a1[2] += w1 * bfu2f(v1.z); a1[3] += w1 * bfu2f(v1.w);
            a2[0] += w2 * bfu2f(v2.x); a2[1] += w2 * bfu2f(v2.y); a2[2] += w2 * bfu2f(v2.z); a2[3] += w2 * bfu2f(v2.w);
            a3[0] += w3 * bfu2f(v3.x); a3[1] += w3 * bfu2f(v3.y); a3[2] += w3 * bfu2f(v3.z); a3[3] += w3 * bfu2f(v3.w);
        } else {
            ushort2 v0 = *reinterpret_cast<const ushort2*>(h + (size_t)s0 * C + c0);
            ushort2 v1 = *reinterpret_cast<const ushort2*>(h + (size_t)s1 * C + c0);
            ushort2 v2 = *reinterpret_cast<const ushort2*>(h + (size_t)s2 * C + c0);
            ushort2 v3 = *reinterpret_cast<const ushort2*>(h + (size_t)s3 * C + c0);
            a0[0] += w0 * bfu2f(v0.x); a0[1] += w0 * bfu2f(v0.y);
            a1[0] += w1 * bfu2f(v1.x); a1[1] += w1 * bfu2f(v1.y);
            a2[0] += w2 * bfu2f(v2.x); a2[1] += w2 * bfu2f(v2.y);
            a3[0] += w3 * bfu2f(v3.x); a3[1] += w3 * bfu2f(v3.y);
        }
    }
    for (; j < end; ++j) {
        int s = csr[j];
        float w = dinv[s] * dd;
        if constexpr (PL == 4) {
            ushort4 v = *reinterpret_cast<const ushort4*>(h + (size_t)s * C + c0);
            a0[0] += w * bfu2f(v.x); a0[1] += w * bfu2f(v.y);
            a0[2] += w * bfu2f(v.z); a0[3] += w * bfu2f(v.w);
        } else {
            ushort2 v = *reinterpret_cast<const ushort2*>(h + (size_t)s * C + c0);
            a0[0] += w * bfu2f(v.x); a0[1] += w * bfu2f(v.y);
        }
    }
#pragma unroll
    for (int p = 0; p < PL; ++p) {
        a0[p] += (a1[p] + a2[p]) + a3[p];
        if (BIAS) a0[p] += bias[c0 + p];
    }
    if constexpr (OUTBF) {
        unsigned short* o = (unsigned short*)outv + (size_t)row * C + c0;
        if constexpr (PL == 4) {
            ushort4 ov = {f2bfu(a0[0]), f2bfu(a0[1]), f2bfu(a0[2]), f2bfu(a0[3])};
            *reinterpret_cast<ushort4*>(o) = ov;
        } else {
            ushort2 ov = {f2bfu(a0[0]), f2bfu(a0[1])};
            *reinterpret_cast<ushort2*>(o) = ov;
        }
    } else {
        float* o = (float*)outv + (size_t)row * C + c0;
        if constexpr (PL == 4) {
            float4 ov = {a0[0], a0[1], a0[2], a0[3]};
            *reinterpret_cast<float4*>(o) = ov;
        } else {
            float2 ov = {a0[0], a0[1]};
            *reinterpret_cast<float2*>(o) = ov;
        }
    }
}

// ---------------- BatchNorm stats (bf16 input) + coef ----------------
__global__ void k_bn_stats_bf(const unsigned short* __restrict__ x, float* __restrict__ sum,
                              float* __restrict__ sq, int n, int rpb) {
    int j = threadIdx.x;   // 256 cols
    int r0 = blockIdx.x * rpb;
    int r1 = min(r0 + rpb, n);
    float s = 0.f, q = 0.f;
    for (int r = r0; r < r1; ++r) {
        float v = bfu2f(x[(size_t)r * 256 + j]);
        s += v; q += v * v;
    }
    atomAddF(&sum[j], s);
    atomAddF(&sq[j], q);
}

// coef[j]=g*rstd (scale), coef[256+j]=be-mean*scale (shift)
__global__ void k_bn_coef(const float* __restrict__ sum, const float* __restrict__ sq,
                          const float* __restrict__ g, const float* __restrict__ be,
                          float* __restrict__ coef, float invN) {
    int j = threadIdx.x;
    float m = sum[j] * invN;
    float v = sq[j] * invN - m * m;
    float r = rsqrtf(fmaxf(v, 0.f) + 1e-5f);
    float sc = g[j] * r;
    coef[j] = sc;
    coef[256 + j] = be[j] - m * sc;
}

// ---------------- atom encoder (writes bf16) ----------------
__global__ __launch_bounds__(256) void k_atom_enc(const int* __restrict__ mol_x,
                                                  const float* __restrict__ emb,
                                                  unsigned short* __restrict__ h) {
    __shared__ int idx[NF];
    int i = blockIdx.x;
    int j = threadIdx.x;
    if (j < NF) idx[j] = mol_x[i * NF + j];
    __syncthreads();
    float s = 0.f;
#pragma unroll
    for (int f = 0; f < NF; ++f)
        s += emb[((size_t)f * NV + idx[f]) * DH + j];
    h[(size_t)i * DH + j] = f2bfu(s);
}

// ---------------- segment pool (mol_batch sorted) ----------------
__global__ void k_bstart(const int* __restrict__ batch, int* __restrict__ bstart) {
    int b = blockIdx.x * 256 + threadIdx.x;
    if (b > BATCH) return;
    if (b == BATCH) { bstart[b] = N_MOL; return; }
    int lo = 0, hi = N_MOL;
    while (lo < hi) {
        int mid = (lo + hi) >> 1;
        if (batch[mid] < b) lo = mid + 1; else hi = mid;
    }
    bstart[b] = lo;
}
__global__ __launch_bounds__(128) void k_pool_seg(const float* __restrict__ mfeat,
                                                  const int* __restrict__ bstart,
                                                  float* __restrict__ mpool) {
    int b = blockIdx.x, t = threadIdx.x;
    float s = 0.f;
    int e = bstart[b + 1];
    for (int i = bstart[b]; i < e; ++i) s += mfeat[(size_t)i * 128 + t];
    mpool[(size_t)b * 128 + t] = s;
}

// ---------------- head: conv1 ----------------
__global__ __launch_bounds__(64) void k_conv1(const float* __restrict__ dfeat,
                                              const float* __restrict__ mpool,
                                              const float* __restrict__ sfeat,
                                              const int* __restrict__ drug_idx,
                                              const int* __restrict__ dis_idx,
                                              const float* __restrict__ W,
                                              const float* __restrict__ bias,
                                              float* __restrict__ y1) {
    __shared__ float xs[3][128];
    __shared__ float w[54];
    __shared__ float bb[6];
    int b = blockIdx.x, t = threadIdx.x;
    int di = drug_idx[b], si = dis_idx[b];
    const float* r0 = dfeat + (size_t)di * 128;
    const float* r1 = mpool + (size_t)b * 128;
    const float* r2 = sfeat + (size_t)si * 128;
    xs[0][t] = r0[t]; xs[0][t + 64] = r0[t + 64];
    xs[1][t] = r1[t]; xs[1][t + 64] = r1[t + 64];
    xs[2][t] = r2[t]; xs[2][t + 64] = r2[t + 64];
    if (t < 54) w[t] = W[t];
    if (t < 6) bb[t] = bias[t];
    __syncthreads();
    int l0 = 2 * t, l1 = l0 + 1;
#pragma unroll
    for (int o = 0; o < 6; ++o) {
        float ya = bb[o], yb = bb[o];
#pragma unroll
        for (int i = 0; i < 3; ++i) {
            const float* wi = &w[(o * 3 + i) * 3];
            float xm1 = (l0 > 0) ? xs[i][l0 - 1] : 0.f;
            float x0 = xs[i][l0];
            float x1 = xs[i][l1];
            float x2 = (l1 < 127) ? xs[i][l1 + 1] : 0.f;
            ya += wi[0] * xm1 + wi[1] * x0 + wi[2] * x1;
            yb += wi[0] * x0 + wi[1] * x1 + wi[2] * x2;
        }
        y1[((size_t)b * 6 + o) * 64 + t] = fmaxf(ya, yb);
    }
}

// hb layout per 'which' (32 floats): [0..5]=sum [8..13]=sumsq [16..21]=mean [24..29]=rstd
__global__ __launch_bounds__(256) void k_head_stats(const float* __restrict__ y,
                                                    float* __restrict__ hb, int which, int L) {
    int o = blockIdx.x;
    int b0 = blockIdx.y * 16;
    int t = threadIdx.x;
    float s = 0.f, q = 0.f;
    int per = 16 * L;
    for (int idx = t; idx < per; idx += 256) {
        int b = b0 + idx / L;
        int l = idx - (idx / L) * L;
        float v = y[((size_t)b * 6 + o) * L + l];
        s += v; q += v * v;
    }
    __shared__ float sms[4], smq[4];
#pragma unroll
    for (int off = 32; off > 0; off >>= 1) {
        s += __shfl_down(s, off);
        q += __shfl_down(q, off);
    }
    if ((t & 63) == 0) { sms[t >> 6] = s; smq[t >> 6] = q; }
    __syncthreads();
    if (t == 0) {
        float S = 0.f, Q = 0.f;
        for (int i = 0; i < 4; ++i) { S += sms[i]; Q += smq[i]; }
        atomAddF(hb + which * 32 + o, S);
        atomAddF(hb + which * 32 + 8 + o, Q);
    }
}

__global__ void k_bn_fin(float* __restrict__ hb, int which, float invN) {
    int o = threadIdx.x;
    if (o >= 6) return;
    float* p = hb + which * 32;
    float m = p[o] * invN;
    float v = p[8 + o] * invN - m * m;
    p[16 + o] = m;
    p[24 + o] = rsqrtf(fmaxf(v, 0.f) + 1e-5f);
}

// ---------------- head: conv2 ----------------
__global__ __launch_bounds__(64) void k_conv2(const float* __restrict__ y1,
                                              const float* __restrict__ hb,
                                              const float* __restrict__ g1,
                                              const float* __restrict__ be1,
                                              const float* __restrict__ W,
                                              const float* __restrict__ bias,
                                              float* __restrict__ y2) {
    __shared__ float xs[6][64];
    __shared__ float w[108];
    __shared__ float bb[6];
    int b = blockIdx.x, t = threadIdx.x;
    const float* mean = hb + 16;
    const float* rstd = hb + 24;
    for (int idx = t; idx < 384; idx += 64) {
        int o = idx >> 6, l = idx & 63;
        float v = y1[((size_t)b * 6 + o) * 64 + l];
        v = g1[o] * (v - mean[o]) * rstd[o] + be1[o];
        xs[o][l] = fmaxf(v, 0.f);
    }
    for (int idx = t; idx < 108; idx += 64) w[idx] = W[idx];
    if (t < 6) bb[t] = bias[t];
    __syncthreads();
    if (t >= 32) return;
    int l0 = 2 * t, l1 = l0 + 1;
#pragma unroll
    for (int o = 0; o < 6; ++o) {
        float ya = bb[o], yb = bb[o];
#pragma unroll
        for (int i = 0; i < 6; ++i) {
            const float* wi = &w[(o * 6 + i) * 3];
            float xm1 = (l0 > 0) ? xs[i][l0 - 1] : 0.f;
            float x0 = xs[i][l0];
            float x1 = xs[i][l1];
            float x2 = (l1 < 63) ? xs[i][l1 + 1] : 0.f;
            ya += wi[0] * xm1 + wi[1] * x0 + wi[2] * x1;
            yb += wi[0] * x0 + wi[1] * x1 + wi[2] * x2;
        }
        y2[((size_t)b * 6 + o) * 32 + t] = fmaxf(ya, yb);
    }
}

// ---------------- head final ----------------
__global__ __launch_bounds__(128) void k_head(const float* __restrict__ y2,
                                              const float* __restrict__ hb,
                                              const float* __restrict__ g2,
                                              const float* __restrict__ be2,
                                              const float* __restrict__ l1W,
                                              const float* __restrict__ l1b,
                                              const float* __restrict__ l2W,
                                              const float* __restrict__ l2b,
                                              float* __restrict__ out) {
    __shared__ float fs[192];
    __shared__ float sm[2];
    int b = blockIdx.x, t = threadIdx.x;
    const float* mean = hb + 32 + 16;
    const float* rstd = hb + 32 + 24;
    for (int idx = t; idx < 192; idx += 128) {
        int o = idx >> 5, l = idx & 31;
        float v = y2[((size_t)b * 6 + o) * 32 + l];
        v = g2[o] * (v - mean[o]) * rstd[o] + be2[o];
        fs[idx] = fmaxf(v, 0.f);
    }
    __syncthreads();
    float h = l1b[t];
    for (int k = 0; k < 192; ++k)
        h += fs[k] * l1W[k * 128 + t];
    h = fmaxf(h, 0.f);
    float p = h * l2W[t];
#pragma unroll
    for (int off = 32; off > 0; off >>= 1) p += __shfl_down(p, off);
    if ((t & 63) == 0) sm[t >> 6] = p;
    __syncthreads();
    if (t == 0) out[b] = sm[0] + sm[1] + l2b[0];
}

// ---------------- host-side GCN driver ----------------
struct GcnScratch {
    int *cnt, *rowStart, *cursor, *csr, *bsum;
    float *dinv, *bnsum, *bnsq, *coef;
    unsigned short *wt0, *wt1, *wt2;
};

// xin: bf16 [n][Cin]. Flow: gather0 -> GEMM0 -> stats/coef -> GEMM1(affine) -> gather1
//      -> stats/coef -> GEMM2(affine) -> gather2(+bias) -> outF f32 [n][128]
static void run_gcn(const unsigned short* xin, int Cin,
                    unsigned short* xb, unsigned short* h_bf, float* outF,
                    const int* ei, int n, int E,
                    const float* W0, const float* W1, const float* W2, const float* b2,
                    const float* g0, const float* g1, const float* be0, const float* be1,
                    GcnScratch& S, hipStream_t stream) {
    const int* src = ei;
    const int* dst = ei + E;
    // CSR build (once per graph)
    hipMemsetAsync(S.cnt, 0, (size_t)n * sizeof(int), stream);
    k_count<<<(E + 255) / 256, 256, 0, stream>>>(dst, S.cnt, E);
    k_dinv<<<(n + 255) / 256, 256, 0, stream>>>(S.cnt, S.dinv, n);
    int nb = (n + 255) / 256;
    k_scan1<<<nb, 256, 0, stream>>>(S.cnt, S.rowStart, S.bsum, n);
    k_scan2<<<1, 256, 0, stream>>>(S.bsum, nb);
    k_scan3<<<nb, 256, 0, stream>>>(S.rowStart, S.cursor, S.bsum, n, E);
    k_fill<<<(E + 255) / 256, 256, 0, stream>>>(src, dst, S.cursor, S.csr, E);
    // weight transposes -> bf16
    k_wcastT<<<(Cin * 256 + 255) / 256, 256, 0, stream>>>(W0, S.wt0, Cin, 256);
    k_wcastT<<<(256 * 256 + 255) / 256, 256, 0, stream>>>(W1, S.wt1, 256, 256);
    k_wcastT<<<(256 * 128 + 255) / 256, 256, 0, stream>>>(W2, S.wt2, 256, 128);

    int gb = (n + 3) / 4;
    int gy = (n + 127) / 128;
    float invN = 1.0f / (float)n;
    int sb = (n + 127) / 128;
    // L0: aggregate-first (S·X)·W0 (bias dropped: cancelled by BN)
    if (Cin == 256)
        k_gather_bf<256, 0, 1><<<gb, 256, 0, stream>>>(xin, S.dinv, nullptr, S.csr, S.rowStart, xb, n);
    else
        k_gather_bf<128, 0, 1><<<gb, 256, 0, stream>>>(xin, S.dinv, nullptr, S.csr, S.rowStart, xb, n);
    k_gemm_mfma<0><<<dim3(2, gy), 256, 0, stream>>>(xb, S.wt0, nullptr, h_bf, n, Cin, 256);
    hipMemsetAsync(S.bnsum, 0, 512 * sizeof(float), stream);
    k_bn_stats_bf<<<sb, 256, 0, stream>>>(h_bf, S.bnsum, S.bnsq, n, 128);
    k_bn_coef<<<1, 256, 0, stream>>>(S.bnsum, S.bnsq, g0, be0, S.coef, invN);
    // L1: GEMM(BN0+relu fused on A) -> gather (bias dropped)
    k_gemm_mfma<1><<<dim3(2, gy), 256, 0, stream>>>(h_bf, S.wt1, S.coef, xb, n, 256, 256);
    k_gather_bf<256, 0, 1><<<gb, 256, 0, stream>>>(xb, S.dinv, nullptr, S.csr, S.rowStart, h_bf, n);
    hipMemsetAsync(S.bnsum, 0, 512 * sizeof(float), stream);
    k_bn_stats_bf<<<sb, 256, 0, stream>>>(h_bf, S.bnsum, S.bnsq, n, 128);
    k_bn_coef<<<1, 256, 0, stream>>>(S.bnsum, S.bnsq, g1, be1, S.coef, invN);
    // L2: GEMM(BN1+relu fused on A) -> gather + bias (no BN)
    k_gemm_mfma<1><<<dim3(1, gy), 256, 0, stream>>>(h_bf, S.wt2, S.coef, xb, n, 256, 128);
    k_gather_bf<128, 1, 0><<<gb, 256, 0, stream>>>(xb, S.dinv, b2, S.csr, S.rowStart, outF, n);
}

extern "C" void kernel_launch(void* const* d_in, const int* in_sizes, int n_in,
                              void* d_out, int out_size, void* d_ws, size_t ws_size,
                              hipStream_t stream) {
    float* out = (float*)d_out;
    if (n_in != 52) { k_sentinel<<<16, 256, 0, stream>>>(out, out_size, -111.f); return; }
    if (in_sizes[0] != N_DRUG * DIN || in_sizes[29] != NF * NV * DH || in_sizes[48] != 192 * 128) {
        k_sentinel<<<16, 256, 0, stream>>>(out, out_size, -222.f); return;
    }

    char* w = (char*)d_ws;
    auto alloc = [&](size_t bytes) { char* p = w; w += (bytes + 255) & ~(size_t)255; return p; };
    unsigned short* xb   = (unsigned short*)alloc((size_t)N_MOL * 256 * 2);
    unsigned short* h_bf = (unsigned short*)alloc((size_t)N_MOL * 256 * 2);
    float* out_f = (float*)alloc((size_t)N_MOL * 256 * 4);
    unsigned short* xin_bf = (unsigned short*)out_f;  // alias: xin dead before out_f written
    float* dfeat = (float*)alloc((size_t)N_DRUG * 128 * 4);
    float* sfeat = (float*)alloc((size_t)N_DIS * 128 * 4);
    float* mpool = (float*)alloc((size_t)BATCH * 128 * 4);
    GcnScratch S;
    S.cnt      = (int*)alloc((size_t)N_MOL * 4);
    S.dinv     = (float*)alloc((size_t)N_MOL * 4);
    S.rowStart = (int*)alloc((size_t)(N_MOL + 1) * 4);
    S.cursor   = (int*)alloc((size_t)N_MOL * 4);
    S.csr      = (int*)alloc((size_t)E_G * 4);
    S.bsum     = (int*)alloc(512 * 4);
    S.bnsum    = (float*)alloc(512 * 4);
    S.bnsq     = S.bnsum + 256;
    S.coef     = (float*)alloc(512 * 4);
    S.wt0      = (unsigned short*)alloc((size_t)256 * 256 * 2);
    S.wt1      = (unsigned short*)alloc((size_t)256 * 256 * 2);
    S.wt2      = (unsigned short*)alloc((size_t)256 * 256 * 2);
    int*   bstart = (int*)alloc((size_t)(BATCH + 1) * 4);
    float* hstat  = (float*)alloc(64 * 4);
    float* y1     = (float*)alloc((size_t)BATCH * 6 * 64 * 4);
    float* y2     = (float*)alloc((size_t)BATCH * 6 * 32 * 4);
    if ((size_t)(w - (char*)d_ws) > ws_size) {
        k_sentinel<<<16, 256, 0, stream>>>(out, out_size, -333.f); return;
    }

    const float* drug_x  = (const float*)d_in[0];
    const int* drug_ei   = (const int*)d_in[1];
    const int* drug_idx  = (const int*)d_in[2];
    const float* dis_x   = (const float*)d_in[3];
    const int* dis_ei    = (const int*)d_in[4];
    const int* dis_idx   = (const int*)d_in[5];
    const int* mol_x     = (const int*)d_in[6];
    const int* mol_ei    = (const int*)d_in[7];
    const int* mol_b     = (const int*)d_in[8];
    const float *dr_W0 = (const float*)d_in[9], *dr_W1 = (const float*)d_in[10], *dr_W2 = (const float*)d_in[11];
    const float *dr_b2 = (const float*)d_in[14];
    const float *dr_g0 = (const float*)d_in[15], *dr_g1 = (const float*)d_in[16];
    const float *dr_be0 = (const float*)d_in[17], *dr_be1 = (const float*)d_in[18];
    const float *di_W0 = (const float*)d_in[19], *di_W1 = (const float*)d_in[20], *di_W2 = (const float*)d_in[21];
    const float *di_b2 = (const float*)d_in[24];
    const float *di_g0 = (const float*)d_in[25], *di_g1 = (const float*)d_in[26];
    const float *di_be0 = (const float*)d_in[27], *di_be1 = (const float*)d_in[28];
    const float* mol_emb = (const float*)d_in[29];
    const float *mo_W0 = (const float*)d_in[30], *mo_W1 = (const float*)d_in[31], *mo_W2 = (const float*)d_in[32];
    const float *mo_b2 = (const float*)d_in[35];
    const float *mo_g0 = (const float*)d_in[36], *mo_g1 = (const float*)d_in[37];
    const float *mo_be0 = (const float*)d_in[38], *mo_be1 = (const float*)d_in[39];
    const float *c1_W = (const float*)d_in[40], *c1_b = (const float*)d_in[41];
    const float *c1_g = (const float*)d_in[42], *c1_be = (const float*)d_in[43];
    const float *c2_W = (const float*)d_in[44], *c2_b = (const float*)d_in[45];
    const float *c2_g = (const float*)d_in[46], *c2_be = (const float*)d_in[47];
    const float *l1_W = (const float*)d_in[48], *l1_b = (const float*)d_in[49];
    const float *l2_W = (const float*)d_in[50], *l2_b = (const float*)d_in[51];

    // ---- drug GCN -> dfeat ----
    k_cast_bf<<<(N_DRUG * DIN + 255) / 256, 256, 0, stream>>>(drug_x, xin_bf, N_DRUG * DIN);
    run_gcn(xin_bf, DIN, xb, h_bf, dfeat, drug_ei, N_DRUG, E_G,
            dr_W0, dr_W1, dr_W2, dr_b2, dr_g0, dr_g1, dr_be0, dr_be1, S, stream);

    // ---- disease GCN -> sfeat ----
    k_cast_bf<<<(N_DIS * DIN + 255) / 256, 256, 0, stream>>>(dis_x, xin_bf, N_DIS * DIN);
    run_gcn(xin_bf, DIN, xb, h_bf, sfeat, dis_ei, N_DIS, E_G,
            di_W0, di_W1, di_W2, di_b2, di_g0, di_g1, di_be0, di_be1, S, stream);

    // ---- mol: atom encoder -> GCN -> pool ----
    k_atom_enc<<<N_MOL, 256, 0, stream>>>(mol_x, mol_emb, xin_bf);
    run_gcn(xin_bf, 256, xb, h_bf, out_f, mol_ei, N_MOL, E_MOL,
            mo_W0, mo_W1, mo_W2, mo_b2, mo_g0, mo_g1, mo_be0, mo_be1, S, stream);
    k_bstart<<<(BATCH + 256) / 256, 256, 0, stream>>>(mol_b, bstart);
    k_pool_seg<<<BATCH, 128, 0, stream>>>(out_f, bstart, mpool);

    // ---- head ----
    hipMemsetAsync(hstat, 0, 64 * 4, stream);
    k_conv1<<<BATCH, 64, 0, stream>>>(dfeat, mpool, sfeat, drug_idx, dis_idx, c1_W, c1_b, y1);
    k_head_stats<<<dim3(6, BATCH / 16), 256, 0, stream>>>(y1, hstat, 0, 64);
    k_bn_fin<<<1, 8, 0, stream>>>(hstat, 0, 1.0f / (BATCH * 64.0f));
    k_conv2<<<BATCH, 64, 0, stream>>>(y1, hstat, c1_g, c1_be, c2_W, c2_b, y2);
    k_head_stats<<<dim3(6, BATCH / 16), 256, 0, stream>>>(y2, hstat, 1, 32);
    k_bn_fin<<<1, 8, 0, stream>>>(hstat, 1, 1.0f / (BATCH * 32.0f));
    k_head<<<BATCH, 128, 0, stream>>>(y2, hstat, c2_g, c2_be, l1_W, l1_b, l2_W, l2_b, out);
}

// Round 7
// 873.355 us; speedup vs baseline: 10.1541x; 1.0513x over previous
//
#include <hip/hip_runtime.h>
#include <hip/hip_bf16.h>

#define N_DRUG 20000
#define N_DIS  20000
#define E_G    320000
#define BATCH  4096
#define N_MOL  65536
#define E_MOL  262144
#define DIN    128
#define DH     256
#define DOUT   128
#define NF     9
#define NV     128

typedef short s16x8 __attribute__((ext_vector_type(8)));
typedef unsigned short u16x8 __attribute__((ext_vector_type(8)));
typedef float f32x4 __attribute__((ext_vector_type(4)));

__device__ __forceinline__ float bfu2f(unsigned short u) {
    return __uint_as_float(((unsigned int)u) << 16);
}
__device__ __forceinline__ unsigned short f2bfu(float f) {
    __hip_bfloat16 b = __float2bfloat16(f);
    return *reinterpret_cast<unsigned short*>(&b);
}
__device__ __forceinline__ void atomAddF(float* p, float v) { atomicAdd(p, v); }

// ---------------- misc ----------------
__global__ void k_sentinel(float* out, int n, float v) {
    int i = blockIdx.x * 256 + threadIdx.x;
    if (i < n) out[i] = v;
}

// 3 weight transposes in one kernel: W[K][N] f32 -> Wt[N][K] bf16
__global__ void k_wcast3(const float* __restrict__ W0, const float* __restrict__ W1,
                         const float* __restrict__ W2,
                         unsigned short* __restrict__ T0, unsigned short* __restrict__ T1,
                         unsigned short* __restrict__ T2, int Cin) {
    int i = blockIdx.x * 256 + threadIdx.x;
    int t0 = Cin * 256, t1 = 256 * 256, t2 = 256 * 128;
    if (i < t0) {
        int k = i / 256, c = i - k * 256;
        T0[(size_t)c * Cin + k] = f2bfu(W0[i]);
    } else if (i < t0 + t1) {
        int e = i - t0;
        int k = e / 256, c = e - k * 256;
        T1[(size_t)c * 256 + k] = f2bfu(W1[e]);
    } else if (i < t0 + t1 + t2) {
        int e = i - t0 - t1;
        int k = e / 128, c = e - k * 128;
        T2[(size_t)c * 256 + k] = f2bfu(W2[e]);
    }
}

// ---------------- degree ----------------
__global__ void k_count(const int* __restrict__ dst, int* __restrict__ cnt, int E) {
    int e = blockIdx.x * 256 + threadIdx.x;
    if (e < E) atomicAdd(&cnt[dst[e]], 1);
}

// ---------------- CSR build (scan1 also computes dinv) ----------------
__global__ void k_scan1(const int* __restrict__ cnt, int* __restrict__ rowStart,
                        int* __restrict__ bsum, float* __restrict__ dinv, int n) {
    __shared__ int sh[256];
    int i = blockIdx.x * 256 + threadIdx.x;
    int v = (i < n) ? cnt[i] : 0;
    if (i < n) dinv[i] = rsqrtf(1.0f + (float)v);
    sh[threadIdx.x] = v;
    __syncthreads();
    for (int off = 1; off < 256; off <<= 1) {
        int t = (threadIdx.x >= off) ? sh[threadIdx.x - off] : 0;
        __syncthreads();
        sh[threadIdx.x] += t;
        __syncthreads();
    }
    if (i < n) rowStart[i] = sh[threadIdx.x] - v;
    if (threadIdx.x == 255) bsum[blockIdx.x] = sh[255];
}
__global__ void k_scan2(int* __restrict__ bsum, int nb) {
    __shared__ int sh[256];
    int t = threadIdx.x;
    int v = (t < nb) ? bsum[t] : 0;
    sh[t] = v;
    __syncthreads();
    for (int off = 1; off < 256; off <<= 1) {
        int u = (t >= off) ? sh[t - off] : 0;
        __syncthreads();
        sh[t] += u;
        __syncthreads();
    }
    if (t < nb) bsum[t] = sh[t] - v;
}
__global__ void k_scan3(int* __restrict__ rowStart, int* __restrict__ cursor,
                        const int* __restrict__ bsum, int n, int E) {
    int i = blockIdx.x * 256 + threadIdx.x;
    if (i < n) {
        int r = rowStart[i] + bsum[blockIdx.x];
        rowStart[i] = r;
        cursor[i] = r;
    }
    if (i == 0) rowStart[n] = E;
}
__global__ void k_fill(const int* __restrict__ src, const int* __restrict__ dst,
                       int* __restrict__ cursor, int* __restrict__ csr, int E) {
    int e = blockIdx.x * 256 + threadIdx.x;
    if (e < E) {
        int p = atomicAdd(&cursor[dst[e]], 1);
        csr[p] = src[e];
    }
}

// ---------------- MFMA GEMM: C[M,N]bf16 = act(A[M,K]bf16) @ B (Bt[N][K]bf16) ----------------
// AFFINE: A' = relu(scale[k]*A + shift[k]) applied during staging (fused BatchNorm+ReLU).
template<int AFFINE>
__global__ __launch_bounds__(256) void k_gemm_mfma(const unsigned short* __restrict__ A,
                                                   const unsigned short* __restrict__ Bt,
                                                   const float* __restrict__ coef,
                                                   unsigned short* __restrict__ Cout,
                                                   int M, int K, int N) {
    __shared__ unsigned short Al[4][128][8];
    __shared__ unsigned short Bl[4][128][8];
    const int tid = threadIdx.x;
    const int bm = blockIdx.y * 128;
    const int bn = blockIdx.x * 128;
    const int w = tid >> 6, l = tid & 63;
    const int wrow = (w >> 1) * 64, wcol = (w & 1) * 64;
    const int kg = l >> 4, lr = l & 15;

    f32x4 acc[4][4];
#pragma unroll
    for (int fm = 0; fm < 4; ++fm)
#pragma unroll
        for (int fn = 0; fn < 4; ++fn) acc[fm][fn] = f32x4{0.f, 0.f, 0.f, 0.f};

    for (int k0 = 0; k0 < K; k0 += 32) {
#pragma unroll
        for (int c = 0; c < 2; ++c) {
            int idx = c * 256 + tid;
            int row = idx >> 2;
            int koff = idx & 3;
            u16x8 va = {0, 0, 0, 0, 0, 0, 0, 0};
            int grow = bm + row;
            if (grow < M)
                va = *reinterpret_cast<const u16x8*>(A + (size_t)grow * K + k0 + koff * 8);
            if (AFFINE) {
                int kb = k0 + koff * 8;
#pragma unroll
                for (int e = 0; e < 8; ++e) {
                    float f = bfu2f((unsigned short)va[e]);
                    f = fmaf(coef[kb + e], f, coef[256 + kb + e]);
                    va[e] = f2bfu(fmaxf(f, 0.f));
                }
            }
            *reinterpret_cast<u16x8*>(&Al[koff][row][0]) = va;
            u16x8 vb = *reinterpret_cast<const u16x8*>(Bt + (size_t)(bn + row) * K + k0 + koff * 8);
            *reinterpret_cast<u16x8*>(&Bl[koff][row][0]) = vb;
        }
        __syncthreads();
        s16x8 a[4], b[4];
#pragma unroll
        for (int fm = 0; fm < 4; ++fm)
            a[fm] = *reinterpret_cast<const s16x8*>(&Al[kg][wrow + fm * 16 + lr][0]);
#pragma unroll
        for (int fn = 0; fn < 4; ++fn)
            b[fn] = *reinterpret_cast<const s16x8*>(&Bl[kg][wcol + fn * 16 + lr][0]);
#pragma unroll
        for (int fm = 0; fm < 4; ++fm)
#pragma unroll
            for (int fn = 0; fn < 4; ++fn)
                acc[fm][fn] = __builtin_amdgcn_mfma_f32_16x16x32_bf16(a[fm], b[fn], acc[fm][fn], 0, 0, 0);
        __syncthreads();
    }
    // C/D layout: col = lane&15, row = (lane>>4)*4 + reg
#pragma unroll
    for (int fm = 0; fm < 4; ++fm)
#pragma unroll
        for (int r = 0; r < 4; ++r) {
            int row = bm + wrow + fm * 16 + kg * 4 + r;
            if (row >= M) continue;
#pragma unroll
            for (int fn = 0; fn < 4; ++fn) {
                int col = bn + wcol + fn * 16 + lr;
                Cout[(size_t)row * N + col] = f2bfu(acc[fm][fn][r]);
            }
        }
}

// ---------------- CSR gather: 32-lane row groups, 8 rows/block, 4-deep unroll ----------------
// out[d,:] = h[d,:]*dinv[d]^2 (+bias) + sum_{s in N(d)} dinv[s]*dinv[d]*h[s,:]
template<int C, int BIAS, int OUTBF, int INF32>
__global__ __launch_bounds__(256) void k_gather(const void* __restrict__ hv,
                                                const float* __restrict__ dinv,
                                                const float* __restrict__ bias,
                                                const int* __restrict__ csr,
                                                const int* __restrict__ rowStart,
                                                void* __restrict__ outv, int n) {
    constexpr int PL = C / 32;  // 8 (C=256) or 4 (C=128)
    int row = blockIdx.x * 8 + (threadIdx.x >> 5);
    if (row >= n) return;
    int lane = threadIdx.x & 31;
    int c0 = lane * PL;

    auto loadRow = [&](int r, float* d) {
        if constexpr (INF32) {
            const float* base = (const float*)hv + (size_t)r * C + c0;
#pragma unroll
            for (int q = 0; q < PL / 4; ++q) {
                float4 v = *reinterpret_cast<const float4*>(base + q * 4);
                d[q * 4 + 0] = v.x; d[q * 4 + 1] = v.y; d[q * 4 + 2] = v.z; d[q * 4 + 3] = v.w;
            }
        } else {
            const unsigned short* base = (const unsigned short*)hv + (size_t)r * C + c0;
            if constexpr (PL == 8) {
                u16x8 v = *reinterpret_cast<const u16x8*>(base);
#pragma unroll
                for (int e = 0; e < 8; ++e) d[e] = bfu2f((unsigned short)v[e]);
            } else {
                ushort4 v = *reinterpret_cast<const ushort4*>(base);
                d[0] = bfu2f(v.x); d[1] = bfu2f(v.y); d[2] = bfu2f(v.z); d[3] = bfu2f(v.w);
            }
        }
    };

    float dd = dinv[row], ws = dd * dd;
    int beg = rowStart[row], end = rowStart[row + 1];
    float a0[PL], a1[PL], a2[PL], a3[PL], t0[PL], t1[PL], t2[PL], t3[PL];
    loadRow(row, t0);
#pragma unroll
    for (int p = 0; p < PL; ++p) { a0[p] = t0[p] * ws; a1[p] = 0.f; a2[p] = 0.f; a3[p] = 0.f; }

    int j = beg;
    for (; j + 4 <= end; j += 4) {
        int s0 = csr[j], s1 = csr[j + 1], s2 = csr[j + 2], s3 = csr[j + 3];
        float w0 = dinv[s0] * dd, w1 = dinv[s1] * dd, w2 = dinv[s2] * dd, w3 = dinv[s3] * dd;
        loadRow(s0, t0); loadRow(s1, t1); loadRow(s2, t2); loadRow(s3, t3);
#pragma unroll
        for (int p = 0; p < PL; ++p) {
            a0[p] += w0 * t0[p]; a1[p] += w1 * t1[p];
            a2[p] += w2 * t2[p]; a3[p] += w3 * t3[p];
        }
    }
    for (; j < end; ++j) {
        int s = csr[j];
        float w = dinv[s] * dd;
        loadRow(s, t0);
#pragma unroll
        for (int p = 0; p < PL; ++p) a0[p] += w * t0[p];
    }
#pragma unroll
    for (int p = 0; p < PL; ++p) {
        a0[p] += (a1[p] + a2[p]) + a3[p];
        if (BIAS) a0[p] += bias[c0 + p];
    }
    if constexpr (OUTBF) {
        unsigned short* o = (unsigned short*)outv + (size_t)row * C + c0;
        if constexpr (PL == 8) {
            u16x8 ov;
#pragma unroll
            for (int e = 0; e < 8; ++e) ov[e] = f2bfu(a0[e]);
            *reinterpret_cast<u16x8*>(o) = ov;
        } else {
            ushort4 ov = {f2bfu(a0[0]), f2bfu(a0[1]), f2bfu(a0[2]), f2bfu(a0[3])};
            *reinterpret_cast<ushort4*>(o) = ov;
        }
    } else {
        float* o = (float*)outv + (size_t)row * C + c0;
#pragma unroll
        for (int q = 0; q < PL / 4; ++q) {
            float4 ov = {a0[q * 4 + 0], a0[q * 4 + 1], a0[q * 4 + 2], a0[q * 4 + 3]};
            *reinterpret_cast<float4*>(o + q * 4) = ov;
        }
    }
}

// ---------------- BatchNorm stats (bf16 input) + coef (self-zeroing) ----------------
__global__ void k_bn_stats_bf(const unsigned short* __restrict__ x, float* __restrict__ sum,
                              float* __restrict__ sq, int n, int rpb) {
    int j = threadIdx.x;
    int r0 = blockIdx.x * rpb;
    int r1 = min(r0 + rpb, n);
    float s = 0.f, q = 0.f;
    for (int r = r0; r < r1; ++r) {
        float v = bfu2f(x[(size_t)r * 256 + j]);
        s += v; q += v * v;
    }
    atomAddF(&sum[j], s);
    atomAddF(&sq[j], q);
}

// coef[j]=g*rstd, coef[256+j]=be-mean*scale; zeroes sum/sq for the next stats pass
__global__ void k_bn_coef(float* __restrict__ sum, float* __restrict__ sq,
                          const float* __restrict__ g, const float* __restrict__ be,
                          float* __restrict__ coef, float invN) {
    int j = threadIdx.x;
    float m = sum[j] * invN;
    float v = sq[j] * invN - m * m;
    float r = rsqrtf(fmaxf(v, 0.f) + 1e-5f);
    float sc = g[j] * r;
    coef[j] = sc;
    coef[256 + j] = be[j] - m * sc;
    sum[j] = 0.f;
    sq[j] = 0.f;
}

// ---------------- atom encoder: 4 rows/block, 64 lanes x float4 ----------------
__global__ __launch_bounds__(256) void k_atom_enc(const int* __restrict__ mol_x,
                                                  const float* __restrict__ emb,
                                                  unsigned short* __restrict__ h) {
    __shared__ int sidx[4][NF];
    int t = threadIdx.x;
    if (t < 4 * NF) sidx[t / NF][t % NF] = mol_x[(blockIdx.x * 4 + t / NF) * NF + t % NF];
    __syncthreads();
    int r = t >> 6, lane = t & 63;
    int c0 = lane * 4;
    int row = blockIdx.x * 4 + r;
    float4 s = {0.f, 0.f, 0.f, 0.f};
#pragma unroll
    for (int f = 0; f < NF; ++f) {
        const float4 v = *reinterpret_cast<const float4*>(emb + ((size_t)f * NV + sidx[r][f]) * DH + c0);
        s.x += v.x; s.y += v.y; s.z += v.z; s.w += v.w;
    }
    ushort4 ov = {f2bfu(s.x), f2bfu(s.y), f2bfu(s.z), f2bfu(s.w)};
    *reinterpret_cast<ushort4*>(h + (size_t)row * DH + c0) = ov;
}

// ---------------- segment pool (bf16 input, internal binary search) ----------------
__global__ __launch_bounds__(128) void k_pool_seg(const unsigned short* __restrict__ mfeat,
                                                  const int* __restrict__ batch,
                                                  float* __restrict__ mpool) {
    __shared__ int sr[2];
    int b = blockIdx.x, t = threadIdx.x;
    if (t < 2) {
        int target = b + t;
        int lo = 0, hi = N_MOL;
        while (lo < hi) {
            int mid = (lo + hi) >> 1;
            if (batch[mid] < target) lo = mid + 1; else hi = mid;
        }
        sr[t] = lo;
    }
    __syncthreads();
    float s = 0.f;
    int e = sr[1];
    for (int i = sr[0]; i < e; ++i) s += bfu2f(mfeat[(size_t)i * 128 + t]);
    mpool[(size_t)b * 128 + t] = s;
}

// ---------------- head: conv1 ----------------
__global__ __launch_bounds__(64) void k_conv1(const float* __restrict__ dfeat,
                                              const float* __restrict__ mpool,
                                              const float* __restrict__ sfeat,
                                              const int* __restrict__ drug_idx,
                                              const int* __restrict__ dis_idx,
                                              const float* __restrict__ W,
                                              const float* __restrict__ bias,
                                              float* __restrict__ y1) {
    __shared__ float xs[3][128];
    __shared__ float w[54];
    __shared__ float bb[6];
    int b = blockIdx.x, t = threadIdx.x;
    int di = drug_idx[b], si = dis_idx[b];
    const float* r0 = dfeat + (size_t)di * 128;
    const float* r1 = mpool + (size_t)b * 128;
    const float* r2 = sfeat + (size_t)si * 128;
    xs[0][t] = r0[t]; xs[0][t + 64] = r0[t + 64];
    xs[1][t] = r1[t]; xs[1][t + 64] = r1[t + 64];
    xs[2][t] = r2[t]; xs[2][t + 64] = r2[t + 64];
    if (t < 54) w[t] = W[t];
    if (t < 6) bb[t] = bias[t];
    __syncthreads();
    int l0 = 2 * t, l1 = l0 + 1;
#pragma unroll
    for (int o = 0; o < 6; ++o) {
        float ya = bb[o], yb = bb[o];
#pragma unroll
        for (int i = 0; i < 3; ++i) {
            const float* wi = &w[(o * 3 + i) * 3];
            float xm1 = (l0 > 0) ? xs[i][l0 - 1] : 0.f;
            float x0 = xs[i][l0];
            float x1 = xs[i][l1];
            float x2 = (l1 < 127) ? xs[i][l1 + 1] : 0.f;
            ya += wi[0] * xm1 + wi[1] * x0 + wi[2] * x1;
            yb += wi[0] * x0 + wi[1] * x1 + wi[2] * x2;
        }
        y1[((size_t)b * 6 + o) * 64 + t] = fmaxf(ya, yb);
    }
}

// hb layout per 'which' (32 floats): [0..5]=sum [8..13]=sumsq [16..21]=mean [24..29]=rstd
__global__ __launch_bounds__(256) void k_head_stats(const float* __restrict__ y,
                                                    float* __restrict__ hb, int which, int L) {
    int o = blockIdx.x;
    int b0 = blockIdx.y * 16;
    int t = threadIdx.x;
    float s = 0.f, q = 0.f;
    int per = 16 * L;
    for (int idx = t; idx < per; idx += 256) {
        int b = b0 + idx / L;
        int l = idx - (idx / L) * L;
        float v = y[((size_t)b * 6 + o) * L + l];
        s += v; q += v * v;
    }
    __shared__ float sms[4], smq[4];
#pragma unroll
    for (int off = 32; off > 0; off >>= 1) {
        s += __shfl_down(s, off);
        q += __shfl_down(q, off);
    }
    if ((t & 63) == 0) { sms[t >> 6] = s; smq[t >> 6] = q; }
    __syncthreads();
    if (t == 0) {
        float S = 0.f, Q = 0.f;
        for (int i = 0; i < 4; ++i) { S += sms[i]; Q += smq[i]; }
        atomAddF(hb + which * 32 + o, S);
        atomAddF(hb + which * 32 + 8 + o, Q);
    }
}

__global__ void k_bn_fin(float* __restrict__ hb, int which, float invN) {
    int o = threadIdx.x;
    if (o >= 6) return;
    float* p = hb + which * 32;
    float m = p[o] * invN;
    float v = p[8 + o] * invN - m * m;
    p[16 + o] = m;
    p[24 + o] = rsqrtf(fmaxf(v, 0.f) + 1e-5f);
}

// ---------------- head: conv2 ----------------
__global__ __launch_bounds__(64) void k_conv2(const float* __restrict__ y1,
                                              const float* __restrict__ hb,
                                              const float* __restrict__ g1,
                                              const float* __restrict__ be1,
                                              const float* __restrict__ W,
                                              const float* __restrict__ bias,
                                              float* __restrict__ y2) {
    __shared__ float xs[6][64];
    __shared__ float w[108];
    __shared__ float bb[6];
    int b = blockIdx.x, t = threadIdx.x;
    const float* mean = hb + 16;
    const float* rstd = hb + 24;
    for (int idx = t; idx < 384; idx += 64) {
        int o = idx >> 6, l = idx & 63;
        float v = y1[((size_t)b * 6 + o) * 64 + l];
        v = g1[o] * (v - mean[o]) * rstd[o] + be1[o];
        xs[o][l] = fmaxf(v, 0.f);
    }
    for (int idx = t; idx < 108; idx += 64) w[idx] = W[idx];
    if (t < 6) bb[t] = bias[t];
    __syncthreads();
    if (t >= 32) return;
    int l0 = 2 * t, l1 = l0 + 1;
#pragma unroll
    for (int o = 0; o < 6; ++o) {
        float ya = bb[o], yb = bb[o];
#pragma unroll
        for (int i = 0; i < 6; ++i) {
            const float* wi = &w[(o * 6 + i) * 3];
            float xm1 = (l0 > 0) ? xs[i][l0 - 1] : 0.f;
            float x0 = xs[i][l0];
            float x1 = xs[i][l1];
            float x2 = (l1 < 63) ? xs[i][l1 + 1] : 0.f;
            ya += wi[0] * xm1 + wi[1] * x0 + wi[2] * x1;
            yb += wi[0] * x0 + wi[1] * x1 + wi[2] * x2;
        }
        y2[((size_t)b * 6 + o) * 32 + t] = fmaxf(ya, yb);
    }
}

// ---------------- head final ----------------
__global__ __launch_bounds__(128) void k_head(const float* __restrict__ y2,
                                              const float* __restrict__ hb,
                                              const float* __restrict__ g2,
                                              const float* __restrict__ be2,
                                              const float* __restrict__ l1W,
                                              const float* __restrict__ l1b,
                                              const float* __restrict__ l2W,
                                              const float* __restrict__ l2b,
                                              float* __restrict__ out) {
    __shared__ float fs[192];
    __shared__ float sm[2];
    int b = blockIdx.x, t = threadIdx.x;
    const float* mean = hb + 32 + 16;
    const float* rstd = hb + 32 + 24;
    for (int idx = t; idx < 192; idx += 128) {
        int o = idx >> 5, l = idx & 31;
        float v = y2[((size_t)b * 6 + o) * 32 + l];
        v = g2[o] * (v - mean[o]) * rstd[o] + be2[o];
        fs[idx] = fmaxf(v, 0.f);
    }
    __syncthreads();
    float h = l1b[t];
    for (int k = 0; k < 192; ++k)
        h += fs[k] * l1W[k * 128 + t];
    h = fmaxf(h, 0.f);
    float p = h * l2W[t];
#pragma unroll
    for (int off = 32; off > 0; off >>= 1) p += __shfl_down(p, off);
    if ((t & 63) == 0) sm[t >> 6] = p;
    __syncthreads();
    if (t == 0) out[b] = sm[0] + sm[1] + l2b[0];
}

// ---------------- host-side GCN driver ----------------
struct GcnScratch {
    int *cnt, *rowStart, *cursor, *csr, *bsum;
    float *dinv, *bnsum, *bnsq, *coef;
    unsigned short *wt0, *wt1, *wt2;
};

// xin: bf16 [n][Cin] (INF32=0) or f32 (INF32=1). Output: OUT2BF? bf16 h_bf : f32 outF [n][128]
static void run_gcn(const void* xin, int Cin, int inF32,
                    unsigned short* xb, unsigned short* h_bf, void* outF, int out2bf,
                    const int* ei, int n, int E,
                    const float* W0, const float* W1, const float* W2, const float* b2,
                    const float* g0, const float* g1, const float* be0, const float* be1,
                    GcnScratch& S, hipStream_t stream) {
    const int* src = ei;
    const int* dst = ei + E;
    hipMemsetAsync(S.cnt, 0, (size_t)n * sizeof(int), stream);
    k_count<<<(E + 255) / 256, 256, 0, stream>>>(dst, S.cnt, E);
    int nb = (n + 255) / 256;
    k_scan1<<<nb, 256, 0, stream>>>(S.cnt, S.rowStart, S.bsum, S.dinv, n);
    k_scan2<<<1, 256, 0, stream>>>(S.bsum, nb);
    k_scan3<<<nb, 256, 0, stream>>>(S.rowStart, S.cursor, S.bsum, n, E);
    k_fill<<<(E + 255) / 256, 256, 0, stream>>>(src, dst, S.cursor, S.csr, E);
    int wtot = Cin * 256 + 256 * 256 + 256 * 128;
    k_wcast3<<<(wtot + 255) / 256, 256, 0, stream>>>(W0, W1, W2, S.wt0, S.wt1, S.wt2, Cin);

    int gb = (n + 7) / 8;
    int gy = (n + 127) / 128;
    float invN = 1.0f / (float)n;
    int sb = (n + 127) / 128;
    // L0: aggregate-first (S·X)·W0 (bias dropped: cancelled by BN)
    if (inF32)
        k_gather<128, 0, 1, 1><<<gb, 256, 0, stream>>>(xin, S.dinv, nullptr, S.csr, S.rowStart, xb, n);
    else
        k_gather<256, 0, 1, 0><<<gb, 256, 0, stream>>>(xin, S.dinv, nullptr, S.csr, S.rowStart, xb, n);
    k_gemm_mfma<0><<<dim3(2, gy), 256, 0, stream>>>(xb, S.wt0, nullptr, h_bf, n, Cin, 256);
    k_bn_stats_bf<<<sb, 256, 0, stream>>>(h_bf, S.bnsum, S.bnsq, n, 128);
    k_bn_coef<<<1, 256, 0, stream>>>(S.bnsum, S.bnsq, g0, be0, S.coef, invN);
    // L1: GEMM(BN0+relu fused on A) -> gather
    k_gemm_mfma<1><<<dim3(2, gy), 256, 0, stream>>>(h_bf, S.wt1, S.coef, xb, n, 256, 256);
    k_gather<256, 0, 1, 0><<<gb, 256, 0, stream>>>(xb, S.dinv, nullptr, S.csr, S.rowStart, h_bf, n);
    k_bn_stats_bf<<<sb, 256, 0, stream>>>(h_bf, S.bnsum, S.bnsq, n, 128);
    k_bn_coef<<<1, 256, 0, stream>>>(S.bnsum, S.bnsq, g1, be1, S.coef, invN);
    // L2: GEMM(BN1+relu fused on A) -> gather + bias (no BN)
    k_gemm_mfma<1><<<dim3(1, gy), 256, 0, stream>>>(h_bf, S.wt2, S.coef, xb, n, 256, 128);
    if (out2bf)
        k_gather<128, 1, 1, 0><<<gb, 256, 0, stream>>>(xb, S.dinv, b2, S.csr, S.rowStart, outF, n);
    else
        k_gather<128, 1, 0, 0><<<gb, 256, 0, stream>>>(xb, S.dinv, b2, S.csr, S.rowStart, outF, n);
}

extern "C" void kernel_launch(void* const* d_in, const int* in_sizes, int n_in,
                              void* d_out, int out_size, void* d_ws, size_t ws_size,
                              hipStream_t stream) {
    float* out = (float*)d_out;
    if (n_in != 52) { k_sentinel<<<16, 256, 0, stream>>>(out, out_size, -111.f); return; }
    if (in_sizes[0] != N_DRUG * DIN || in_sizes[29] != NF * NV * DH || in_sizes[48] != 192 * 128) {
        k_sentinel<<<16, 256, 0, stream>>>(out, out_size, -222.f); return;
    }

    char* w = (char*)d_ws;
    auto alloc = [&](size_t bytes) { char* p = w; w += (bytes + 255) & ~(size_t)255; return p; };
    unsigned short* xb   = (unsigned short*)alloc((size_t)N_MOL * 256 * 2);
    unsigned short* h_bf = (unsigned short*)alloc((size_t)N_MOL * 256 * 2);
    unsigned short* xin  = (unsigned short*)alloc((size_t)N_MOL * 256 * 2);
    float* dfeat = (float*)alloc((size_t)N_DRUG * 128 * 4);
    float* sfeat = (float*)alloc((size_t)N_DIS * 128 * 4);
    float* mpool = (float*)alloc((size_t)BATCH * 128 * 4);
    GcnScratch S;
    S.cnt      = (int*)alloc((size_t)N_MOL * 4);
    S.dinv     = (float*)alloc((size_t)N_MOL * 4);
    S.rowStart = (int*)alloc((size_t)(N_MOL + 1) * 4);
    S.cursor   = (int*)alloc((size_t)N_MOL * 4);
    S.csr      = (int*)alloc((size_t)E_G * 4);
    S.bsum     = (int*)alloc(512 * 4);
    S.bnsum    = (float*)alloc(512 * 4);
    S.bnsq     = S.bnsum + 256;
    S.coef     = (float*)alloc(512 * 4);
    S.wt0      = (unsigned short*)alloc((size_t)256 * 256 * 2);
    S.wt1      = (unsigned short*)alloc((size_t)256 * 256 * 2);
    S.wt2      = (unsigned short*)alloc((size_t)256 * 256 * 2);
    float* hstat  = (float*)alloc(64 * 4);
    float* y1     = (float*)alloc((size_t)BATCH * 6 * 64 * 4);
    float* y2     = (float*)alloc((size_t)BATCH * 6 * 32 * 4);
    if ((size_t)(w - (char*)d_ws) > ws_size) {
        k_sentinel<<<16, 256, 0, stream>>>(out, out_size, -333.f); return;
    }

    const float* drug_x  = (const float*)d_in[0];
    const int* drug_ei   = (const int*)d_in[1];
    const int* drug_idx  = (const int*)d_in[2];
    const float* dis_x   = (const float*)d_in[3];
    const int* dis_ei    = (const int*)d_in[4];
    const int* dis_idx   = (const int*)d_in[5];
    const int* mol_x     = (const int*)d_in[6];
    const int* mol_ei    = (const int*)d_in[7];
    const int* mol_b     = (const int*)d_in[8];
    const float *dr_W0 = (const float*)d_in[9], *dr_W1 = (const float*)d_in[10], *dr_W2 = (const float*)d_in[11];
    const float *dr_b2 = (const float*)d_in[14];
    const float *dr_g0 = (const float*)d_in[15], *dr_g1 = (const float*)d_in[16];
    const float *dr_be0 = (const float*)d_in[17], *dr_be1 = (const float*)d_in[18];
    const float *di_W0 = (const float*)d_in[19], *di_W1 = (const float*)d_in[20], *di_W2 = (const float*)d_in[21];
    const float *di_b2 = (const float*)d_in[24];
    const float *di_g0 = (const float*)d_in[25], *di_g1 = (const float*)d_in[26];
    const float *di_be0 = (const float*)d_in[27], *di_be1 = (const float*)d_in[28];
    const float* mol_emb = (const float*)d_in[29];
    const float *mo_W0 = (const float*)d_in[30], *mo_W1 = (const float*)d_in[31], *mo_W2 = (const float*)d_in[32];
    const float *mo_b2 = (const float*)d_in[35];
    const float *mo_g0 = (const float*)d_in[36], *mo_g1 = (const float*)d_in[37];
    const float *mo_be0 = (const float*)d_in[38], *mo_be1 = (const float*)d_in[39];
    const float *c1_W = (const float*)d_in[40], *c1_b = (const float*)d_in[41];
    const float *c1_g = (const float*)d_in[42], *c1_be = (const float*)d_in[43];
    const float *c2_W = (const float*)d_in[44], *c2_b = (const float*)d_in[45];
    const float *c2_g = (const float*)d_in[46], *c2_be = (const float*)d_in[47];
    const float *l1_W = (const float*)d_in[48], *l1_b = (const float*)d_in[49];
    const float *l2_W = (const float*)d_in[50], *l2_b = (const float*)d_in[51];

    hipMemsetAsync(S.bnsum, 0, 512 * sizeof(float), stream);   // bn_coef self-zeroes thereafter

    // ---- drug GCN -> dfeat (f32) ----
    run_gcn(drug_x, DIN, 1, xb, h_bf, dfeat, 0, drug_ei, N_DRUG, E_G,
            dr_W0, dr_W1, dr_W2, dr_b2, dr_g0, dr_g1, dr_be0, dr_be1, S, stream);

    // ---- disease GCN -> sfeat (f32) ----
    run_gcn(dis_x, DIN, 1, xb, h_bf, sfeat, 0, dis_ei, N_DIS, E_G,
            di_W0, di_W1, di_W2, di_b2, di_g0, di_g1, di_be0, di_be1, S, stream);

    // ---- mol: atom encoder -> GCN (bf16 out) -> pool ----
    k_atom_enc<<<N_MOL / 4, 256, 0, stream>>>(mol_x, mol_emb, xin);
    run_gcn(xin, 256, 0, xb, h_bf, h_bf, 1, mol_ei, N_MOL, E_MOL,
            mo_W0, mo_W1, mo_W2, mo_b2, mo_g0, mo_g1, mo_be0, mo_be1, S, stream);
    k_pool_seg<<<BATCH, 128, 0, stream>>>(h_bf, mol_b, mpool);

    // ---- head ----
    hipMemsetAsync(hstat, 0, 64 * 4, stream);
    k_conv1<<<BATCH, 64, 0, stream>>>(dfeat, mpool, sfeat, drug_idx, dis_idx, c1_W, c1_b, y1);
    k_head_stats<<<dim3(6, BATCH / 16), 256, 0, stream>>>(y1, hstat, 0, 64);
    k_bn_fin<<<1, 8, 0, stream>>>(hstat, 0, 1.0f / (BATCH * 64.0f));
    k_conv2<<<BATCH, 64, 0, stream>>>(y1, hstat, c1_g, c1_be, c2_W, c2_b, y2);
    k_head_stats<<<dim3(6, BATCH / 16), 256, 0, stream>>>(y2, hstat, 1, 32);
    k_bn_fin<<<1, 8, 0, stream>>>(hstat, 1, 1.0f / (BATCH * 32.0f));
    k_head<<<BATCH, 128, 0, stream>>>(y2, hstat, c2_g, c2_be, l1_W, l1_b, l2_W, l2_b, out);
}

// Round 8
// 755.516 us; speedup vs baseline: 11.7378x; 1.1560x over previous
//
#include <hip/hip_runtime.h>
#include <hip/hip_bf16.h>

#define N_DRUG 20000
#define N_DIS  20000
#define E_G    320000
#define BATCH  4096
#define N_MOL  65536
#define E_MOL  262144
#define DIN    128
#define DH     256
#define DOUT   128
#define NF     9
#define NV     128

typedef short s16x8 __attribute__((ext_vector_type(8)));
typedef unsigned short u16x8 __attribute__((ext_vector_type(8)));
typedef float f32x4 __attribute__((ext_vector_type(4)));

__device__ __forceinline__ float bfu2f(unsigned short u) {
    return __uint_as_float(((unsigned int)u) << 16);
}
__device__ __forceinline__ unsigned short f2bfu(float f) {
    __hip_bfloat16 b = __float2bfloat16(f);
    return *reinterpret_cast<unsigned short*>(&b);
}
__device__ __forceinline__ void atomAddF(float* p, float v) { atomicAdd(p, v); }

// ---------------- misc ----------------
__global__ void k_sentinel(float* out, int n, float v) {
    int i = blockIdx.x * 256 + threadIdx.x;
    if (i < n) out[i] = v;
}

// 3 weight transposes in one kernel: W[K][N] f32 -> Wt[N][K] bf16
__global__ void k_wcast3(const float* __restrict__ W0, const float* __restrict__ W1,
                         const float* __restrict__ W2,
                         unsigned short* __restrict__ T0, unsigned short* __restrict__ T1,
                         unsigned short* __restrict__ T2, int Cin) {
    int i = blockIdx.x * 256 + threadIdx.x;
    int t0 = Cin * 256, t1 = 256 * 256, t2 = 256 * 128;
    if (i < t0) {
        int k = i / 256, c = i - k * 256;
        T0[(size_t)c * Cin + k] = f2bfu(W0[i]);
    } else if (i < t0 + t1) {
        int e = i - t0;
        int k = e / 256, c = e - k * 256;
        T1[(size_t)c * 256 + k] = f2bfu(W1[e]);
    } else if (i < t0 + t1 + t2) {
        int e = i - t0 - t1;
        int k = e / 128, c = e - k * 128;
        T2[(size_t)c * 256 + k] = f2bfu(W2[e]);
    }
}

// ---------------- degree ----------------
__global__ void k_count(const int* __restrict__ dst, int* __restrict__ cnt, int E) {
    int e = blockIdx.x * 256 + threadIdx.x;
    if (e < E) atomicAdd(&cnt[dst[e]], 1);
}

// ---------------- CSR build (scan1 also computes dinv) ----------------
__global__ void k_scan1(const int* __restrict__ cnt, int* __restrict__ rowStart,
                        int* __restrict__ bsum, float* __restrict__ dinv, int n) {
    __shared__ int sh[256];
    int i = blockIdx.x * 256 + threadIdx.x;
    int v = (i < n) ? cnt[i] : 0;
    if (i < n) dinv[i] = rsqrtf(1.0f + (float)v);
    sh[threadIdx.x] = v;
    __syncthreads();
    for (int off = 1; off < 256; off <<= 1) {
        int t = (threadIdx.x >= off) ? sh[threadIdx.x - off] : 0;
        __syncthreads();
        sh[threadIdx.x] += t;
        __syncthreads();
    }
    if (i < n) rowStart[i] = sh[threadIdx.x] - v;
    if (threadIdx.x == 255) bsum[blockIdx.x] = sh[255];
}
__global__ void k_scan2(int* __restrict__ bsum, int nb) {
    __shared__ int sh[256];
    int t = threadIdx.x;
    int v = (t < nb) ? bsum[t] : 0;
    sh[t] = v;
    __syncthreads();
    for (int off = 1; off < 256; off <<= 1) {
        int u = (t >= off) ? sh[t - off] : 0;
        __syncthreads();
        sh[t] += u;
        __syncthreads();
    }
    if (t < nb) bsum[t] = sh[t] - v;
}
__global__ void k_scan3(int* __restrict__ rowStart, int* __restrict__ cursor,
                        const int* __restrict__ bsum, int n, int E) {
    int i = blockIdx.x * 256 + threadIdx.x;
    if (i < n) {
        int r = rowStart[i] + bsum[blockIdx.x];
        rowStart[i] = r;
        cursor[i] = r;
    }
    if (i == 0) rowStart[n] = E;
}
__global__ void k_fill(const int* __restrict__ src, const int* __restrict__ dst,
                       int* __restrict__ cursor, int* __restrict__ csr, int E) {
    int e = blockIdx.x * 256 + threadIdx.x;
    if (e < E) {
        int p = atomicAdd(&cursor[dst[e]], 1);
        csr[p] = src[e];
    }
}

// ---------------- MFMA GEMM: C[M,N]bf16 = act(A[M,K]bf16) @ B (Bt[N][K]bf16) ----------------
// AFFINE: A' = relu(scale[k]*A + shift[k]) applied during staging (fused BatchNorm+ReLU).
template<int AFFINE>
__global__ __launch_bounds__(256) void k_gemm_mfma(const unsigned short* __restrict__ A,
                                                   const unsigned short* __restrict__ Bt,
                                                   const float* __restrict__ coef,
                                                   unsigned short* __restrict__ Cout,
                                                   int M, int K, int N) {
    __shared__ unsigned short Al[4][128][8];
    __shared__ unsigned short Bl[4][128][8];
    const int tid = threadIdx.x;
    const int bm = blockIdx.y * 128;
    const int bn = blockIdx.x * 128;
    const int w = tid >> 6, l = tid & 63;
    const int wrow = (w >> 1) * 64, wcol = (w & 1) * 64;
    const int kg = l >> 4, lr = l & 15;

    f32x4 acc[4][4];
#pragma unroll
    for (int fm = 0; fm < 4; ++fm)
#pragma unroll
        for (int fn = 0; fn < 4; ++fn) acc[fm][fn] = f32x4{0.f, 0.f, 0.f, 0.f};

    for (int k0 = 0; k0 < K; k0 += 32) {
#pragma unroll
        for (int c = 0; c < 2; ++c) {
            int idx = c * 256 + tid;
            int row = idx >> 2;
            int koff = idx & 3;
            u16x8 va = {0, 0, 0, 0, 0, 0, 0, 0};
            int grow = bm + row;
            if (grow < M)
                va = *reinterpret_cast<const u16x8*>(A + (size_t)grow * K + k0 + koff * 8);
            if (AFFINE) {
                int kb = k0 + koff * 8;
#pragma unroll
                for (int e = 0; e < 8; ++e) {
                    float f = bfu2f((unsigned short)va[e]);
                    f = fmaf(coef[kb + e], f, coef[256 + kb + e]);
                    va[e] = f2bfu(fmaxf(f, 0.f));
                }
            }
            *reinterpret_cast<u16x8*>(&Al[koff][row][0]) = va;
            u16x8 vb = *reinterpret_cast<const u16x8*>(Bt + (size_t)(bn + row) * K + k0 + koff * 8);
            *reinterpret_cast<u16x8*>(&Bl[koff][row][0]) = vb;
        }
        __syncthreads();
        s16x8 a[4], b[4];
#pragma unroll
        for (int fm = 0; fm < 4; ++fm)
            a[fm] = *reinterpret_cast<const s16x8*>(&Al[kg][wrow + fm * 16 + lr][0]);
#pragma unroll
        for (int fn = 0; fn < 4; ++fn)
            b[fn] = *reinterpret_cast<const s16x8*>(&Bl[kg][wcol + fn * 16 + lr][0]);
#pragma unroll
        for (int fm = 0; fm < 4; ++fm)
#pragma unroll
            for (int fn = 0; fn < 4; ++fn)
                acc[fm][fn] = __builtin_amdgcn_mfma_f32_16x16x32_bf16(a[fm], b[fn], acc[fm][fn], 0, 0, 0);
        __syncthreads();
    }
    // C/D layout: col = lane&15, row = (lane>>4)*4 + reg
#pragma unroll
    for (int fm = 0; fm < 4; ++fm)
#pragma unroll
        for (int r = 0; r < 4; ++r) {
            int row = bm + wrow + fm * 16 + kg * 4 + r;
            if (row >= M) continue;
#pragma unroll
            for (int fn = 0; fn < 4; ++fn) {
                int col = bn + wcol + fn * 16 + lr;
                Cout[(size_t)row * N + col] = f2bfu(acc[fm][fn][r]);
            }
        }
}

// ---------------- CSR gather: 32-lane row groups, 8 rows/block, 4-deep unroll ----------------
// out[d,:] = h[d,:]*dinv[d]^2 (+bias) + sum_{s in N(d)} dinv[s]*dinv[d]*h[s,:]
template<int C, int BIAS, int OUTBF, int INF32>
__global__ __launch_bounds__(256) void k_gather(const void* __restrict__ hv,
                                                const float* __restrict__ dinv,
                                                const float* __restrict__ bias,
                                                const int* __restrict__ csr,
                                                const int* __restrict__ rowStart,
                                                void* __restrict__ outv, int n) {
    constexpr int PL = C / 32;  // 8 (C=256) or 4 (C=128)
    int row = blockIdx.x * 8 + (threadIdx.x >> 5);
    if (row >= n) return;
    int lane = threadIdx.x & 31;
    int c0 = lane * PL;

    auto loadRow = [&](int r, float* d) {
        if constexpr (INF32) {
            const float* base = (const float*)hv + (size_t)r * C + c0;
#pragma unroll
            for (int q = 0; q < PL / 4; ++q) {
                float4 v = *reinterpret_cast<const float4*>(base + q * 4);
                d[q * 4 + 0] = v.x; d[q * 4 + 1] = v.y; d[q * 4 + 2] = v.z; d[q * 4 + 3] = v.w;
            }
        } else {
            const unsigned short* base = (const unsigned short*)hv + (size_t)r * C + c0;
            if constexpr (PL == 8) {
                u16x8 v = *reinterpret_cast<const u16x8*>(base);
#pragma unroll
                for (int e = 0; e < 8; ++e) d[e] = bfu2f((unsigned short)v[e]);
            } else {
                ushort4 v = *reinterpret_cast<const ushort4*>(base);
                d[0] = bfu2f(v.x); d[1] = bfu2f(v.y); d[2] = bfu2f(v.z); d[3] = bfu2f(v.w);
            }
        }
    };

    float dd = dinv[row], ws = dd * dd;
    int beg = rowStart[row], end = rowStart[row + 1];
    float a0[PL], a1[PL], a2[PL], a3[PL], t0[PL], t1[PL], t2[PL], t3[PL];
    loadRow(row, t0);
#pragma unroll
    for (int p = 0; p < PL; ++p) { a0[p] = t0[p] * ws; a1[p] = 0.f; a2[p] = 0.f; a3[p] = 0.f; }

    int j = beg;
    for (; j + 4 <= end; j += 4) {
        int s0 = csr[j], s1 = csr[j + 1], s2 = csr[j + 2], s3 = csr[j + 3];
        float w0 = dinv[s0] * dd, w1 = dinv[s1] * dd, w2 = dinv[s2] * dd, w3 = dinv[s3] * dd;
        loadRow(s0, t0); loadRow(s1, t1); loadRow(s2, t2); loadRow(s3, t3);
#pragma unroll
        for (int p = 0; p < PL; ++p) {
            a0[p] += w0 * t0[p]; a1[p] += w1 * t1[p];
            a2[p] += w2 * t2[p]; a3[p] += w3 * t3[p];
        }
    }
    for (; j < end; ++j) {
        int s = csr[j];
        float w = dinv[s] * dd;
        loadRow(s, t0);
#pragma unroll
        for (int p = 0; p < PL; ++p) a0[p] += w * t0[p];
    }
#pragma unroll
    for (int p = 0; p < PL; ++p) {
        a0[p] += (a1[p] + a2[p]) + a3[p];
        if (BIAS) a0[p] += bias[c0 + p];
    }
    if constexpr (OUTBF) {
        unsigned short* o = (unsigned short*)outv + (size_t)row * C + c0;
        if constexpr (PL == 8) {
            u16x8 ov;
#pragma unroll
            for (int e = 0; e < 8; ++e) ov[e] = f2bfu(a0[e]);
            *reinterpret_cast<u16x8*>(o) = ov;
        } else {
            ushort4 ov = {f2bfu(a0[0]), f2bfu(a0[1]), f2bfu(a0[2]), f2bfu(a0[3])};
            *reinterpret_cast<ushort4*>(o) = ov;
        }
    } else {
        float* o = (float*)outv + (size_t)row * C + c0;
#pragma unroll
        for (int q = 0; q < PL / 4; ++q) {
            float4 ov = {a0[q * 4 + 0], a0[q * 4 + 1], a0[q * 4 + 2], a0[q * 4 + 3]};
            *reinterpret_cast<float4*>(o + q * 4) = ov;
        }
    }
}

// ---------------- BatchNorm stats: grid-stride, u16x8 loads, LDS group reduce ----------------
__global__ __launch_bounds__(256) void k_bn_stats_bf(const unsigned short* __restrict__ x,
                                                     float* __restrict__ sum,
                                                     float* __restrict__ sq, int n) {
    __shared__ float smS[8][256];
    __shared__ float smQ[8][256];
    int t = threadIdx.x;
    int g = t >> 5;          // row group 0..7
    int lane = t & 31;
    int c0 = lane * 8;
    float s[8], q[8];
#pragma unroll
    for (int e = 0; e < 8; ++e) { s[e] = 0.f; q[e] = 0.f; }
    int stride = gridDim.x * 8;
    for (int r = blockIdx.x * 8 + g; r < n; r += stride) {
        u16x8 v = *reinterpret_cast<const u16x8*>(x + (size_t)r * 256 + c0);
#pragma unroll
        for (int e = 0; e < 8; ++e) {
            float f = bfu2f((unsigned short)v[e]);
            s[e] += f; q[e] += f * f;
        }
    }
#pragma unroll
    for (int e = 0; e < 8; ++e) { smS[g][c0 + e] = s[e]; smQ[g][c0 + e] = q[e]; }
    __syncthreads();
    float S = 0.f, Q = 0.f;
#pragma unroll
    for (int g2 = 0; g2 < 8; ++g2) { S += smS[g2][t]; Q += smQ[g2][t]; }
    atomAddF(&sum[t], S);
    atomAddF(&sq[t], Q);
}

// coef[j]=g*rstd, coef[256+j]=be-mean*scale; zeroes sum/sq for the next stats pass
__global__ void k_bn_coef(float* __restrict__ sum, float* __restrict__ sq,
                          const float* __restrict__ g, const float* __restrict__ be,
                          float* __restrict__ coef, float invN) {
    int j = threadIdx.x;
    float m = sum[j] * invN;
    float v = sq[j] * invN - m * m;
    float r = rsqrtf(fmaxf(v, 0.f) + 1e-5f);
    float sc = g[j] * r;
    coef[j] = sc;
    coef[256 + j] = be[j] - m * sc;
    sum[j] = 0.f;
    sq[j] = 0.f;
}

// ---------------- atom encoder: 4 rows/block, 64 lanes x float4 ----------------
__global__ __launch_bounds__(256) void k_atom_enc(const int* __restrict__ mol_x,
                                                  const float* __restrict__ emb,
                                                  unsigned short* __restrict__ h) {
    __shared__ int sidx[4][NF];
    int t = threadIdx.x;
    if (t < 4 * NF) sidx[t / NF][t % NF] = mol_x[(blockIdx.x * 4 + t / NF) * NF + t % NF];
    __syncthreads();
    int r = t >> 6, lane = t & 63;
    int c0 = lane * 4;
    int row = blockIdx.x * 4 + r;
    float4 s = {0.f, 0.f, 0.f, 0.f};
#pragma unroll
    for (int f = 0; f < NF; ++f) {
        const float4 v = *reinterpret_cast<const float4*>(emb + ((size_t)f * NV + sidx[r][f]) * DH + c0);
        s.x += v.x; s.y += v.y; s.z += v.z; s.w += v.w;
    }
    ushort4 ov = {f2bfu(s.x), f2bfu(s.y), f2bfu(s.z), f2bfu(s.w)};
    *reinterpret_cast<ushort4*>(h + (size_t)row * DH + c0) = ov;
}

// ---------------- segment pool: 8 row-groups x 16 lanes x u16x8, LDS reduce ----------------
__global__ __launch_bounds__(128) void k_pool_seg(const unsigned short* __restrict__ mfeat,
                                                  const int* __restrict__ batch,
                                                  float* __restrict__ mpool) {
    __shared__ int sr[2];
    __shared__ float smS[8][128];
    int b = blockIdx.x, t = threadIdx.x;
    if (t < 2) {
        int target = b + t;
        int lo = 0, hi = N_MOL;
        while (lo < hi) {
            int mid = (lo + hi) >> 1;
            if (batch[mid] < target) lo = mid + 1; else hi = mid;
        }
        sr[t] = lo;
    }
    __syncthreads();
    int g = t >> 4;        // 0..7
    int lane = t & 15;
    int c0 = lane * 8;
    float s[8];
#pragma unroll
    for (int e = 0; e < 8; ++e) s[e] = 0.f;
    int e1 = sr[1];
    for (int i = sr[0] + g; i < e1; i += 8) {
        u16x8 v = *reinterpret_cast<const u16x8*>(mfeat + (size_t)i * 128 + c0);
#pragma unroll
        for (int e = 0; e < 8; ++e) s[e] += bfu2f((unsigned short)v[e]);
    }
#pragma unroll
    for (int e = 0; e < 8; ++e) smS[g][c0 + e] = s[e];
    __syncthreads();
    float S = 0.f;
#pragma unroll
    for (int g2 = 0; g2 < 8; ++g2) S += smS[g2][t];
    mpool[(size_t)b * 128 + t] = S;
}

// ---------------- head: conv1 ----------------
__global__ __launch_bounds__(64) void k_conv1(const float* __restrict__ dfeat,
                                              const float* __restrict__ mpool,
                                              const float* __restrict__ sfeat,
                                              const int* __restrict__ drug_idx,
                                              const int* __restrict__ dis_idx,
                                              const float* __restrict__ W,
                                              const float* __restrict__ bias,
                                              float* __restrict__ y1) {
    __shared__ float xs[3][128];
    __shared__ float w[54];
    __shared__ float bb[6];
    int b = blockIdx.x, t = threadIdx.x;
    int di = drug_idx[b], si = dis_idx[b];
    const float* r0 = dfeat + (size_t)di * 128;
    const float* r1 = mpool + (size_t)b * 128;
    const float* r2 = sfeat + (size_t)si * 128;
    xs[0][t] = r0[t]; xs[0][t + 64] = r0[t + 64];
    xs[1][t] = r1[t]; xs[1][t + 64] = r1[t + 64];
    xs[2][t] = r2[t]; xs[2][t + 64] = r2[t + 64];
    if (t < 54) w[t] = W[t];
    if (t < 6) bb[t] = bias[t];
    __syncthreads();
    int l0 = 2 * t, l1 = l0 + 1;
#pragma unroll
    for (int o = 0; o < 6; ++o) {
        float ya = bb[o], yb = bb[o];
#pragma unroll
        for (int i = 0; i < 3; ++i) {
            const float* wi = &w[(o * 3 + i) * 3];
            float xm1 = (l0 > 0) ? xs[i][l0 - 1] : 0.f;
            float x0 = xs[i][l0];
            float x1 = xs[i][l1];
            float x2 = (l1 < 127) ? xs[i][l1 + 1] : 0.f;
            ya += wi[0] * xm1 + wi[1] * x0 + wi[2] * x1;
            yb += wi[0] * x0 + wi[1] * x1 + wi[2] * x2;
        }
        y1[((size_t)b * 6 + o) * 64 + t] = fmaxf(ya, yb);
    }
}

// hb layout per 'which' (32 floats): [0..5]=sum [8..13]=sumsq [16..21]=mean [24..29]=rstd
__global__ __launch_bounds__(256) void k_head_stats(const float* __restrict__ y,
                                                    float* __restrict__ hb, int which, int L) {
    int o = blockIdx.x;
    int b0 = blockIdx.y * 16;
    int t = threadIdx.x;
    float s = 0.f, q = 0.f;
    int per = 16 * L;
    for (int idx = t; idx < per; idx += 256) {
        int b = b0 + idx / L;
        int l = idx - (idx / L) * L;
        float v = y[((size_t)b * 6 + o) * L + l];
        s += v; q += v * v;
    }
    __shared__ float sms[4], smq[4];
#pragma unroll
    for (int off = 32; off > 0; off >>= 1) {
        s += __shfl_down(s, off);
        q += __shfl_down(q, off);
    }
    if ((t & 63) == 0) { sms[t >> 6] = s; smq[t >> 6] = q; }
    __syncthreads();
    if (t == 0) {
        float S = 0.f, Q = 0.f;
        for (int i = 0; i < 4; ++i) { S += sms[i]; Q += smq[i]; }
        atomAddF(hb + which * 32 + o, S);
        atomAddF(hb + which * 32 + 8 + o, Q);
    }
}

__global__ void k_bn_fin(float* __restrict__ hb, int which, float invN) {
    int o = threadIdx.x;
    if (o >= 6) return;
    float* p = hb + which * 32;
    float m = p[o] * invN;
    float v = p[8 + o] * invN - m * m;
    p[16 + o] = m;
    p[24 + o] = rsqrtf(fmaxf(v, 0.f) + 1e-5f);
}

// ---------------- head: conv2 ----------------
__global__ __launch_bounds__(64) void k_conv2(const float* __restrict__ y1,
                                              const float* __restrict__ hb,
                                              const float* __restrict__ g1,
                                              const float* __restrict__ be1,
                                              const float* __restrict__ W,
                                              const float* __restrict__ bias,
                                              float* __restrict__ y2) {
    __shared__ float xs[6][64];
    __shared__ float w[108];
    __shared__ float bb[6];
    int b = blockIdx.x, t = threadIdx.x;
    const float* mean = hb + 16;
    const float* rstd = hb + 24;
    for (int idx = t; idx < 384; idx += 64) {
        int o = idx >> 6, l = idx & 63;
        float v = y1[((size_t)b * 6 + o) * 64 + l];
        v = g1[o] * (v - mean[o]) * rstd[o] + be1[o];
        xs[o][l] = fmaxf(v, 0.f);
    }
    for (int idx = t; idx < 108; idx += 64) w[idx] = W[idx];
    if (t < 6) bb[t] = bias[t];
    __syncthreads();
    if (t >= 32) return;
    int l0 = 2 * t, l1 = l0 + 1;
#pragma unroll
    for (int o = 0; o < 6; ++o) {
        float ya = bb[o], yb = bb[o];
#pragma unroll
        for (int i = 0; i < 6; ++i) {
            const float* wi = &w[(o * 6 + i) * 3];
            float xm1 = (l0 > 0) ? xs[i][l0 - 1] : 0.f;
            float x0 = xs[i][l0];
            float x1 = xs[i][l1];
            float x2 = (l1 < 63) ? xs[i][l1 + 1] : 0.f;
            ya += wi[0] * xm1 + wi[1] * x0 + wi[2] * x1;
            yb += wi[0] * x0 + wi[1] * x1 + wi[2] * x2;
        }
        y2[((size_t)b * 6 + o) * 32 + t] = fmaxf(ya, yb);
    }
}

// ---------------- head final ----------------
__global__ __launch_bounds__(128) void k_head(const float* __restrict__ y2,
                                              const float* __restrict__ hb,
                                              const float* __restrict__ g2,
                                              const float* __restrict__ be2,
                                              const float* __restrict__ l1W,
                                              const float* __restrict__ l1b,
                                              const float* __restrict__ l2W,
                                              const float* __restrict__ l2b,
                                              float* __restrict__ out) {
    __shared__ float fs[192];
    __shared__ float sm[2];
    int b = blockIdx.x, t = threadIdx.x;
    const float* mean = hb + 32 + 16;
    const float* rstd = hb + 32 + 24;
    for (int idx = t; idx < 192; idx += 128) {
        int o = idx >> 5, l = idx & 31;
        float v = y2[((size_t)b * 6 + o) * 32 + l];
        v = g2[o] * (v - mean[o]) * rstd[o] + be2[o];
        fs[idx] = fmaxf(v, 0.f);
    }
    __syncthreads();
    float h = l1b[t];
    for (int k = 0; k < 192; ++k)
        h += fs[k] * l1W[k * 128 + t];
    h = fmaxf(h, 0.f);
    float p = h * l2W[t];
#pragma unroll
    for (int off = 32; off > 0; off >>= 1) p += __shfl_down(p, off);
    if ((t & 63) == 0) sm[t >> 6] = p;
    __syncthreads();
    if (t == 0) out[b] = sm[0] + sm[1] + l2b[0];
}

// ---------------- host-side GCN driver ----------------
struct GcnScratch {
    int *cnt, *rowStart, *cursor, *csr, *bsum;
    float *dinv, *bnsum, *bnsq, *coef;
    unsigned short *wt0, *wt1, *wt2;
};

// xin: bf16 [n][Cin] (INF32=0) or f32 (INF32=1). Output: out2bf? bf16 : f32 [n][128]
static void run_gcn(const void* xin, int Cin, int inF32,
                    unsigned short* xb, unsigned short* h_bf, void* outF, int out2bf,
                    const int* ei, int n, int E,
                    const float* W0, const float* W1, const float* W2, const float* b2,
                    const float* g0, const float* g1, const float* be0, const float* be1,
                    GcnScratch& S, hipStream_t stream) {
    const int* src = ei;
    const int* dst = ei + E;
    hipMemsetAsync(S.cnt, 0, (size_t)n * sizeof(int), stream);
    k_count<<<(E + 255) / 256, 256, 0, stream>>>(dst, S.cnt, E);
    int nb = (n + 255) / 256;
    k_scan1<<<nb, 256, 0, stream>>>(S.cnt, S.rowStart, S.bsum, S.dinv, n);
    k_scan2<<<1, 256, 0, stream>>>(S.bsum, nb);
    k_scan3<<<nb, 256, 0, stream>>>(S.rowStart, S.cursor, S.bsum, n, E);
    k_fill<<<(E + 255) / 256, 256, 0, stream>>>(src, dst, S.cursor, S.csr, E);
    int wtot = Cin * 256 + 256 * 256 + 256 * 128;
    k_wcast3<<<(wtot + 255) / 256, 256, 0, stream>>>(W0, W1, W2, S.wt0, S.wt1, S.wt2, Cin);

    int gb = (n + 7) / 8;
    int gy = (n + 127) / 128;
    float invN = 1.0f / (float)n;
    int sb = min(512, (n + 7) / 8);
    // L0: aggregate-first (S·X)·W0 (bias dropped: cancelled by BN)
    if (inF32)
        k_gather<128, 0, 1, 1><<<gb, 256, 0, stream>>>(xin, S.dinv, nullptr, S.csr, S.rowStart, xb, n);
    else
        k_gather<256, 0, 1, 0><<<gb, 256, 0, stream>>>(xin, S.dinv, nullptr, S.csr, S.rowStart, xb, n);
    k_gemm_mfma<0><<<dim3(2, gy), 256, 0, stream>>>(xb, S.wt0, nullptr, h_bf, n, Cin, 256);
    k_bn_stats_bf<<<sb, 256, 0, stream>>>(h_bf, S.bnsum, S.bnsq, n);
    k_bn_coef<<<1, 256, 0, stream>>>(S.bnsum, S.bnsq, g0, be0, S.coef, invN);
    // L1: GEMM(BN0+relu fused on A) -> gather
    k_gemm_mfma<1><<<dim3(2, gy), 256, 0, stream>>>(h_bf, S.wt1, S.coef, xb, n, 256, 256);
    k_gather<256, 0, 1, 0><<<gb, 256, 0, stream>>>(xb, S.dinv, nullptr, S.csr, S.rowStart, h_bf, n);
    k_bn_stats_bf<<<sb, 256, 0, stream>>>(h_bf, S.bnsum, S.bnsq, n);
    k_bn_coef<<<1, 256, 0, stream>>>(S.bnsum, S.bnsq, g1, be1, S.coef, invN);
    // L2: GEMM(BN1+relu fused on A) -> gather + bias (no BN)
    k_gemm_mfma<1><<<dim3(1, gy), 256, 0, stream>>>(h_bf, S.wt2, S.coef, xb, n, 256, 128);
    if (out2bf)
        k_gather<128, 1, 1, 0><<<gb, 256, 0, stream>>>(xb, S.dinv, b2, S.csr, S.rowStart, outF, n);
    else
        k_gather<128, 1, 0, 0><<<gb, 256, 0, stream>>>(xb, S.dinv, b2, S.csr, S.rowStart, outF, n);
}

extern "C" void kernel_launch(void* const* d_in, const int* in_sizes, int n_in,
                              void* d_out, int out_size, void* d_ws, size_t ws_size,
                              hipStream_t stream) {
    float* out = (float*)d_out;
    if (n_in != 52) { k_sentinel<<<16, 256, 0, stream>>>(out, out_size, -111.f); return; }
    if (in_sizes[0] != N_DRUG * DIN || in_sizes[29] != NF * NV * DH || in_sizes[48] != 192 * 128) {
        k_sentinel<<<16, 256, 0, stream>>>(out, out_size, -222.f); return;
    }

    char* w = (char*)d_ws;
    auto alloc = [&](size_t bytes) { char* p = w; w += (bytes + 255) & ~(size_t)255; return p; };
    unsigned short* xb   = (unsigned short*)alloc((size_t)N_MOL * 256 * 2);
    unsigned short* h_bf = (unsigned short*)alloc((size_t)N_MOL * 256 * 2);
    unsigned short* xin  = (unsigned short*)alloc((size_t)N_MOL * 256 * 2);
    float* dfeat = (float*)alloc((size_t)N_DRUG * 128 * 4);
    float* sfeat = (float*)alloc((size_t)N_DIS * 128 * 4);
    float* mpool = (float*)alloc((size_t)BATCH * 128 * 4);
    GcnScratch S;
    S.cnt      = (int*)alloc((size_t)N_MOL * 4);
    S.dinv     = (float*)alloc((size_t)N_MOL * 4);
    S.rowStart = (int*)alloc((size_t)(N_MOL + 1) * 4);
    S.cursor   = (int*)alloc((size_t)N_MOL * 4);
    S.csr      = (int*)alloc((size_t)E_G * 4);
    S.bsum     = (int*)alloc(512 * 4);
    S.bnsum    = (float*)alloc(512 * 4);
    S.bnsq     = S.bnsum + 256;
    S.coef     = (float*)alloc(512 * 4);
    S.wt0      = (unsigned short*)alloc((size_t)256 * 256 * 2);
    S.wt1      = (unsigned short*)alloc((size_t)256 * 256 * 2);
    S.wt2      = (unsigned short*)alloc((size_t)256 * 256 * 2);
    float* hstat  = (float*)alloc(64 * 4);
    float* y1     = (float*)alloc((size_t)BATCH * 6 * 64 * 4);
    float* y2     = (float*)alloc((size_t)BATCH * 6 * 32 * 4);
    if ((size_t)(w - (char*)d_ws) > ws_size) {
        k_sentinel<<<16, 256, 0, stream>>>(out, out_size, -333.f); return;
    }

    const float* drug_x  = (const float*)d_in[0];
    const int* drug_ei   = (const int*)d_in[1];
    const int* drug_idx  = (const int*)d_in[2];
    const float* dis_x   = (const float*)d_in[3];
    const int* dis_ei    = (const int*)d_in[4];
    const int* dis_idx   = (const int*)d_in[5];
    const int* mol_x     = (const int*)d_in[6];
    const int* mol_ei    = (const int*)d_in[7];
    const int* mol_b     = (const int*)d_in[8];
    const float *dr_W0 = (const float*)d_in[9], *dr_W1 = (const float*)d_in[10], *dr_W2 = (const float*)d_in[11];
    const float *dr_b2 = (const float*)d_in[14];
    const float *dr_g0 = (const float*)d_in[15], *dr_g1 = (const float*)d_in[16];
    const float *dr_be0 = (const float*)d_in[17], *dr_be1 = (const float*)d_in[18];
    const float *di_W0 = (const float*)d_in[19], *di_W1 = (const float*)d_in[20], *di_W2 = (const float*)d_in[21];
    const float *di_b2 = (const float*)d_in[24];
    const float *di_g0 = (const float*)d_in[25], *di_g1 = (const float*)d_in[26];
    const float *di_be0 = (const float*)d_in[27], *di_be1 = (const float*)d_in[28];
    const float* mol_emb = (const float*)d_in[29];
    const float *mo_W0 = (const float*)d_in[30], *mo_W1 = (const float*)d_in[31], *mo_W2 = (const float*)d_in[32];
    const float *mo_b2 = (const float*)d_in[35];
    const float *mo_g0 = (const float*)d_in[36], *mo_g1 = (const float*)d_in[37];
    const float *mo_be0 = (const float*)d_in[38], *mo_be1 = (const float*)d_in[39];
    const float *c1_W = (const float*)d_in[40], *c1_b = (const float*)d_in[41];
    const float *c1_g = (const float*)d_in[42], *c1_be = (const float*)d_in[43];
    const float *c2_W = (const float*)d_in[44], *c2_b = (const float*)d_in[45];
    const float *c2_g = (const float*)d_in[46], *c2_be = (const float*)d_in[47];
    const float *l1_W = (const float*)d_in[48], *l1_b = (const float*)d_in[49];
    const float *l2_W = (const float*)d_in[50], *l2_b = (const float*)d_in[51];

    hipMemsetAsync(S.bnsum, 0, 512 * sizeof(float), stream);   // bn_coef self-zeroes thereafter

    // ---- drug GCN -> dfeat (f32) ----
    run_gcn(drug_x, DIN, 1, xb, h_bf, dfeat, 0, drug_ei, N_DRUG, E_G,
            dr_W0, dr_W1, dr_W2, dr_b2, dr_g0, dr_g1, dr_be0, dr_be1, S, stream);

    // ---- disease GCN -> sfeat (f32) ----
    run_gcn(dis_x, DIN, 1, xb, h_bf, sfeat, 0, dis_ei, N_DIS, E_G,
            di_W0, di_W1, di_W2, di_b2, di_g0, di_g1, di_be0, di_be1, S, stream);

    // ---- mol: atom encoder -> GCN (bf16 out) -> pool ----
    k_atom_enc<<<N_MOL / 4, 256, 0, stream>>>(mol_x, mol_emb, xin);
    run_gcn(xin, 256, 0, xb, h_bf, h_bf, 1, mol_ei, N_MOL, E_MOL,
            mo_W0, mo_W1, mo_W2, mo_b2, mo_g0, mo_g1, mo_be0, mo_be1, S, stream);
    k_pool_seg<<<BATCH, 128, 0, stream>>>(h_bf, mol_b, mpool);

    // ---- head ----
    hipMemsetAsync(hstat, 0, 64 * 4, stream);
    k_conv1<<<BATCH, 64, 0, stream>>>(dfeat, mpool, sfeat, drug_idx, dis_idx, c1_W, c1_b, y1);
    k_head_stats<<<dim3(6, BATCH / 16), 256, 0, stream>>>(y1, hstat, 0, 64);
    k_bn_fin<<<1, 8, 0, stream>>>(hstat, 0, 1.0f / (BATCH * 64.0f));
    k_conv2<<<BATCH, 64, 0, stream>>>(y1, hstat, c1_g, c1_be, c2_W, c2_b, y2);
    k_head_stats<<<dim3(6, BATCH / 16), 256, 0, stream>>>(y2, hstat, 1, 32);
    k_bn_fin<<<1, 8, 0, stream>>>(hstat, 1, 1.0f / (BATCH * 32.0f));
    k_head<<<BATCH, 128, 0, stream>>>(y2, hstat, c2_g, c2_be, l1_W, l1_b, l2_W, l2_b, out);
}

// Round 9
// 709.247 us; speedup vs baseline: 12.5036x; 1.0652x over previous
//
#include <hip/hip_runtime.h>
#include <hip/hip_bf16.h>

#define N_DRUG 20000
#define N_DIS  20000
#define E_G    320000
#define BATCH  4096
#define N_MOL  65536
#define E_MOL  262144
#define DIN    128
#define DH     256
#define DOUT   128
#define NF     9
#define NV     128

typedef short s16x8 __attribute__((ext_vector_type(8)));
typedef unsigned short u16x8 __attribute__((ext_vector_type(8)));
typedef float f32x4 __attribute__((ext_vector_type(4)));

__device__ __forceinline__ float bfu2f(unsigned short u) {
    return __uint_as_float(((unsigned int)u) << 16);
}
__device__ __forceinline__ unsigned short f2bfu(float f) {
    __hip_bfloat16 b = __float2bfloat16(f);
    return *reinterpret_cast<unsigned short*>(&b);
}
__device__ __forceinline__ void atomAddF(float* p, float v) { atomicAdd(p, v); }

// ---------------- misc ----------------
__global__ void k_sentinel(float* out, int n, float v) {
    int i = blockIdx.x * 256 + threadIdx.x;
    if (i < n) out[i] = v;
}

// 3 weight transposes in one kernel: W[K][N] f32 -> Wt[N][K] bf16
__global__ void k_wcast3(const float* __restrict__ W0, const float* __restrict__ W1,
                         const float* __restrict__ W2,
                         unsigned short* __restrict__ T0, unsigned short* __restrict__ T1,
                         unsigned short* __restrict__ T2, int Cin) {
    int i = blockIdx.x * 256 + threadIdx.x;
    int t0 = Cin * 256, t1 = 256 * 256, t2 = 256 * 128;
    if (i < t0) {
        int k = i / 256, c = i - k * 256;
        T0[(size_t)c * Cin + k] = f2bfu(W0[i]);
    } else if (i < t0 + t1) {
        int e = i - t0;
        int k = e / 256, c = e - k * 256;
        T1[(size_t)c * 256 + k] = f2bfu(W1[e]);
    } else if (i < t0 + t1 + t2) {
        int e = i - t0 - t1;
        int k = e / 128, c = e - k * 128;
        T2[(size_t)c * 256 + k] = f2bfu(W2[e]);
    }
}

// ---------------- degree ----------------
__global__ void k_count(const int* __restrict__ dst, int* __restrict__ cnt, int E) {
    int e = blockIdx.x * 256 + threadIdx.x;
    if (e < E) atomicAdd(&cnt[dst[e]], 1);
}

// ---------------- CSR build (scan1 also computes dinv) ----------------
__global__ void k_scan1(const int* __restrict__ cnt, int* __restrict__ rowStart,
                        int* __restrict__ bsum, float* __restrict__ dinv, int n) {
    __shared__ int sh[256];
    int i = blockIdx.x * 256 + threadIdx.x;
    int v = (i < n) ? cnt[i] : 0;
    if (i < n) dinv[i] = rsqrtf(1.0f + (float)v);
    sh[threadIdx.x] = v;
    __syncthreads();
    for (int off = 1; off < 256; off <<= 1) {
        int t = (threadIdx.x >= off) ? sh[threadIdx.x - off] : 0;
        __syncthreads();
        sh[threadIdx.x] += t;
        __syncthreads();
    }
    if (i < n) rowStart[i] = sh[threadIdx.x] - v;
    if (threadIdx.x == 255) bsum[blockIdx.x] = sh[255];
}
__global__ void k_scan2(int* __restrict__ bsum, int nb) {
    __shared__ int sh[256];
    int t = threadIdx.x;
    int v = (t < nb) ? bsum[t] : 0;
    sh[t] = v;
    __syncthreads();
    for (int off = 1; off < 256; off <<= 1) {
        int u = (t >= off) ? sh[t - off] : 0;
        __syncthreads();
        sh[t] += u;
        __syncthreads();
    }
    if (t < nb) bsum[t] = sh[t] - v;
}
__global__ void k_scan3(int* __restrict__ rowStart, int* __restrict__ cursor,
                        const int* __restrict__ bsum, int n, int E) {
    int i = blockIdx.x * 256 + threadIdx.x;
    if (i < n) {
        int r = rowStart[i] + bsum[blockIdx.x];
        rowStart[i] = r;
        cursor[i] = r;
    }
    if (i == 0) rowStart[n] = E;
}
__global__ void k_fill(const int* __restrict__ src, const int* __restrict__ dst,
                       int* __restrict__ cursor, int* __restrict__ csr, int E) {
    int e = blockIdx.x * 256 + threadIdx.x;
    if (e < E) {
        int p = atomicAdd(&cursor[dst[e]], 1);
        csr[p] = src[e];
    }
}

// ---------------- MFMA GEMM: C[M,N]bf16 = act(A[M,K]bf16) @ B (Bt[N][K]bf16) ----------------
// AFFINE: A' = relu(scale[k]*A + shift[k]) applied during staging (fused BatchNorm+ReLU).
template<int AFFINE>
__global__ __launch_bounds__(256) void k_gemm_mfma(const unsigned short* __restrict__ A,
                                                   const unsigned short* __restrict__ Bt,
                                                   const float* __restrict__ coef,
                                                   unsigned short* __restrict__ Cout,
                                                   int M, int K, int N) {
    __shared__ unsigned short Al[4][128][8];
    __shared__ unsigned short Bl[4][128][8];
    const int tid = threadIdx.x;
    const int bm = blockIdx.y * 128;
    const int bn = blockIdx.x * 128;
    const int w = tid >> 6, l = tid & 63;
    const int wrow = (w >> 1) * 64, wcol = (w & 1) * 64;
    const int kg = l >> 4, lr = l & 15;

    f32x4 acc[4][4];
#pragma unroll
    for (int fm = 0; fm < 4; ++fm)
#pragma unroll
        for (int fn = 0; fn < 4; ++fn) acc[fm][fn] = f32x4{0.f, 0.f, 0.f, 0.f};

    for (int k0 = 0; k0 < K; k0 += 32) {
#pragma unroll
        for (int c = 0; c < 2; ++c) {
            int idx = c * 256 + tid;
            int row = idx >> 2;
            int koff = idx & 3;
            u16x8 va = {0, 0, 0, 0, 0, 0, 0, 0};
            int grow = bm + row;
            if (grow < M)
                va = *reinterpret_cast<const u16x8*>(A + (size_t)grow * K + k0 + koff * 8);
            if (AFFINE) {
                int kb = k0 + koff * 8;
#pragma unroll
                for (int e = 0; e < 8; ++e) {
                    float f = bfu2f((unsigned short)va[e]);
                    f = fmaf(coef[kb + e], f, coef[256 + kb + e]);
                    va[e] = f2bfu(fmaxf(f, 0.f));
                }
            }
            *reinterpret_cast<u16x8*>(&Al[koff][row][0]) = va;
            u16x8 vb = *reinterpret_cast<const u16x8*>(Bt + (size_t)(bn + row) * K + k0 + koff * 8);
            *reinterpret_cast<u16x8*>(&Bl[koff][row][0]) = vb;
        }
        __syncthreads();
        s16x8 a[4], b[4];
#pragma unroll
        for (int fm = 0; fm < 4; ++fm)
            a[fm] = *reinterpret_cast<const s16x8*>(&Al[kg][wrow + fm * 16 + lr][0]);
#pragma unroll
        for (int fn = 0; fn < 4; ++fn)
            b[fn] = *reinterpret_cast<const s16x8*>(&Bl[kg][wcol + fn * 16 + lr][0]);
#pragma unroll
        for (int fm = 0; fm < 4; ++fm)
#pragma unroll
            for (int fn = 0; fn < 4; ++fn)
                acc[fm][fn] = __builtin_amdgcn_mfma_f32_16x16x32_bf16(a[fm], b[fn], acc[fm][fn], 0, 0, 0);
        __syncthreads();
    }
    // C/D layout: col = lane&15, row = (lane>>4)*4 + reg
#pragma unroll
    for (int fm = 0; fm < 4; ++fm)
#pragma unroll
        for (int r = 0; r < 4; ++r) {
            int row = bm + wrow + fm * 16 + kg * 4 + r;
            if (row >= M) continue;
#pragma unroll
            for (int fn = 0; fn < 4; ++fn) {
                int col = bn + wcol + fn * 16 + lr;
                Cout[(size_t)row * N + col] = f2bfu(acc[fm][fn][r]);
            }
        }
}

// ---------------- CSR gather: 32-lane row groups, 8 rows/block, 4-deep unroll ----------------
// out[d,:] = h[d,:]*dinv[d]^2 (+bias) + sum_{s in N(d)} dinv[s]*dinv[d]*h[s,:]
template<int C, int BIAS, int OUTBF, int INF32>
__global__ __launch_bounds__(256) void k_gather(const void* __restrict__ hv,
                                                const float* __restrict__ dinv,
                                                const float* __restrict__ bias,
                                                const int* __restrict__ csr,
                                                const int* __restrict__ rowStart,
                                                void* __restrict__ outv, int n) {
    constexpr int PL = C / 32;  // 8 (C=256) or 4 (C=128)
    int row = blockIdx.x * 8 + (threadIdx.x >> 5);
    if (row >= n) return;
    int lane = threadIdx.x & 31;
    int c0 = lane * PL;

    auto loadRow = [&](int r, float* d) {
        if constexpr (INF32) {
            const float* base = (const float*)hv + (size_t)r * C + c0;
#pragma unroll
            for (int q = 0; q < PL / 4; ++q) {
                float4 v = *reinterpret_cast<const float4*>(base + q * 4);
                d[q * 4 + 0] = v.x; d[q * 4 + 1] = v.y; d[q * 4 + 2] = v.z; d[q * 4 + 3] = v.w;
            }
        } else {
            const unsigned short* base = (const unsigned short*)hv + (size_t)r * C + c0;
            if constexpr (PL == 8) {
                u16x8 v = *reinterpret_cast<const u16x8*>(base);
#pragma unroll
                for (int e = 0; e < 8; ++e) d[e] = bfu2f((unsigned short)v[e]);
            } else {
                ushort4 v = *reinterpret_cast<const ushort4*>(base);
                d[0] = bfu2f(v.x); d[1] = bfu2f(v.y); d[2] = bfu2f(v.z); d[3] = bfu2f(v.w);
            }
        }
    };

    float dd = dinv[row], ws = dd * dd;
    int beg = rowStart[row], end = rowStart[row + 1];
    float a0[PL], a1[PL], a2[PL], a3[PL], t0[PL], t1[PL], t2[PL], t3[PL];
    loadRow(row, t0);
#pragma unroll
    for (int p = 0; p < PL; ++p) { a0[p] = t0[p] * ws; a1[p] = 0.f; a2[p] = 0.f; a3[p] = 0.f; }

    int j = beg;
    for (; j + 4 <= end; j += 4) {
        int s0 = csr[j], s1 = csr[j + 1], s2 = csr[j + 2], s3 = csr[j + 3];
        float w0 = dinv[s0] * dd, w1 = dinv[s1] * dd, w2 = dinv[s2] * dd, w3 = dinv[s3] * dd;
        loadRow(s0, t0); loadRow(s1, t1); loadRow(s2, t2); loadRow(s3, t3);
#pragma unroll
        for (int p = 0; p < PL; ++p) {
            a0[p] += w0 * t0[p]; a1[p] += w1 * t1[p];
            a2[p] += w2 * t2[p]; a3[p] += w3 * t3[p];
        }
    }
    for (; j < end; ++j) {
        int s = csr[j];
        float w = dinv[s] * dd;
        loadRow(s, t0);
#pragma unroll
        for (int p = 0; p < PL; ++p) a0[p] += w * t0[p];
    }
#pragma unroll
    for (int p = 0; p < PL; ++p) {
        a0[p] += (a1[p] + a2[p]) + a3[p];
        if (BIAS) a0[p] += bias[c0 + p];
    }
    if constexpr (OUTBF) {
        unsigned short* o = (unsigned short*)outv + (size_t)row * C + c0;
        if constexpr (PL == 8) {
            u16x8 ov;
#pragma unroll
            for (int e = 0; e < 8; ++e) ov[e] = f2bfu(a0[e]);
            *reinterpret_cast<u16x8*>(o) = ov;
        } else {
            ushort4 ov = {f2bfu(a0[0]), f2bfu(a0[1]), f2bfu(a0[2]), f2bfu(a0[3])};
            *reinterpret_cast<ushort4*>(o) = ov;
        }
    } else {
        float* o = (float*)outv + (size_t)row * C + c0;
#pragma unroll
        for (int q = 0; q < PL / 4; ++q) {
            float4 ov = {a0[q * 4 + 0], a0[q * 4 + 1], a0[q * 4 + 2], a0[q * 4 + 3]};
            *reinterpret_cast<float4*>(o + q * 4) = ov;
        }
    }
}

// ---------------- BatchNorm stats: grid-stride, u16x8 loads, LDS group reduce ----------------
__global__ __launch_bounds__(256) void k_bn_stats_bf(const unsigned short* __restrict__ x,
                                                     float* __restrict__ sum,
                                                     float* __restrict__ sq, int n) {
    __shared__ float smS[8][256];
    __shared__ float smQ[8][256];
    int t = threadIdx.x;
    int g = t >> 5;          // row group 0..7
    int lane = t & 31;
    int c0 = lane * 8;
    float s[8], q[8];
#pragma unroll
    for (int e = 0; e < 8; ++e) { s[e] = 0.f; q[e] = 0.f; }
    int stride = gridDim.x * 8;
    for (int r = blockIdx.x * 8 + g; r < n; r += stride) {
        u16x8 v = *reinterpret_cast<const u16x8*>(x + (size_t)r * 256 + c0);
#pragma unroll
        for (int e = 0; e < 8; ++e) {
            float f = bfu2f((unsigned short)v[e]);
            s[e] += f; q[e] += f * f;
        }
    }
#pragma unroll
    for (int e = 0; e < 8; ++e) { smS[g][c0 + e] = s[e]; smQ[g][c0 + e] = q[e]; }
    __syncthreads();
    float S = 0.f, Q = 0.f;
#pragma unroll
    for (int g2 = 0; g2 < 8; ++g2) { S += smS[g2][t]; Q += smQ[g2][t]; }
    atomAddF(&sum[t], S);
    atomAddF(&sq[t], Q);
}

// coef[j]=g*rstd, coef[256+j]=be-mean*scale; zeroes sum/sq for the next stats pass
__global__ void k_bn_coef(float* __restrict__ sum, float* __restrict__ sq,
                          const float* __restrict__ g, const float* __restrict__ be,
                          float* __restrict__ coef, float invN) {
    int j = threadIdx.x;
    float m = sum[j] * invN;
    float v = sq[j] * invN - m * m;
    float r = rsqrtf(fmaxf(v, 0.f) + 1e-5f);
    float sc = g[j] * r;
    coef[j] = sc;
    coef[256 + j] = be[j] - m * sc;
    sum[j] = 0.f;
    sq[j] = 0.f;
}

// ---------------- atom encoder: 4 rows/block, 64 lanes x float4 ----------------
__global__ __launch_bounds__(256) void k_atom_enc(const int* __restrict__ mol_x,
                                                  const float* __restrict__ emb,
                                                  unsigned short* __restrict__ h) {
    __shared__ int sidx[4][NF];
    int t = threadIdx.x;
    if (t < 4 * NF) sidx[t / NF][t % NF] = mol_x[(blockIdx.x * 4 + t / NF) * NF + t % NF];
    __syncthreads();
    int r = t >> 6, lane = t & 63;
    int c0 = lane * 4;
    int row = blockIdx.x * 4 + r;
    float4 s = {0.f, 0.f, 0.f, 0.f};
#pragma unroll
    for (int f = 0; f < NF; ++f) {
        const float4 v = *reinterpret_cast<const float4*>(emb + ((size_t)f * NV + sidx[r][f]) * DH + c0);
        s.x += v.x; s.y += v.y; s.z += v.z; s.w += v.w;
    }
    ushort4 ov = {f2bfu(s.x), f2bfu(s.y), f2bfu(s.z), f2bfu(s.w)};
    *reinterpret_cast<ushort4*>(h + (size_t)row * DH + c0) = ov;
}

// ---------------- segment pool: 8 row-groups x 16 lanes x u16x8, LDS reduce ----------------
__global__ __launch_bounds__(128) void k_pool_seg(const unsigned short* __restrict__ mfeat,
                                                  const int* __restrict__ batch,
                                                  float* __restrict__ mpool) {
    __shared__ int sr[2];
    __shared__ float smS[8][128];
    int b = blockIdx.x, t = threadIdx.x;
    if (t < 2) {
        int target = b + t;
        int lo = 0, hi = N_MOL;
        while (lo < hi) {
            int mid = (lo + hi) >> 1;
            if (batch[mid] < target) lo = mid + 1; else hi = mid;
        }
        sr[t] = lo;
    }
    __syncthreads();
    int g = t >> 4;        // 0..7
    int lane = t & 15;
    int c0 = lane * 8;
    float s[8];
#pragma unroll
    for (int e = 0; e < 8; ++e) s[e] = 0.f;
    int e1 = sr[1];
    for (int i = sr[0] + g; i < e1; i += 8) {
        u16x8 v = *reinterpret_cast<const u16x8*>(mfeat + (size_t)i * 128 + c0);
#pragma unroll
        for (int e = 0; e < 8; ++e) s[e] += bfu2f((unsigned short)v[e]);
    }
#pragma unroll
    for (int e = 0; e < 8; ++e) smS[g][c0 + e] = s[e];
    __syncthreads();
    float S = 0.f;
#pragma unroll
    for (int g2 = 0; g2 < 8; ++g2) S += smS[g2][t];
    mpool[(size_t)b * 128 + t] = S;
}

// ---------------- head: conv1 ----------------
__global__ __launch_bounds__(64) void k_conv1(const float* __restrict__ dfeat,
                                              const float* __restrict__ mpool,
                                              const float* __restrict__ sfeat,
                                              const int* __restrict__ drug_idx,
                                              const int* __restrict__ dis_idx,
                                              const float* __restrict__ W,
                                              const float* __restrict__ bias,
                                              float* __restrict__ y1) {
    __shared__ float xs[3][128];
    __shared__ float w[54];
    __shared__ float bb[6];
    int b = blockIdx.x, t = threadIdx.x;
    int di = drug_idx[b], si = dis_idx[b];
    const float* r0 = dfeat + (size_t)di * 128;
    const float* r1 = mpool + (size_t)b * 128;
    const float* r2 = sfeat + (size_t)si * 128;
    xs[0][t] = r0[t]; xs[0][t + 64] = r0[t + 64];
    xs[1][t] = r1[t]; xs[1][t + 64] = r1[t + 64];
    xs[2][t] = r2[t]; xs[2][t + 64] = r2[t + 64];
    if (t < 54) w[t] = W[t];
    if (t < 6) bb[t] = bias[t];
    __syncthreads();
    int l0 = 2 * t, l1 = l0 + 1;
#pragma unroll
    for (int o = 0; o < 6; ++o) {
        float ya = bb[o], yb = bb[o];
#pragma unroll
        for (int i = 0; i < 3; ++i) {
            const float* wi = &w[(o * 3 + i) * 3];
            float xm1 = (l0 > 0) ? xs[i][l0 - 1] : 0.f;
            float x0 = xs[i][l0];
            float x1 = xs[i][l1];
            float x2 = (l1 < 127) ? xs[i][l1 + 1] : 0.f;
            ya += wi[0] * xm1 + wi[1] * x0 + wi[2] * x1;
            yb += wi[0] * x0 + wi[1] * x1 + wi[2] * x2;
        }
        y1[((size_t)b * 6 + o) * 64 + t] = fmaxf(ya, yb);
    }
}

// hb layout per 'which' (32 floats): [0..5]=sum [8..13]=sumsq [16..21]=mean [24..29]=rstd
// grid (6, 16): 16 blocks per channel -> low atomic contention (was 256, 42us CAS chain)
__global__ __launch_bounds__(256) void k_head_stats(const float* __restrict__ y,
                                                    float* __restrict__ hb, int which, int L) {
    int o = blockIdx.x;
    int b0 = blockIdx.y * 256;   // 256 batches per block
    int t = threadIdx.x;
    float s = 0.f, q = 0.f;
    int per = 256 * L;
    for (int idx = t; idx < per; idx += 256) {
        int b = b0 + idx / L;
        int l = idx - (idx / L) * L;
        float v = y[((size_t)b * 6 + o) * L + l];
        s += v; q += v * v;
    }
    __shared__ float sms[4], smq[4];
#pragma unroll
    for (int off = 32; off > 0; off >>= 1) {
        s += __shfl_down(s, off);
        q += __shfl_down(q, off);
    }
    if ((t & 63) == 0) { sms[t >> 6] = s; smq[t >> 6] = q; }
    __syncthreads();
    if (t == 0) {
        float S = 0.f, Q = 0.f;
        for (int i = 0; i < 4; ++i) { S += sms[i]; Q += smq[i]; }
        atomAddF(hb + which * 32 + o, S);
        atomAddF(hb + which * 32 + 8 + o, Q);
    }
}

__global__ void k_bn_fin(float* __restrict__ hb, int which, float invN) {
    int o = threadIdx.x;
    if (o >= 6) return;
    float* p = hb + which * 32;
    float m = p[o] * invN;
    float v = p[8 + o] * invN - m * m;
    p[16 + o] = m;
    p[24 + o] = rsqrtf(fmaxf(v, 0.f) + 1e-5f);
}

// ---------------- head: conv2 ----------------
__global__ __launch_bounds__(64) void k_conv2(const float* __restrict__ y1,
                                              const float* __restrict__ hb,
                                              const float* __restrict__ g1,
                                              const float* __restrict__ be1,
                                              const float* __restrict__ W,
                                              const float* __restrict__ bias,
                                              float* __restrict__ y2) {
    __shared__ float xs[6][64];
    __shared__ float w[108];
    __shared__ float bb[6];
    int b = blockIdx.x, t = threadIdx.x;
    const float* mean = hb + 16;
    const float* rstd = hb + 24;
    for (int idx = t; idx < 384; idx += 64) {
        int o = idx >> 6, l = idx & 63;
        float v = y1[((size_t)b * 6 + o) * 64 + l];
        v = g1[o] * (v - mean[o]) * rstd[o] + be1[o];
        xs[o][l] = fmaxf(v, 0.f);
    }
    for (int idx = t; idx < 108; idx += 64) w[idx] = W[idx];
    if (t < 6) bb[t] = bias[t];
    __syncthreads();
    if (t >= 32) return;
    int l0 = 2 * t, l1 = l0 + 1;
#pragma unroll
    for (int o = 0; o < 6; ++o) {
        float ya = bb[o], yb = bb[o];
#pragma unroll
        for (int i = 0; i < 6; ++i) {
            const float* wi = &w[(o * 6 + i) * 3];
            float xm1 = (l0 > 0) ? xs[i][l0 - 1] : 0.f;
            float x0 = xs[i][l0];
            float x1 = xs[i][l1];
            float x2 = (l1 < 63) ? xs[i][l1 + 1] : 0.f;
            ya += wi[0] * xm1 + wi[1] * x0 + wi[2] * x1;
            yb += wi[0] * x0 + wi[1] * x1 + wi[2] * x2;
        }
        y2[((size_t)b * 6 + o) * 32 + t] = fmaxf(ya, yb);
    }
}

// ---------------- head final ----------------
__global__ __launch_bounds__(128) void k_head(const float* __restrict__ y2,
                                              const float* __restrict__ hb,
                                              const float* __restrict__ g2,
                                              const float* __restrict__ be2,
                                              const float* __restrict__ l1W,
                                              const float* __restrict__ l1b,
                                              const float* __restrict__ l2W,
                                              const float* __restrict__ l2b,
                                              float* __restrict__ out) {
    __shared__ float fs[192];
    __shared__ float sm[2];
    int b = blockIdx.x, t = threadIdx.x;
    const float* mean = hb + 32 + 16;
    const float* rstd = hb + 32 + 24;
    for (int idx = t; idx < 192; idx += 128) {
        int o = idx >> 5, l = idx & 31;
        float v = y2[((size_t)b * 6 + o) * 32 + l];
        v = g2[o] * (v - mean[o]) * rstd[o] + be2[o];
        fs[idx] = fmaxf(v, 0.f);
    }
    __syncthreads();
    float h = l1b[t];
    for (int k = 0; k < 192; ++k)
        h += fs[k] * l1W[k * 128 + t];
    h = fmaxf(h, 0.f);
    float p = h * l2W[t];
#pragma unroll
    for (int off = 32; off > 0; off >>= 1) p += __shfl_down(p, off);
    if ((t & 63) == 0) sm[t >> 6] = p;
    __syncthreads();
    if (t == 0) out[b] = sm[0] + sm[1] + l2b[0];
}

// ---------------- host-side GCN driver ----------------
struct GcnScratch {
    int *cnt, *rowStart, *cursor, *csr, *bsum;
    float *dinv, *bnsum, *bnsq, *coef;
    unsigned short *wt0, *wt1, *wt2;
};

// xin: bf16 [n][Cin] (INF32=0) or f32 (INF32=1). Output: out2bf? bf16 : f32 [n][128]
static void run_gcn(const void* xin, int Cin, int inF32,
                    unsigned short* xb, unsigned short* h_bf, void* outF, int out2bf,
                    const int* ei, int n, int E,
                    const float* W0, const float* W1, const float* W2, const float* b2,
                    const float* g0, const float* g1, const float* be0, const float* be1,
                    GcnScratch& S, hipStream_t stream) {
    const int* src = ei;
    const int* dst = ei + E;
    hipMemsetAsync(S.cnt, 0, (size_t)n * sizeof(int), stream);
    k_count<<<(E + 255) / 256, 256, 0, stream>>>(dst, S.cnt, E);
    int nb = (n + 255) / 256;
    k_scan1<<<nb, 256, 0, stream>>>(S.cnt, S.rowStart, S.bsum, S.dinv, n);
    k_scan2<<<1, 256, 0, stream>>>(S.bsum, nb);
    k_scan3<<<nb, 256, 0, stream>>>(S.rowStart, S.cursor, S.bsum, n, E);
    k_fill<<<(E + 255) / 256, 256, 0, stream>>>(src, dst, S.cursor, S.csr, E);
    int wtot = Cin * 256 + 256 * 256 + 256 * 128;
    k_wcast3<<<(wtot + 255) / 256, 256, 0, stream>>>(W0, W1, W2, S.wt0, S.wt1, S.wt2, Cin);

    int gb = (n + 7) / 8;
    int gy = (n + 127) / 128;
    float invN = 1.0f / (float)n;
    int sb = min(512, (n + 7) / 8);
    // L0: aggregate-first (S·X)·W0 (bias dropped: cancelled by BN)
    if (inF32)
        k_gather<128, 0, 1, 1><<<gb, 256, 0, stream>>>(xin, S.dinv, nullptr, S.csr, S.rowStart, xb, n);
    else
        k_gather<256, 0, 1, 0><<<gb, 256, 0, stream>>>(xin, S.dinv, nullptr, S.csr, S.rowStart, xb, n);
    k_gemm_mfma<0><<<dim3(2, gy), 256, 0, stream>>>(xb, S.wt0, nullptr, h_bf, n, Cin, 256);
    k_bn_stats_bf<<<sb, 256, 0, stream>>>(h_bf, S.bnsum, S.bnsq, n);
    k_bn_coef<<<1, 256, 0, stream>>>(S.bnsum, S.bnsq, g0, be0, S.coef, invN);
    // L1: GEMM(BN0+relu fused on A) -> gather
    k_gemm_mfma<1><<<dim3(2, gy), 256, 0, stream>>>(h_bf, S.wt1, S.coef, xb, n, 256, 256);
    k_gather<256, 0, 1, 0><<<gb, 256, 0, stream>>>(xb, S.dinv, nullptr, S.csr, S.rowStart, h_bf, n);
    k_bn_stats_bf<<<sb, 256, 0, stream>>>(h_bf, S.bnsum, S.bnsq, n);
    k_bn_coef<<<1, 256, 0, stream>>>(S.bnsum, S.bnsq, g1, be1, S.coef, invN);
    // L2: GEMM(BN1+relu fused on A) -> gather + bias (no BN)
    k_gemm_mfma<1><<<dim3(1, gy), 256, 0, stream>>>(h_bf, S.wt2, S.coef, xb, n, 256, 128);
    if (out2bf)
        k_gather<128, 1, 1, 0><<<gb, 256, 0, stream>>>(xb, S.dinv, b2, S.csr, S.rowStart, outF, n);
    else
        k_gather<128, 1, 0, 0><<<gb, 256, 0, stream>>>(xb, S.dinv, b2, S.csr, S.rowStart, outF, n);
}

extern "C" void kernel_launch(void* const* d_in, const int* in_sizes, int n_in,
                              void* d_out, int out_size, void* d_ws, size_t ws_size,
                              hipStream_t stream) {
    float* out = (float*)d_out;
    if (n_in != 52) { k_sentinel<<<16, 256, 0, stream>>>(out, out_size, -111.f); return; }
    if (in_sizes[0] != N_DRUG * DIN || in_sizes[29] != NF * NV * DH || in_sizes[48] != 192 * 128) {
        k_sentinel<<<16, 256, 0, stream>>>(out, out_size, -222.f); return;
    }

    char* w = (char*)d_ws;
    auto alloc = [&](size_t bytes) { char* p = w; w += (bytes + 255) & ~(size_t)255; return p; };
    unsigned short* xb   = (unsigned short*)alloc((size_t)N_MOL * 256 * 2);
    unsigned short* h_bf = (unsigned short*)alloc((size_t)N_MOL * 256 * 2);
    unsigned short* xin  = (unsigned short*)alloc((size_t)N_MOL * 256 * 2);
    float* dfeat = (float*)alloc((size_t)N_DRUG * 128 * 4);
    float* sfeat = (float*)alloc((size_t)N_DIS * 128 * 4);
    float* mpool = (float*)alloc((size_t)BATCH * 128 * 4);
    GcnScratch S;
    S.cnt      = (int*)alloc((size_t)N_MOL * 4);
    S.dinv     = (float*)alloc((size_t)N_MOL * 4);
    S.rowStart = (int*)alloc((size_t)(N_MOL + 1) * 4);
    S.cursor   = (int*)alloc((size_t)N_MOL * 4);
    S.csr      = (int*)alloc((size_t)E_G * 4);
    S.bsum     = (int*)alloc(512 * 4);
    S.bnsum    = (float*)alloc(512 * 4);
    S.bnsq     = S.bnsum + 256;
    S.coef     = (float*)alloc(512 * 4);
    S.wt0      = (unsigned short*)alloc((size_t)256 * 256 * 2);
    S.wt1      = (unsigned short*)alloc((size_t)256 * 256 * 2);
    S.wt2      = (unsigned short*)alloc((size_t)256 * 256 * 2);
    float* hstat  = (float*)alloc(64 * 4);
    float* y1     = (float*)alloc((size_t)BATCH * 6 * 64 * 4);
    float* y2     = (float*)alloc((size_t)BATCH * 6 * 32 * 4);
    if ((size_t)(w - (char*)d_ws) > ws_size) {
        k_sentinel<<<16, 256, 0, stream>>>(out, out_size, -333.f); return;
    }

    const float* drug_x  = (const float*)d_in[0];
    const int* drug_ei   = (const int*)d_in[1];
    const int* drug_idx  = (const int*)d_in[2];
    const float* dis_x   = (const float*)d_in[3];
    const int* dis_ei    = (const int*)d_in[4];
    const int* dis_idx   = (const int*)d_in[5];
    const int* mol_x     = (const int*)d_in[6];
    const int* mol_ei    = (const int*)d_in[7];
    const int* mol_b     = (const int*)d_in[8];
    const float *dr_W0 = (const float*)d_in[9], *dr_W1 = (const float*)d_in[10], *dr_W2 = (const float*)d_in[11];
    const float *dr_b2 = (const float*)d_in[14];
    const float *dr_g0 = (const float*)d_in[15], *dr_g1 = (const float*)d_in[16];
    const float *dr_be0 = (const float*)d_in[17], *dr_be1 = (const float*)d_in[18];
    const float *di_W0 = (const float*)d_in[19], *di_W1 = (const float*)d_in[20], *di_W2 = (const float*)d_in[21];
    const float *di_b2 = (const float*)d_in[24];
    const float *di_g0 = (const float*)d_in[25], *di_g1 = (const float*)d_in[26];
    const float *di_be0 = (const float*)d_in[27], *di_be1 = (const float*)d_in[28];
    const float* mol_emb = (const float*)d_in[29];
    const float *mo_W0 = (const float*)d_in[30], *mo_W1 = (const float*)d_in[31], *mo_W2 = (const float*)d_in[32];
    const float *mo_b2 = (const float*)d_in[35];
    const float *mo_g0 = (const float*)d_in[36], *mo_g1 = (const float*)d_in[37];
    const float *mo_be0 = (const float*)d_in[38], *mo_be1 = (const float*)d_in[39];
    const float *c1_W = (const float*)d_in[40], *c1_b = (const float*)d_in[41];
    const float *c1_g = (const float*)d_in[42], *c1_be = (const float*)d_in[43];
    const float *c2_W = (const float*)d_in[44], *c2_b = (const float*)d_in[45];
    const float *c2_g = (const float*)d_in[46], *c2_be = (const float*)d_in[47];
    const float *l1_W = (const float*)d_in[48], *l1_b = (const float*)d_in[49];
    const float *l2_W = (const float*)d_in[50], *l2_b = (const float*)d_in[51];

    hipMemsetAsync(S.bnsum, 0, 512 * sizeof(float), stream);   // bn_coef self-zeroes thereafter

    // ---- drug GCN -> dfeat (f32) ----
    run_gcn(drug_x, DIN, 1, xb, h_bf, dfeat, 0, drug_ei, N_DRUG, E_G,
            dr_W0, dr_W1, dr_W2, dr_b2, dr_g0, dr_g1, dr_be0, dr_be1, S, stream);

    // ---- disease GCN -> sfeat (f32) ----
    run_gcn(dis_x, DIN, 1, xb, h_bf, sfeat, 0, dis_ei, N_DIS, E_G,
            di_W0, di_W1, di_W2, di_b2, di_g0, di_g1, di_be0, di_be1, S, stream);

    // ---- mol: atom encoder -> GCN (bf16 out) -> pool ----
    k_atom_enc<<<N_MOL / 4, 256, 0, stream>>>(mol_x, mol_emb, xin);
    run_gcn(xin, 256, 0, xb, h_bf, h_bf, 1, mol_ei, N_MOL, E_MOL,
            mo_W0, mo_W1, mo_W2, mo_b2, mo_g0, mo_g1, mo_be0, mo_be1, S, stream);
    k_pool_seg<<<BATCH, 128, 0, stream>>>(h_bf, mol_b, mpool);

    // ---- head ----
    hipMemsetAsync(hstat, 0, 64 * 4, stream);
    k_conv1<<<BATCH, 64, 0, stream>>>(dfeat, mpool, sfeat, drug_idx, dis_idx, c1_W, c1_b, y1);
    k_head_stats<<<dim3(6, BATCH / 256), 256, 0, stream>>>(y1, hstat, 0, 64);
    k_bn_fin<<<1, 8, 0, stream>>>(hstat, 0, 1.0f / (BATCH * 64.0f));
    k_conv2<<<BATCH, 64, 0, stream>>>(y1, hstat, c1_g, c1_be, c2_W, c2_b, y2);
    k_head_stats<<<dim3(6, BATCH / 256), 256, 0, stream>>>(y2, hstat, 1, 32);
    k_bn_fin<<<1, 8, 0, stream>>>(hstat, 1, 1.0f / (BATCH * 32.0f));
    k_head<<<BATCH, 128, 0, stream>>>(y2, hstat, c2_g, c2_be, l1_W, l1_b, l2_W, l2_b, out);
}

// Round 10
// 670.698 us; speedup vs baseline: 13.2222x; 1.0575x over previous
//
#include <hip/hip_runtime.h>
#include <hip/hip_bf16.h>

#define N_DRUG 20000
#define N_DIS  20000
#define E_G    320000
#define BATCH  4096
#define N_MOL  65536
#define E_MOL  262144
#define DIN    128
#define DH     256
#define DOUT   128
#define NF     9
#define NV     128

typedef short s16x8 __attribute__((ext_vector_type(8)));
typedef unsigned short u16x8 __attribute__((ext_vector_type(8)));
typedef float f32x4 __attribute__((ext_vector_type(4)));

__device__ __forceinline__ float bfu2f(unsigned short u) {
    return __uint_as_float(((unsigned int)u) << 16);
}
__device__ __forceinline__ unsigned short f2bfu(float f) {
    __hip_bfloat16 b = __float2bfloat16(f);
    return *reinterpret_cast<unsigned short*>(&b);
}
// HW fp atomic (no CAS retry). d_ws is coarse-grained device memory -> safe.
__device__ __forceinline__ void atomAddF(float* p, float v) { unsafeAtomicAdd(p, v); }

// ---------------- misc ----------------
__global__ void k_sentinel(float* out, int n, float v) {
    int i = blockIdx.x * 256 + threadIdx.x;
    if (i < n) out[i] = v;
}

// f32 -> bf16 cast, 4 elems/thread
__global__ void k_cast_bf4(const float* __restrict__ in, unsigned short* __restrict__ out, int n4) {
    int i = blockIdx.x * 256 + threadIdx.x;
    if (i < n4) {
        float4 v = reinterpret_cast<const float4*>(in)[i];
        ushort4 o = {f2bfu(v.x), f2bfu(v.y), f2bfu(v.z), f2bfu(v.w)};
        reinterpret_cast<ushort4*>(out)[i] = o;
    }
}

// 3 weight transposes in one kernel: W[K][N] f32 -> Wt[N][K] bf16
__global__ void k_wcast3(const float* __restrict__ W0, const float* __restrict__ W1,
                         const float* __restrict__ W2,
                         unsigned short* __restrict__ T0, unsigned short* __restrict__ T1,
                         unsigned short* __restrict__ T2, int Cin) {
    int i = blockIdx.x * 256 + threadIdx.x;
    int t0 = Cin * 256, t1 = 256 * 256, t2 = 256 * 128;
    if (i < t0) {
        int k = i / 256, c = i - k * 256;
        T0[(size_t)c * Cin + k] = f2bfu(W0[i]);
    } else if (i < t0 + t1) {
        int e = i - t0;
        int k = e / 256, c = e - k * 256;
        T1[(size_t)c * 256 + k] = f2bfu(W1[e]);
    } else if (i < t0 + t1 + t2) {
        int e = i - t0 - t1;
        int k = e / 128, c = e - k * 128;
        T2[(size_t)c * 256 + k] = f2bfu(W2[e]);
    }
}

// ---------------- degree ----------------
__global__ void k_count(const int* __restrict__ dst, int* __restrict__ cnt, int E) {
    int e = blockIdx.x * 256 + threadIdx.x;
    if (e < E) atomicAdd(&cnt[dst[e]], 1);
}

// ---------------- CSR build (scan1 also computes dinv) ----------------
__global__ void k_scan1(const int* __restrict__ cnt, int* __restrict__ rowStart,
                        int* __restrict__ bsum, float* __restrict__ dinv, int n) {
    __shared__ int sh[256];
    int i = blockIdx.x * 256 + threadIdx.x;
    int v = (i < n) ? cnt[i] : 0;
    if (i < n) dinv[i] = rsqrtf(1.0f + (float)v);
    sh[threadIdx.x] = v;
    __syncthreads();
    for (int off = 1; off < 256; off <<= 1) {
        int t = (threadIdx.x >= off) ? sh[threadIdx.x - off] : 0;
        __syncthreads();
        sh[threadIdx.x] += t;
        __syncthreads();
    }
    if (i < n) rowStart[i] = sh[threadIdx.x] - v;
    if (threadIdx.x == 255) bsum[blockIdx.x] = sh[255];
}
__global__ void k_scan2(int* __restrict__ bsum, int nb) {
    __shared__ int sh[256];
    int t = threadIdx.x;
    int v = (t < nb) ? bsum[t] : 0;
    sh[t] = v;
    __syncthreads();
    for (int off = 1; off < 256; off <<= 1) {
        int u = (t >= off) ? sh[t - off] : 0;
        __syncthreads();
        sh[t] += u;
        __syncthreads();
    }
    if (t < nb) bsum[t] = sh[t] - v;
}
__global__ void k_scan3(int* __restrict__ rowStart, int* __restrict__ cursor,
                        const int* __restrict__ bsum, int n, int E) {
    int i = blockIdx.x * 256 + threadIdx.x;
    if (i < n) {
        int r = rowStart[i] + bsum[blockIdx.x];
        rowStart[i] = r;
        cursor[i] = r;
    }
    if (i == 0) rowStart[n] = E;
}
// fill stores (src, precomputed edge weight dinv[s]*dinv[d]) pairs
__global__ void k_fill(const int* __restrict__ src, const int* __restrict__ dst,
                       const float* __restrict__ dinv,
                       int* __restrict__ cursor, int2* __restrict__ csr2, int E) {
    int e = blockIdx.x * 256 + threadIdx.x;
    if (e < E) {
        int s = src[e], d = dst[e];
        int p = atomicAdd(&cursor[d], 1);
        csr2[p] = make_int2(s, __float_as_int(dinv[s] * dinv[d]));
    }
}

// ---------------- MFMA GEMM: C[M,N]bf16 = act(A[M,K]bf16) @ B (Bt[N][K]bf16) ----------------
// AFFINE: A' = relu(scale[k]*A + shift[k]) applied during staging (fused BatchNorm+ReLU).
// STATS:  accumulate per-column sum/sumsq of C (f32 acc) into bnsum/bnsq (fused BN stats).
template<int AFFINE, int STATS>
__global__ __launch_bounds__(256) void k_gemm_mfma(const unsigned short* __restrict__ A,
                                                   const unsigned short* __restrict__ Bt,
                                                   const float* __restrict__ coef,
                                                   unsigned short* __restrict__ Cout,
                                                   float* __restrict__ bnsum,
                                                   float* __restrict__ bnsq,
                                                   int M, int K, int N) {
    __shared__ unsigned short Al[4][128][8];
    __shared__ unsigned short Bl[4][128][8];
    const int tid = threadIdx.x;
    const int bm = blockIdx.y * 128;
    const int bn = blockIdx.x * 128;
    const int w = tid >> 6, l = tid & 63;
    const int wrow = (w >> 1) * 64, wcol = (w & 1) * 64;
    const int kg = l >> 4, lr = l & 15;

    f32x4 acc[4][4];
#pragma unroll
    for (int fm = 0; fm < 4; ++fm)
#pragma unroll
        for (int fn = 0; fn < 4; ++fn) acc[fm][fn] = f32x4{0.f, 0.f, 0.f, 0.f};

    for (int k0 = 0; k0 < K; k0 += 32) {
#pragma unroll
        for (int c = 0; c < 2; ++c) {
            int idx = c * 256 + tid;
            int row = idx >> 2;
            int koff = idx & 3;
            u16x8 va = {0, 0, 0, 0, 0, 0, 0, 0};
            int grow = bm + row;
            if (grow < M)
                va = *reinterpret_cast<const u16x8*>(A + (size_t)grow * K + k0 + koff * 8);
            if (AFFINE) {
                int kb = k0 + koff * 8;
#pragma unroll
                for (int e = 0; e < 8; ++e) {
                    float f = bfu2f((unsigned short)va[e]);
                    f = fmaf(coef[kb + e], f, coef[256 + kb + e]);
                    va[e] = f2bfu(fmaxf(f, 0.f));
                }
            }
            *reinterpret_cast<u16x8*>(&Al[koff][row][0]) = va;
            u16x8 vb = *reinterpret_cast<const u16x8*>(Bt + (size_t)(bn + row) * K + k0 + koff * 8);
            *reinterpret_cast<u16x8*>(&Bl[koff][row][0]) = vb;
        }
        __syncthreads();
        s16x8 a[4], b[4];
#pragma unroll
        for (int fm = 0; fm < 4; ++fm)
            a[fm] = *reinterpret_cast<const s16x8*>(&Al[kg][wrow + fm * 16 + lr][0]);
#pragma unroll
        for (int fn = 0; fn < 4; ++fn)
            b[fn] = *reinterpret_cast<const s16x8*>(&Bl[kg][wcol + fn * 16 + lr][0]);
#pragma unroll
        for (int fm = 0; fm < 4; ++fm)
#pragma unroll
            for (int fn = 0; fn < 4; ++fn)
                acc[fm][fn] = __builtin_amdgcn_mfma_f32_16x16x32_bf16(a[fm], b[fn], acc[fm][fn], 0, 0, 0);
        __syncthreads();
    }
    // C/D layout: col = lane&15, row = (lane>>4)*4 + reg
#pragma unroll
    for (int fm = 0; fm < 4; ++fm)
#pragma unroll
        for (int r = 0; r < 4; ++r) {
            int row = bm + wrow + fm * 16 + kg * 4 + r;
            if (row >= M) continue;
#pragma unroll
            for (int fn = 0; fn < 4; ++fn) {
                int col = bn + wcol + fn * 16 + lr;
                Cout[(size_t)row * N + col] = f2bfu(acc[fm][fn][r]);
            }
        }
    if constexpr (STATS) {
        // padded rows (>=M) have zero A -> zero acc -> contribute 0 to both sums.
        __shared__ float colS[128], colQ[128];
        if (tid < 128) { colS[tid] = 0.f; colQ[tid] = 0.f; }
        __syncthreads();
#pragma unroll
        for (int fn = 0; fn < 4; ++fn) {
            float s = 0.f, q = 0.f;
#pragma unroll
            for (int fm = 0; fm < 4; ++fm)
#pragma unroll
                for (int r = 0; r < 4; ++r) {
                    float v = acc[fm][fn][r];
                    s += v; q += v * v;
                }
            int cl = (w & 1) * 64 + fn * 16 + lr;   // column within 128-wide tile
            atomicAdd(&colS[cl], s);
            atomicAdd(&colQ[cl], q);
        }
        __syncthreads();
        if (tid < 128) {
            atomAddF(&bnsum[bn + tid], colS[tid]);
            atomAddF(&bnsq[bn + tid], colQ[tid]);
        }
    }
}

// ---------------- CSR gather: 32-lane row groups, 8 rows/block, 4-deep unroll ----------------
// out[d,:] = h[d,:]*dinv[d]^2 (+bias) + sum_{(s,w) in csr2[d]} w*h[s,:]  (w precomputed)
template<int C, int BIAS, int OUTBF>
__global__ __launch_bounds__(256) void k_gather(const unsigned short* __restrict__ h,
                                                const float* __restrict__ dinv,
                                                const float* __restrict__ bias,
                                                const int2* __restrict__ csr2,
                                                const int* __restrict__ rowStart,
                                                void* __restrict__ outv, int n) {
    constexpr int PL = C / 32;  // 8 (C=256) or 4 (C=128)
    int row = blockIdx.x * 8 + (threadIdx.x >> 5);
    if (row >= n) return;
    int lane = threadIdx.x & 31;
    int c0 = lane * PL;

    auto loadRow = [&](int r, float* d) {
        const unsigned short* base = h + (size_t)r * C + c0;
        if constexpr (PL == 8) {
            u16x8 v = *reinterpret_cast<const u16x8*>(base);
#pragma unroll
            for (int e = 0; e < 8; ++e) d[e] = bfu2f((unsigned short)v[e]);
        } else {
            ushort4 v = *reinterpret_cast<const ushort4*>(base);
            d[0] = bfu2f(v.x); d[1] = bfu2f(v.y); d[2] = bfu2f(v.z); d[3] = bfu2f(v.w);
        }
    };

    float dd = dinv[row], ws = dd * dd;
    int beg = rowStart[row], end = rowStart[row + 1];
    float a0[PL], a1[PL], a2[PL], a3[PL], t0[PL], t1[PL], t2[PL], t3[PL];
    loadRow(row, t0);
#pragma unroll
    for (int p = 0; p < PL; ++p) { a0[p] = t0[p] * ws; a1[p] = 0.f; a2[p] = 0.f; a3[p] = 0.f; }

    int j = beg;
    for (; j + 4 <= end; j += 4) {
        int2 e0 = csr2[j], e1 = csr2[j + 1], e2 = csr2[j + 2], e3 = csr2[j + 3];
        float w0 = __int_as_float(e0.y), w1 = __int_as_float(e1.y);
        float w2 = __int_as_float(e2.y), w3 = __int_as_float(e3.y);
        loadRow(e0.x, t0); loadRow(e1.x, t1); loadRow(e2.x, t2); loadRow(e3.x, t3);
#pragma unroll
        for (int p = 0; p < PL; ++p) {
            a0[p] += w0 * t0[p]; a1[p] += w1 * t1[p];
            a2[p] += w2 * t2[p]; a3[p] += w3 * t3[p];
        }
    }
    for (; j < end; ++j) {
        int2 e0 = csr2[j];
        float w = __int_as_float(e0.y);
        loadRow(e0.x, t0);
#pragma unroll
        for (int p = 0; p < PL; ++p) a0[p] += w * t0[p];
    }
#pragma unroll
    for (int p = 0; p < PL; ++p) {
        a0[p] += (a1[p] + a2[p]) + a3[p];
        if (BIAS) a0[p] += bias[c0 + p];
    }
    if constexpr (OUTBF) {
        unsigned short* o = (unsigned short*)outv + (size_t)row * C + c0;
        if constexpr (PL == 8) {
            u16x8 ov;
#pragma unroll
            for (int e = 0; e < 8; ++e) ov[e] = f2bfu(a0[e]);
            *reinterpret_cast<u16x8*>(o) = ov;
        } else {
            ushort4 ov = {f2bfu(a0[0]), f2bfu(a0[1]), f2bfu(a0[2]), f2bfu(a0[3])};
            *reinterpret_cast<ushort4*>(o) = ov;
        }
    } else {
        float* o = (float*)outv + (size_t)row * C + c0;
#pragma unroll
        for (int q = 0; q < PL / 4; ++q) {
            float4 ov = {a0[q * 4 + 0], a0[q * 4 + 1], a0[q * 4 + 2], a0[q * 4 + 3]};
            *reinterpret_cast<float4*>(o + q * 4) = ov;
        }
    }
}

// ---------------- BatchNorm stats (post-gather): grid-stride, u16x8, LDS reduce ----------------
__global__ __launch_bounds__(256) void k_bn_stats_bf(const unsigned short* __restrict__ x,
                                                     float* __restrict__ sum,
                                                     float* __restrict__ sq, int n) {
    __shared__ float smS[8][256];
    __shared__ float smQ[8][256];
    int t = threadIdx.x;
    int g = t >> 5;          // row group 0..7
    int lane = t & 31;
    int c0 = lane * 8;
    float s[8], q[8];
#pragma unroll
    for (int e = 0; e < 8; ++e) { s[e] = 0.f; q[e] = 0.f; }
    int stride = gridDim.x * 8;
    for (int r = blockIdx.x * 8 + g; r < n; r += stride) {
        u16x8 v = *reinterpret_cast<const u16x8*>(x + (size_t)r * 256 + c0);
#pragma unroll
        for (int e = 0; e < 8; ++e) {
            float f = bfu2f((unsigned short)v[e]);
            s[e] += f; q[e] += f * f;
        }
    }
#pragma unroll
    for (int e = 0; e < 8; ++e) { smS[g][c0 + e] = s[e]; smQ[g][c0 + e] = q[e]; }
    __syncthreads();
    float S = 0.f, Q = 0.f;
#pragma unroll
    for (int g2 = 0; g2 < 8; ++g2) { S += smS[g2][t]; Q += smQ[g2][t]; }
    atomAddF(&sum[t], S);
    atomAddF(&sq[t], Q);
}

// coef[j]=g*rstd, coef[256+j]=be-mean*scale; zeroes sum/sq for the next stats pass
__global__ void k_bn_coef(float* __restrict__ sum, float* __restrict__ sq,
                          const float* __restrict__ g, const float* __restrict__ be,
                          float* __restrict__ coef, float invN) {
    int j = threadIdx.x;
    float m = sum[j] * invN;
    float v = sq[j] * invN - m * m;
    float r = rsqrtf(fmaxf(v, 0.f) + 1e-5f);
    float sc = g[j] * r;
    coef[j] = sc;
    coef[256 + j] = be[j] - m * sc;
    sum[j] = 0.f;
    sq[j] = 0.f;
}

// ---------------- atom encoder: 4 rows/block, 64 lanes x float4 ----------------
__global__ __launch_bounds__(256) void k_atom_enc(const int* __restrict__ mol_x,
                                                  const float* __restrict__ emb,
                                                  unsigned short* __restrict__ h) {
    __shared__ int sidx[4][NF];
    int t = threadIdx.x;
    if (t < 4 * NF) sidx[t / NF][t % NF] = mol_x[(blockIdx.x * 4 + t / NF) * NF + t % NF];
    __syncthreads();
    int r = t >> 6, lane = t & 63;
    int c0 = lane * 4;
    int row = blockIdx.x * 4 + r;
    float4 s = {0.f, 0.f, 0.f, 0.f};
#pragma unroll
    for (int f = 0; f < NF; ++f) {
        const float4 v = *reinterpret_cast<const float4*>(emb + ((size_t)f * NV + sidx[r][f]) * DH + c0);
        s.x += v.x; s.y += v.y; s.z += v.z; s.w += v.w;
    }
    ushort4 ov = {f2bfu(s.x), f2bfu(s.y), f2bfu(s.z), f2bfu(s.w)};
    *reinterpret_cast<ushort4*>(h + (size_t)row * DH + c0) = ov;
}

// ---------------- segment pool: 8 row-groups x 16 lanes x u16x8, LDS reduce ----------------
__global__ __launch_bounds__(128) void k_pool_seg(const unsigned short* __restrict__ mfeat,
                                                  const int* __restrict__ batch,
                                                  float* __restrict__ mpool) {
    __shared__ int sr[2];
    __shared__ float smS[8][128];
    int b = blockIdx.x, t = threadIdx.x;
    if (t < 2) {
        int target = b + t;
        int lo = 0, hi = N_MOL;
        while (lo < hi) {
            int mid = (lo + hi) >> 1;
            if (batch[mid] < target) lo = mid + 1; else hi = mid;
        }
        sr[t] = lo;
    }
    __syncthreads();
    int g = t >> 4;        // 0..7
    int lane = t & 15;
    int c0 = lane * 8;
    float s[8];
#pragma unroll
    for (int e = 0; e < 8; ++e) s[e] = 0.f;
    int e1 = sr[1];
    for (int i = sr[0] + g; i < e1; i += 8) {
        u16x8 v = *reinterpret_cast<const u16x8*>(mfeat + (size_t)i * 128 + c0);
#pragma unroll
        for (int e = 0; e < 8; ++e) s[e] += bfu2f((unsigned short)v[e]);
    }
#pragma unroll
    for (int e = 0; e < 8; ++e) smS[g][c0 + e] = s[e];
    __syncthreads();
    float S = 0.f;
#pragma unroll
    for (int g2 = 0; g2 < 8; ++g2) S += smS[g2][t];
    mpool[(size_t)b * 128 + t] = S;
}

// ---------------- head: conv1 ----------------
__global__ __launch_bounds__(64) void k_conv1(const float* __restrict__ dfeat,
                                              const float* __restrict__ mpool,
                                              const float* __restrict__ sfeat,
                                              const int* __restrict__ drug_idx,
                                              const int* __restrict__ dis_idx,
                                              const float* __restrict__ W,
                                              const float* __restrict__ bias,
                                              float* __restrict__ y1) {
    __shared__ float xs[3][128];
    __shared__ float w[54];
    __shared__ float bb[6];
    int b = blockIdx.x, t = threadIdx.x;
    int di = drug_idx[b], si = dis_idx[b];
    const float* r0 = dfeat + (size_t)di * 128;
    const float* r1 = mpool + (size_t)b * 128;
    const float* r2 = sfeat + (size_t)si * 128;
    xs[0][t] = r0[t]; xs[0][t + 64] = r0[t + 64];
    xs[1][t] = r1[t]; xs[1][t + 64] = r1[t + 64];
    xs[2][t] = r2[t]; xs[2][t + 64] = r2[t + 64];
    if (t < 54) w[t] = W[t];
    if (t < 6) bb[t] = bias[t];
    __syncthreads();
    int l0 = 2 * t, l1 = l0 + 1;
#pragma unroll
    for (int o = 0; o < 6; ++o) {
        float ya = bb[o], yb = bb[o];
#pragma unroll
        for (int i = 0; i < 3; ++i) {
            const float* wi = &w[(o * 3 + i) * 3];
            float xm1 = (l0 > 0) ? xs[i][l0 - 1] : 0.f;
            float x0 = xs[i][l0];
            float x1 = xs[i][l1];
            float x2 = (l1 < 127) ? xs[i][l1 + 1] : 0.f;
            ya += wi[0] * xm1 + wi[1] * x0 + wi[2] * x1;
            yb += wi[0] * x0 + wi[1] * x1 + wi[2] * x2;
        }
        y1[((size_t)b * 6 + o) * 64 + t] = fmaxf(ya, yb);
    }
}

// hb layout per 'which' (32 floats): [0..5]=sum [8..13]=sumsq [16..21]=mean [24..29]=rstd
// grid (6, 16): 16 blocks per channel -> low atomic contention
__global__ __launch_bounds__(256) void k_head_stats(const float* __restrict__ y,
                                                    float* __restrict__ hb, int which, int L) {
    int o = blockIdx.x;
    int b0 = blockIdx.y * 256;   // 256 batches per block
    int t = threadIdx.x;
    float s = 0.f, q = 0.f;
    int per = 256 * L;
    for (int idx = t; idx < per; idx += 256) {
        int b = b0 + idx / L;
        int l = idx - (idx / L) * L;
        float v = y[((size_t)b * 6 + o) * L + l];
        s += v; q += v * v;
    }
    __shared__ float sms[4], smq[4];
#pragma unroll
    for (int off = 32; off > 0; off >>= 1) {
        s += __shfl_down(s, off);
        q += __shfl_down(q, off);
    }
    if ((t & 63) == 0) { sms[t >> 6] = s; smq[t >> 6] = q; }
    __syncthreads();
    if (t == 0) {
        float S = 0.f, Q = 0.f;
        for (int i = 0; i < 4; ++i) { S += sms[i]; Q += smq[i]; }
        atomAddF(hb + which * 32 + o, S);
        atomAddF(hb + which * 32 + 8 + o, Q);
    }
}

__global__ void k_bn_fin(float* __restrict__ hb, int which, float invN) {
    int o = threadIdx.x;
    if (o >= 6) return;
    float* p = hb + which * 32;
    float m = p[o] * invN;
    float v = p[8 + o] * invN - m * m;
    p[16 + o] = m;
    p[24 + o] = rsqrtf(fmaxf(v, 0.f) + 1e-5f);
}

// ---------------- head: conv2 ----------------
__global__ __launch_bounds__(64) void k_conv2(const float* __restrict__ y1,
                                              const float* __restrict__ hb,
                                              const float* __restrict__ g1,
                                              const float* __restrict__ be1,
                                              const float* __restrict__ W,
                                              const float* __restrict__ bias,
                                              float* __restrict__ y2) {
    __shared__ float xs[6][64];
    __shared__ float w[108];
    __shared__ float bb[6];
    int b = blockIdx.x, t = threadIdx.x;
    const float* mean = hb + 16;
    const float* rstd = hb + 24;
    for (int idx = t; idx < 384; idx += 64) {
        int o = idx >> 6, l = idx & 63;
        float v = y1[((size_t)b * 6 + o) * 64 + l];
        v = g1[o] * (v - mean[o]) * rstd[o] + be1[o];
        xs[o][l] = fmaxf(v, 0.f);
    }
    for (int idx = t; idx < 108; idx += 64) w[idx] = W[idx];
    if (t < 6) bb[t] = bias[t];
    __syncthreads();
    if (t >= 32) return;
    int l0 = 2 * t, l1 = l0 + 1;
#pragma unroll
    for (int o = 0; o < 6; ++o) {
        float ya = bb[o], yb = bb[o];
#pragma unroll
        for (int i = 0; i < 6; ++i) {
            const float* wi = &w[(o * 6 + i) * 3];
            float xm1 = (l0 > 0) ? xs[i][l0 - 1] : 0.f;
            float x0 = xs[i][l0];
            float x1 = xs[i][l1];
            float x2 = (l1 < 63) ? xs[i][l1 + 1] : 0.f;
            ya += wi[0] * xm1 + wi[1] * x0 + wi[2] * x1;
            yb += wi[0] * x0 + wi[1] * x1 + wi[2] * x2;
        }
        y2[((size_t)b * 6 + o) * 32 + t] = fmaxf(ya, yb);
    }
}

// ---------------- head final ----------------
__global__ __launch_bounds__(128) void k_head(const float* __restrict__ y2,
                                              const float* __restrict__ hb,
                                              const float* __restrict__ g2,
                                              const float* __restrict__ be2,
                                              const float* __restrict__ l1W,
                                              const float* __restrict__ l1b,
                                              const float* __restrict__ l2W,
                                              const float* __restrict__ l2b,
                                              float* __restrict__ out) {
    __shared__ float fs[192];
    __shared__ float sm[2];
    int b = blockIdx.x, t = threadIdx.x;
    const float* mean = hb + 32 + 16;
    const float* rstd = hb + 32 + 24;
    for (int idx = t; idx < 192; idx += 128) {
        int o = idx >> 5, l = idx & 31;
        float v = y2[((size_t)b * 6 + o) * 32 + l];
        v = g2[o] * (v - mean[o]) * rstd[o] + be2[o];
        fs[idx] = fmaxf(v, 0.f);
    }
    __syncthreads();
    float h = l1b[t];
    for (int k = 0; k < 192; ++k)
        h += fs[k] * l1W[k * 128 + t];
    h = fmaxf(h, 0.f);
    float p = h * l2W[t];
#pragma unroll
    for (int off = 32; off > 0; off >>= 1) p += __shfl_down(p, off);
    if ((t & 63) == 0) sm[t >> 6] = p;
    __syncthreads();
    if (t == 0) out[b] = sm[0] + sm[1] + l2b[0];
}

// ---------------- host-side GCN driver ----------------
struct GcnScratch {
    int *cnt, *rowStart, *cursor, *bsum;
    int2* csr2;
    float *dinv, *bnsum, *bnsq, *coef;
    unsigned short *wt0, *wt1, *wt2;
};

// xin: bf16 [n][Cin]. Output: out2bf? bf16 : f32 [n][128]
static void run_gcn(const unsigned short* xin, int Cin,
                    unsigned short* xb, unsigned short* h_bf, void* outF, int out2bf,
                    const int* ei, int n, int E,
                    const float* W0, const float* W1, const float* W2, const float* b2,
                    const float* g0, const float* g1, const float* be0, const float* be1,
                    GcnScratch& S, hipStream_t stream) {
    const int* src = ei;
    const int* dst = ei + E;
    hipMemsetAsync(S.cnt, 0, (size_t)n * sizeof(int), stream);
    k_count<<<(E + 255) / 256, 256, 0, stream>>>(dst, S.cnt, E);
    int nb = (n + 255) / 256;
    k_scan1<<<nb, 256, 0, stream>>>(S.cnt, S.rowStart, S.bsum, S.dinv, n);
    k_scan2<<<1, 256, 0, stream>>>(S.bsum, nb);
    k_scan3<<<nb, 256, 0, stream>>>(S.rowStart, S.cursor, S.bsum, n, E);
    k_fill<<<(E + 255) / 256, 256, 0, stream>>>(src, dst, S.dinv, S.cursor, S.csr2, E);
    int wtot = Cin * 256 + 256 * 256 + 256 * 128;
    k_wcast3<<<(wtot + 255) / 256, 256, 0, stream>>>(W0, W1, W2, S.wt0, S.wt1, S.wt2, Cin);

    int gb = (n + 7) / 8;
    int gy = (n + 127) / 128;
    float invN = 1.0f / (float)n;
    int sb = min(512, (n + 7) / 8);
    // L0: aggregate-first (S·X)·W0 (bias dropped: cancelled by BN); stats fused in GEMM epilogue
    if (Cin == 256)
        k_gather<256, 0, 1><<<gb, 256, 0, stream>>>(xin, S.dinv, nullptr, S.csr2, S.rowStart, xb, n);
    else
        k_gather<128, 0, 1><<<gb, 256, 0, stream>>>(xin, S.dinv, nullptr, S.csr2, S.rowStart, xb, n);
    k_gemm_mfma<0, 1><<<dim3(2, gy), 256, 0, stream>>>(xb, S.wt0, nullptr, h_bf, S.bnsum, S.bnsq, n, Cin, 256);
    k_bn_coef<<<1, 256, 0, stream>>>(S.bnsum, S.bnsq, g0, be0, S.coef, invN);
    // L1: GEMM(BN0+relu fused on A) -> gather -> stats
    k_gemm_mfma<1, 0><<<dim3(2, gy), 256, 0, stream>>>(h_bf, S.wt1, S.coef, xb, nullptr, nullptr, n, 256, 256);
    k_gather<256, 0, 1><<<gb, 256, 0, stream>>>(xb, S.dinv, nullptr, S.csr2, S.rowStart, h_bf, n);
    k_bn_stats_bf<<<sb, 256, 0, stream>>>(h_bf, S.bnsum, S.bnsq, n);
    k_bn_coef<<<1, 256, 0, stream>>>(S.bnsum, S.bnsq, g1, be1, S.coef, invN);
    // L2: GEMM(BN1+relu fused on A) -> gather + bias (no BN)
    k_gemm_mfma<1, 0><<<dim3(1, gy), 256, 0, stream>>>(h_bf, S.wt2, S.coef, xb, nullptr, nullptr, n, 256, 128);
    if (out2bf)
        k_gather<128, 1, 1><<<gb, 256, 0, stream>>>(xb, S.dinv, b2, S.csr2, S.rowStart, outF, n);
    else
        k_gather<128, 1, 0><<<gb, 256, 0, stream>>>(xb, S.dinv, b2, S.csr2, S.rowStart, outF, n);
}

extern "C" void kernel_launch(void* const* d_in, const int* in_sizes, int n_in,
                              void* d_out, int out_size, void* d_ws, size_t ws_size,
                              hipStream_t stream) {
    float* out = (float*)d_out;
    if (n_in != 52) { k_sentinel<<<16, 256, 0, stream>>>(out, out_size, -111.f); return; }
    if (in_sizes[0] != N_DRUG * DIN || in_sizes[29] != NF * NV * DH || in_sizes[48] != 192 * 128) {
        k_sentinel<<<16, 256, 0, stream>>>(out, out_size, -222.f); return;
    }

    char* w = (char*)d_ws;
    auto alloc = [&](size_t bytes) { char* p = w; w += (bytes + 255) & ~(size_t)255; return p; };
    unsigned short* xb   = (unsigned short*)alloc((size_t)N_MOL * 256 * 2);
    unsigned short* h_bf = (unsigned short*)alloc((size_t)N_MOL * 256 * 2);
    unsigned short* xin  = (unsigned short*)alloc((size_t)N_MOL * 256 * 2);
    float* dfeat = (float*)alloc((size_t)N_DRUG * 128 * 4);
    float* sfeat = (float*)alloc((size_t)N_DIS * 128 * 4);
    float* mpool = (float*)alloc((size_t)BATCH * 128 * 4);
    GcnScratch S;
    S.cnt      = (int*)alloc((size_t)N_MOL * 4);
    S.dinv     = (float*)alloc((size_t)N_MOL * 4);
    S.rowStart = (int*)alloc((size_t)(N_MOL + 1) * 4);
    S.cursor   = (int*)alloc((size_t)N_MOL * 4);
    S.csr2     = (int2*)alloc((size_t)E_G * 8);
    S.bsum     = (int*)alloc(512 * 4);
    S.bnsum    = (float*)alloc(512 * 4);
    S.bnsq     = S.bnsum + 256;
    S.coef     = (float*)alloc(512 * 4);
    S.wt0      = (unsigned short*)alloc((size_t)256 * 256 * 2);
    S.wt1      = (unsigned short*)alloc((size_t)256 * 256 * 2);
    S.wt2      = (unsigned short*)alloc((size_t)256 * 256 * 2);
    float* hstat  = (float*)alloc(64 * 4);
    float* y1     = (float*)alloc((size_t)BATCH * 6 * 64 * 4);
    float* y2     = (float*)alloc((size_t)BATCH * 6 * 32 * 4);
    if ((size_t)(w - (char*)d_ws) > ws_size) {
        k_sentinel<<<16, 256, 0, stream>>>(out, out_size, -333.f); return;
    }

    const float* drug_x  = (const float*)d_in[0];
    const int* drug_ei   = (const int*)d_in[1];
    const int* drug_idx  = (const int*)d_in[2];
    const float* dis_x   = (const float*)d_in[3];
    const int* dis_ei    = (const int*)d_in[4];
    const int* dis_idx   = (const int*)d_in[5];
    const int* mol_x     = (const int*)d_in[6];
    const int* mol_ei    = (const int*)d_in[7];
    const int* mol_b     = (const int*)d_in[8];
    const float *dr_W0 = (const float*)d_in[9], *dr_W1 = (const float*)d_in[10], *dr_W2 = (const float*)d_in[11];
    const float *dr_b2 = (const float*)d_in[14];
    const float *dr_g0 = (const float*)d_in[15], *dr_g1 = (const float*)d_in[16];
    const float *dr_be0 = (const float*)d_in[17], *dr_be1 = (const float*)d_in[18];
    const float *di_W0 = (const float*)d_in[19], *di_W1 = (const float*)d_in[20], *di_W2 = (const float*)d_in[21];
    const float *di_b2 = (const float*)d_in[24];
    const float *di_g0 = (const float*)d_in[25], *di_g1 = (const float*)d_in[26];
    const float *di_be0 = (const float*)d_in[27], *di_be1 = (const float*)d_in[28];
    const float* mol_emb = (const float*)d_in[29];
    const float *mo_W0 = (const float*)d_in[30], *mo_W1 = (const float*)d_in[31], *mo_W2 = (const float*)d_in[32];
    const float *mo_b2 = (const float*)d_in[35];
    const float *mo_g0 = (const float*)d_in[36], *mo_g1 = (const float*)d_in[37];
    const float *mo_be0 = (const float*)d_in[38], *mo_be1 = (const float*)d_in[39];
    const float *c1_W = (const float*)d_in[40], *c1_b = (const float*)d_in[41];
    const float *c1_g = (const float*)d_in[42], *c1_be = (const float*)d_in[43];
    const float *c2_W = (const float*)d_in[44], *c2_b = (const float*)d_in[45];
    const float *c2_g = (const float*)d_in[46], *c2_be = (const float*)d_in[47];
    const float *l1_W = (const float*)d_in[48], *l1_b = (const float*)d_in[49];
    const float *l2_W = (const float*)d_in[50], *l2_b = (const float*)d_in[51];

    hipMemsetAsync(S.bnsum, 0, 512 * sizeof(float), stream);   // bn_coef self-zeroes thereafter

    // ---- drug GCN -> dfeat (f32) ----
    k_cast_bf4<<<(N_DRUG * DIN / 4 + 255) / 256, 256, 0, stream>>>(drug_x, xin, N_DRUG * DIN / 4);
    run_gcn(xin, DIN, xb, h_bf, dfeat, 0, drug_ei, N_DRUG, E_G,
            dr_W0, dr_W1, dr_W2, dr_b2, dr_g0, dr_g1, dr_be0, dr_be1, S, stream);

    // ---- disease GCN -> sfeat (f32) ----
    k_cast_bf4<<<(N_DIS * DIN / 4 + 255) / 256, 256, 0, stream>>>(dis_x, xin, N_DIS * DIN / 4);
    run_gcn(xin, DIN, xb, h_bf, sfeat, 0, dis_ei, N_DIS, E_G,
            di_W0, di_W1, di_W2, di_b2, di_g0, di_g1, di_be0, di_be1, S, stream);

    // ---- mol: atom encoder -> GCN (bf16 out) -> pool ----
    k_atom_enc<<<N_MOL / 4, 256, 0, stream>>>(mol_x, mol_emb, xin);
    run_gcn(xin, 256, xb, h_bf, h_bf, 1, mol_ei, N_MOL, E_MOL,
            mo_W0, mo_W1, mo_W2, mo_b2, mo_g0, mo_g1, mo_be0, mo_be1, S, stream);
    k_pool_seg<<<BATCH, 128, 0, stream>>>(h_bf, mol_b, mpool);

    // ---- head ----
    hipMemsetAsync(hstat, 0, 64 * 4, stream);
    k_conv1<<<BATCH, 64, 0, stream>>>(dfeat, mpool, sfeat, drug_idx, dis_idx, c1_W, c1_b, y1);
    k_head_stats<<<dim3(6, BATCH / 256), 256, 0, stream>>>(y1, hstat, 0, 64);
    k_bn_fin<<<1, 8, 0, stream>>>(hstat, 0, 1.0f / (BATCH * 64.0f));
    k_conv2<<<BATCH, 64, 0, stream>>>(y1, hstat, c1_g, c1_be, c2_W, c2_b, y2);
    k_head_stats<<<dim3(6, BATCH / 256), 256, 0, stream>>>(y2, hstat, 1, 32);
    k_bn_fin<<<1, 8, 0, stream>>>(hstat, 1, 1.0f / (BATCH * 32.0f));
    k_head<<<BATCH, 128, 0, stream>>>(y2, hstat, c2_g, c2_be, l1_W, l1_b, l2_W, l2_b, out);
}